// Round 2
// baseline (1819.071 us; speedup 1.0000x reference)
//
#include <hip/hip_runtime.h>
#include <math.h>

#define HD 48
#define NB 2304      // 48*48
#define NC 64
#define IMG 96
#define NP 2401      // 49*49

#define CDIV(a,b) (((a)+(b)-1)/(b))

// ---------------- workspace layout (floats) ----------------
constexpr int SZ_IMGC = NC*NB;          // 147456
constexpr size_t O_MASKDS = 0;                      // NB
constexpr size_t O_MM     = O_MASKDS + NB;          // NB
constexpr size_t O_FDS    = O_MM + NB;
constexpr size_t O_BDS    = O_FDS + SZ_IMGC;
constexpr size_t O_QF     = O_BDS + SZ_IMGC;
constexpr size_t O_KF     = O_QF + SZ_IMGC;
constexpr size_t O_VF     = O_KF + SZ_IMGC;
constexpr size_t O_FP     = O_VF + SZ_IMGC;
constexpr size_t O_WIN    = O_FP + SZ_IMGC;         // NB*576
constexpr size_t O_BCOL   = O_WIN + (size_t)NB*576; // 576*NB (also 4x K-split partials = 256*NB)
constexpr size_t O_BIG0   = O_BCOL + (size_t)576*NB;
constexpr size_t O_BIG1   = O_BIG0 + (size_t)NB*NB;
// U reuses [O_WIN, O_BIG1): win+bcol+big0 are dead when U is built (needs NP*NP <= 7,962,624: ok)
constexpr size_t O_U      = O_WIN;
// b4m + G reuse big1's region: big1 (yi) is dead after k_zbuild
constexpr size_t O_B4     = O_BIG1;                  // 256*NP
constexpr size_t O_G      = O_B4 + (size_t)256*NP;   // 256*NP
constexpr size_t O_PMAX   = O_BIG1 + (size_t)NB*NB;  // 16*NB
constexpr size_t O_PSUM   = O_PMAX + 16*NB;          // 16*NB
constexpr size_t O_CMAX   = O_PSUM + 16*NB;          // NB
constexpr size_t O_CINV   = O_CMAX + NB;             // NB
constexpr size_t TOTAL_F  = O_CINV + NB;             // ~14.24M floats ~57MB

// ---------------- kernels ----------------

// maskds[q] = mask0[2hq,2wq];  mm[q] = 1 if all in-bounds 3x3 neighbors are 0
__global__ void k_prep_mask(const float* __restrict__ mask, float* __restrict__ maskds,
                            float* __restrict__ mm){
  int q = blockIdx.x*256 + threadIdx.x;
  if(q >= NB) return;
  int hq = q/HD, wq = q%HD;
  maskds[q] = mask[(2*hq)*IMG + 2*wq];
  float any = 0.f;
  for(int u=-1;u<=1;u++)
    for(int v=-1;v<=1;v++){
      int y=hq+u, x=wq+v;
      if(y>=0&&y<HD&&x>=0&&x<HD) any += mask[(2*y)*IMG + 2*x];
    }
  mm[q] = (any == 0.f) ? 1.f : 0.f;
}

// downsample: dst[c][j] = src[s][c][2h][2w]
__global__ void k_ds(const float* __restrict__ src, float* __restrict__ dst, int s){
  int idx = blockIdx.x*256 + threadIdx.x;
  if(idx >= NC*NB) return;
  int c = idx/NB, j = idx%NB;
  int h = j/HD, w = j%HD;
  dst[idx] = src[(((size_t)s*NC + c)*IMG + 2*h)*IMG + 2*w];
}

// Stage A: per-patch attention (pa weights) + patch normalization -> wi_n[p][c][i]
__global__ void k_patch_attn(const float* __restrict__ fds, const float* __restrict__ bds,
                             const float* __restrict__ maskds,
                             const float* __restrict__ wq, const float* __restrict__ bq,
                             const float* __restrict__ wk, const float* __restrict__ bk,
                             const float* __restrict__ wv, const float* __restrict__ bv,
                             const float* __restrict__ gammap,
                             float* __restrict__ win){
  __shared__ float A[64][9], Bm[64][9], Q[64][9], K[64][9], V[64][9];
  __shared__ float attn[9][9];
  __shared__ float mval[9];
  int p = blockIdx.x;
  int ph = p/HD, pw = p%HD;
  int c = threadIdx.x;  // 64 threads = 1 wave
  for(int i=0;i<9;i++){
    int u=i/3, v=i%3;
    int y=ph+u-1, x=pw+v-1;
    bool in = (y>=0&&y<HD&&x>=0&&x<HD);
    float fv = in ? fds[c*NB + y*HD + x] : 0.f;
    float bvv= in ? bds[c*NB + y*HD + x] : 0.f;
    A[c][i] = fv;  Bm[c][i] = bvv;
    if(c==0) mval[i] = in ? maskds[y*HD + x] : 0.f;
  }
  __syncthreads();
  float qr[9]={}, kr[9]={}, vr[9]={};
  for(int cc=0;cc<64;cc++){
    float wqv = wq[c*64+cc], wkv = wk[c*64+cc], wvv = wv[c*64+cc];
    #pragma unroll
    for(int i=0;i<9;i++){
      qr[i] += wqv*A[cc][i];
      kr[i] += wkv*Bm[cc][i];
      vr[i] += wvv*A[cc][i];
    }
  }
  float bqv=bq[c], bkv=bk[c], bvv2=bv[c];
  #pragma unroll
  for(int i=0;i<9;i++){ Q[c][i]=qr[i]+bqv; K[c][i]=kr[i]+bkv; V[c][i]=vr[i]+bvv2; }
  __syncthreads();
  if(c<9){
    int i = c;
    float mv = mval[i];
    float L[9];
    for(int j=0;j<9;j++){
      float sacc = 0.f;
      for(int cc=0;cc<64;cc++) sacc += Q[cc][i]*K[cc][j];
      L[j] = sacc*mv;
    }
    float mx = L[0];
    for(int j=1;j<9;j++) mx = fmaxf(mx, L[j]);
    float sum = 0.f;
    for(int j=0;j<9;j++){ L[j] = expf(L[j]-mx); sum += L[j]; }
    float inv = 1.f/sum;
    for(int j=0;j<9;j++) attn[i][j] = L[j]*inv;
  }
  __syncthreads();
  float gamma = gammap[0];
  float fpv[9];
  float ss = 0.f;
  #pragma unroll
  for(int i=0;i<9;i++){
    float o = 0.f;
    #pragma unroll
    for(int j=0;j<9;j++) o += V[c][j]*attn[i][j];
    float mv = mval[i];
    float val = gamma*A[c][i]*mv + (1.f-mv)*o;
    fpv[i] = val;
    ss += val*val;
  }
  for(int off=32; off>0; off>>=1) ss += __shfl_down(ss, off);
  ss = __shfl(ss, 0);
  float scale = 1.f / fmaxf(sqrtf(ss), 1e-4f);
  #pragma unroll
  for(int i=0;i<9;i++) win[(size_t)p*576 + c*9 + i] = fpv[i]*scale;
}

// B1: qf/kf/vf = W @ X + bias  (fa weights)
__global__ void k_conv1x1(const float* __restrict__ fds, const float* __restrict__ bds,
                          const float* __restrict__ wq, const float* __restrict__ bq,
                          const float* __restrict__ wk, const float* __restrict__ bk,
                          const float* __restrict__ wv, const float* __restrict__ bv,
                          float* __restrict__ qf, float* __restrict__ kf, float* __restrict__ vf){
  int m = blockIdx.z;
  const float* W    = (m==0)? wq : (m==1? wk : wv);
  const float* bias = (m==0)? bq : (m==1? bk : bv);
  const float* src  = (m==1)? bds : fds;
  float* dst        = (m==0)? qf : (m==1? kf : vf);
  __shared__ float Wl[16][64];
  int o0 = blockIdx.x*16;
  int j  = blockIdx.y*256 + threadIdx.x;
  for(int t=threadIdx.x; t<16*64; t+=256) Wl[t>>6][t&63] = W[(o0 + (t>>6))*64 + (t&63)];
  __syncthreads();
  float acc[16]={};
  for(int c=0;c<64;c++){
    float xv = src[c*NB + j];
    #pragma unroll
    for(int oo=0;oo<16;oo++) acc[oo] += Wl[oo][c]*xv;
  }
  for(int oo=0;oo<16;oo++) dst[(size_t)(o0+oo)*NB + j] = acc[oo] + bias[o0+oo];
}

// B2: sim[i][j] = sum_c qf[c][i]*kf[c][j]
__global__ void k_simgemm(const float* __restrict__ Amat, const float* __restrict__ Bmat,
                          float* __restrict__ Cm){
  __shared__ float At[64][32], Bt2[64][32];
  int i0 = blockIdx.y*32, j0 = blockIdx.x*32;
  int tid = threadIdx.x;
  for(int t=tid; t<2048; t+=256){
    int cc=t>>5, xx=t&31;
    At[cc][xx]  = Amat[cc*NB + i0+xx];
    Bt2[cc][xx] = Bmat[cc*NB + j0+xx];
  }
  __syncthreads();
  int ti = tid>>4, tj = tid&15;
  float a00=0,a01=0,a10=0,a11=0;
  for(int cc=0;cc<64;cc++){
    float x0=At[cc][ti*2], x1=At[cc][ti*2+1];
    float y0=Bt2[cc][tj*2], y1=Bt2[cc][tj*2+1];
    a00+=x0*y0; a01+=x0*y1; a10+=x1*y0; a11+=x1*y1;
  }
  size_t r0=(size_t)(i0+ti*2)*NB + j0+tj*2;
  Cm[r0]=a00; Cm[r0+1]=a01; Cm[r0+NB]=a10; Cm[r0+NB+1]=a11;
}

// B3: attn[i][:] = softmax_j(sim[i][j]*maskds[i])
__global__ void k_rowsm(const float* __restrict__ sim, const float* __restrict__ maskds,
                        float* __restrict__ attn){
  int i = blockIdx.x;
  float mv = maskds[i];
  const float* row = sim + (size_t)i*NB;
  float* orow = attn + (size_t)i*NB;
  __shared__ float red[8];
  int tid = threadIdx.x;
  float mx = -1e30f;
  for(int j=tid;j<NB;j+=256) mx = fmaxf(mx, row[j]*mv);
  for(int off=32;off>0;off>>=1) mx = fmaxf(mx, __shfl_down(mx,off));
  if((tid&63)==0) red[tid>>6]=mx;
  __syncthreads();
  mx = fmaxf(fmaxf(red[0],red[1]),fmaxf(red[2],red[3]));
  float sum=0.f;
  for(int j=tid;j<NB;j+=256){ float e = expf(row[j]*mv - mx); orow[j]=e; sum+=e; }
  for(int off=32;off>0;off>>=1) sum += __shfl_down(sum,off);
  if((tid&63)==0) red[4+(tid>>6)]=sum;
  __syncthreads();
  sum = red[4]+red[5]+red[6]+red[7];
  float inv = 1.f/sum;
  for(int j=tid;j<NB;j+=256) orow[j] *= inv;
}

// B4 (K-split): part[ks][c][i] = sum_{j in ks-chunk} vf[c][j]*attn[i][j]
__global__ void k_attn_apply(const float* __restrict__ vf, const float* __restrict__ attn,
                             float* __restrict__ part){
  int i0 = blockIdx.x*32;
  int ks = blockIdx.y;
  __shared__ float Vt[64][33];
  __shared__ float At[32][33];
  int tid = threadIdx.x;
  int il = tid&31, cg = tid>>5;
  float acc[8]={};
  for(int k0=ks*576; k0<ks*576+576; k0+=32){
    for(int t=tid;t<2048;t+=256){ int c=t>>5, j=t&31; Vt[c][j]=vf[c*NB + k0+j]; }
    for(int t=tid;t<1024;t+=256){ int i=t>>5, j=t&31; At[i][j]=attn[(size_t)(i0+i)*NB + k0+j]; }
    __syncthreads();
    for(int j=0;j<32;j++){
      float a = At[il][j];
      #pragma unroll
      for(int q=0;q<8;q++) acc[q] += Vt[cg*8+q][j]*a;
    }
    __syncthreads();
  }
  #pragma unroll
  for(int q=0;q<8;q++) part[(size_t)(ks*64 + cg*8+q)*NB + i0+il] = acc[q];
}

// reduce partials + epilogue: fp = gamma*fds*mv + (1-mv)*out
__global__ void k_fp(const float* __restrict__ part, const float* __restrict__ fds,
                     const float* __restrict__ maskds, const float* __restrict__ gammap,
                     float* __restrict__ fp){
  int idx = blockIdx.x*256 + threadIdx.x;
  if(idx >= NC*NB) return;
  int i = idx%NB;
  float o = part[idx] + part[(size_t)NC*NB + idx] + part[(size_t)2*NC*NB + idx] + part[(size_t)3*NC*NB + idx];
  float mv = maskds[i];
  fp[idx] = gammap[0]*fds[idx]*mv + (1.f-mv)*o;
}

// im2col of fp (3x3, pad 1): bcol[k=(c,u,v)][P]
__global__ void k_bcol(const float* __restrict__ fp, float* __restrict__ bcol){
  int idx = blockIdx.x*256 + threadIdx.x;
  if(idx >= 576*NB) return;
  int k = idx/NB, P = idx%NB;
  int c = k/9, i = k%9, u = i/3, v = i%3;
  int hP = P/HD, wP = P%HD;
  int y = hP+u-1, x = wP+v-1;
  bcol[idx] = (y>=0&&y<HD&&x>=0&&x<HD) ? fp[c*NB + y*HD + x] : 0.f;
}

// generic row-major GEMM C[M][N] = A[M][Kd] @ B[Kd][N], bounds-guarded
__global__ void k_gemm(const float* __restrict__ A, const float* __restrict__ B,
                       float* __restrict__ Cm, int M, int N, int Kd){
  __shared__ float At[64][17];
  __shared__ float Bt[16][64];
  int n0 = blockIdx.x*64, m0 = blockIdx.y*64;
  int tid = threadIdx.x;
  int tr = tid>>4, tc = tid&15;
  float acc[4][4]={};
  for(int k0=0;k0<Kd;k0+=16){
    for(int t=tid;t<1024;t+=256){
      int r=t>>4, k=t&15;
      At[r][k] = (m0+r < M && k0+k < Kd) ? A[(size_t)(m0+r)*Kd + k0+k] : 0.f;
    }
    for(int t=tid;t<1024;t+=256){
      int k=t>>6, c=t&63;
      Bt[k][c] = (k0+k < Kd && n0+c < N) ? B[(size_t)(k0+k)*N + n0+c] : 0.f;
    }
    __syncthreads();
    #pragma unroll
    for(int k=0;k<16;k++){
      float a0=At[tr*4+0][k], a1=At[tr*4+1][k], a2=At[tr*4+2][k], a3=At[tr*4+3][k];
      float b0=Bt[k][tc*4+0], b1=Bt[k][tc*4+1], b2=Bt[k][tc*4+2], b3=Bt[k][tc*4+3];
      acc[0][0]+=a0*b0; acc[0][1]+=a0*b1; acc[0][2]+=a0*b2; acc[0][3]+=a0*b3;
      acc[1][0]+=a1*b0; acc[1][1]+=a1*b1; acc[1][2]+=a1*b2; acc[1][3]+=a1*b3;
      acc[2][0]+=a2*b0; acc[2][1]+=a2*b1; acc[2][2]+=a2*b2; acc[2][3]+=a2*b3;
      acc[3][0]+=a3*b0; acc[3][1]+=a3*b1; acc[3][2]+=a3*b2; acc[3][3]+=a3*b3;
    }
    __syncthreads();
  }
  for(int r=0;r<4;r++)
    for(int c2=0;c2<4;c2++){
      int mi = m0+tr*4+r, ni = n0+tc*4+c2;
      if(mi < M && ni < N) Cm[(size_t)mi*N + ni] = acc[r][c2];
    }
}

// D1: diagonal fuse in h-major flat space
__global__ void k_fuse1(const float* __restrict__ in, float* __restrict__ out){
  size_t idx = (size_t)blockIdx.x*256 + threadIdx.x;
  if(idx >= (size_t)NB*NB) return;
  int q = (int)(idx/NB), P = (int)(idx%NB);
  float s = in[idx];
  if(q>0 && P>0)       s += in[idx - NB - 1];
  if(q<NB-1 && P<NB-1) s += in[idx + NB + 1];
  out[idx] = s;
}

// D2: diagonal fuse in w-major flat space (transpose-fuse-transpose)
__global__ void k_fuse2(const float* __restrict__ in, float* __restrict__ out){
  size_t idx = (size_t)blockIdx.x*256 + threadIdx.x;
  if(idx >= (size_t)NB*NB) return;
  int q = (int)(idx/NB), P = (int)(idx%NB);
  int hq=q/HD, wq=q%HD, hP=P/HD, wP=P%HD;
  int qw = wq*HD + hq, Pw = wP*HD + hP;
  float s = 0.f;
  #pragma unroll
  for(int d=-1;d<=1;d++){
    int qd = qw+d, Pd = Pw+d;
    if(qd>=0 && qd<NB && Pd>=0 && Pd<NB){
      int q2 = (qd%HD)*HD + qd/HD;
      int P2 = (Pd%HD)*HD + Pd/HD;
      s += in[(size_t)q2*NB + P2];
    }
  }
  out[idx] = s;
}

// E1: per-(chunk,col) online softmax partials over q; logits L = mm[q]? 10*sc : 0
__global__ void k_colsm_partial(const float* __restrict__ sc, const float* __restrict__ mm,
                                float* __restrict__ pmax, float* __restrict__ psum){
  int col = blockIdx.x*256 + threadIdx.x;
  int q0 = blockIdx.y*144;
  float mx = -1e30f, sum = 0.f;
  for(int q=q0; q<q0+144; q++){
    float L = (mm[q]!=0.f) ? 10.f*sc[(size_t)q*NB + col] : 0.f;
    if(L > mx){ sum *= expf(mx - L); mx = L; }
    sum += expf(L - mx);
  }
  pmax[blockIdx.y*NB + col] = mx;
  psum[blockIdx.y*NB + col] = sum;
}

// E2: combine partials -> cmax, cinv(=1/sum)
__global__ void k_colsm_combine(const float* __restrict__ pmax, const float* __restrict__ psum,
                                float* __restrict__ cmax, float* __restrict__ cinv){
  int col = blockIdx.x*256 + threadIdx.x;
  if(col >= NB) return;
  float M = -1e30f;
  for(int k=0;k<16;k++) M = fmaxf(M, pmax[k*NB+col]);
  float S = 0.f;
  for(int k=0;k<16;k++) S += psum[k*NB+col]*expf(pmax[k*NB+col]-M);
  cmax[col] = M;
  cinv[col] = 1.f/S;
}

// E3: yi[q][P] = mm[q] ? exp(10*sc - cmax[P]) * cinv[P] : 0
__global__ void k_colsm_apply(const float* __restrict__ sc, const float* __restrict__ mm,
                              const float* __restrict__ cmax, const float* __restrict__ cinv,
                              float* __restrict__ yi){
  size_t idx = (size_t)blockIdx.x*256 + threadIdx.x;
  if(idx >= (size_t)NB*NB) return;
  int q = (int)(idx/NB), P = (int)(idx%NB);
  yi[idx] = (mm[q]!=0.f) ? expf(10.f*sc[idx] - cmax[P])*cinv[P] : 0.f;
}

// F1 (FIXED): U[p'][(rho,sig)] = sum_{a,b in {0,1}} yi[(p'h-a, p'w-b)][(rho-a, sig-b)]
// derived from y = 2h-1+ky, q' = q+(a,b):
// out[c,2r+py,2s+px] = sum_{q'} b[c,2q'h-py,2q'w-px] * U[q'][(r+py, s+px)] / 4
__global__ void k_zbuild(const float* __restrict__ yi, float* __restrict__ U){
  size_t idx = (size_t)blockIdx.x*256 + threadIdx.x;
  if(idx >= (size_t)NP*NP) return;
  int pp = (int)(idx/NP), col = (int)(idx%NP);
  int ph = pp/49, pw = pp%49;
  int rho = col/49, sig = col%49;
  float z = 0.f;
  #pragma unroll
  for(int a=0;a<2;a++)
    #pragma unroll
    for(int bb=0;bb<2;bb++){
      int sh=ph-a, sw=pw-bb, rr=rho-a, ss=sig-bb;
      if(sh>=0 && sh<HD && sw>=0 && sw<HD && rr>=0 && rr<HD && ss>=0 && ss<HD)
        z += yi[(size_t)(sh*HD+sw)*NB + rr*HD+ss];
    }
  U[idx] = z;
}

// F2: phase-gathered b: b4m[(py*2+px)*64 + c][p'] = b[s][c][2p'h - py][2p'w - px]
__global__ void k_b4(const float* __restrict__ b, float* __restrict__ b4m, int s){
  int idx = blockIdx.x*256 + threadIdx.x;
  if(idx >= 256*NP) return;
  int m = idx/NP, pp = idx%NP;
  int phase = m>>6, c = m&63;
  int py = phase>>1, px = phase&1;
  int ph = pp/49, pw = pp%49;
  int y = 2*ph - py, x = 2*pw - px;
  b4m[idx] = (y>=0&&y<IMG&&x>=0&&x<IMG) ? b[(((size_t)s*NC + c)*IMG + y)*IMG + x] : 0.f;
}

// F4: out[c, 2r+py, 2s+px] = G[(py*2+px)*64+c][(r+py)*49 + (s+px)] * 0.25
__global__ void k_epi(const float* __restrict__ G, float* __restrict__ out, int s){
  int idx = blockIdx.x*256 + threadIdx.x;
  if(idx >= NC*IMG*IMG) return;
  int c = idx/(IMG*IMG), rem = idx%(IMG*IMG);
  int y = rem/IMG, x = rem%IMG;
  int py = y&1, px = x&1, r = y>>1, s2 = x>>1;
  out[((size_t)s*NC + c)*IMG*IMG + rem] =
      G[(size_t)((py*2+px)*64 + c)*NP + (r+py)*49 + (s2+px)] * 0.25f;
}

// ---------------- launcher ----------------
extern "C" void kernel_launch(void* const* d_in, const int* in_sizes, int n_in,
                              void* d_out, int out_size, void* d_ws, size_t ws_size,
                              hipStream_t stream){
  const float* f    = (const float*)d_in[0];
  const float* b    = (const float*)d_in[1];
  const float* mask = (const float*)d_in[2];
  const float* fa_wq=(const float*)d_in[3];  const float* fa_bq=(const float*)d_in[4];
  const float* fa_wk=(const float*)d_in[5];  const float* fa_bk=(const float*)d_in[6];
  const float* fa_wv=(const float*)d_in[7];  const float* fa_bv=(const float*)d_in[8];
  const float* fa_g =(const float*)d_in[9];
  const float* pa_wq=(const float*)d_in[10]; const float* pa_bq=(const float*)d_in[11];
  const float* pa_wk=(const float*)d_in[12]; const float* pa_bk=(const float*)d_in[13];
  const float* pa_wv=(const float*)d_in[14]; const float* pa_bv=(const float*)d_in[15];
  const float* pa_g =(const float*)d_in[16];
  float* out = (float*)d_out;
  float* ws  = (float*)d_ws;
  if(ws_size < TOTAL_F*sizeof(float)) return;

  float* maskds = ws + O_MASKDS;
  float* mm     = ws + O_MM;
  float* fds    = ws + O_FDS;
  float* bds    = ws + O_BDS;
  float* qf     = ws + O_QF;
  float* kf     = ws + O_KF;
  float* vf     = ws + O_VF;
  float* fp     = ws + O_FP;
  float* win    = ws + O_WIN;
  float* bcol   = ws + O_BCOL;
  float* big0   = ws + O_BIG0;
  float* big1   = ws + O_BIG1;
  float* U      = ws + O_U;
  float* b4m    = ws + O_B4;
  float* Gb     = ws + O_G;
  float* pmax   = ws + O_PMAX;
  float* psum   = ws + O_PSUM;
  float* cmax   = ws + O_CMAX;
  float* cinv   = ws + O_CINV;

  k_prep_mask<<<9, 256, 0, stream>>>(mask, maskds, mm);

  for(int s=0; s<2; s++){
    k_ds<<<CDIV(NC*NB,256), 256, 0, stream>>>(f, fds, s);
    k_ds<<<CDIV(NC*NB,256), 256, 0, stream>>>(b, bds, s);

    // Stage A: patch attention -> normalized filters wi_n
    k_patch_attn<<<NB, 64, 0, stream>>>(fds, bds, maskds,
        pa_wq, pa_bq, pa_wk, pa_bk, pa_wv, pa_bv, pa_g, win);

    // Stage B: full global attention -> fp
    k_conv1x1<<<dim3(4,9,3), 256, 0, stream>>>(fds, bds,
        fa_wq, fa_bq, fa_wk, fa_bk, fa_wv, fa_bv, qf, kf, vf);
    k_simgemm<<<dim3(72,72), 256, 0, stream>>>(qf, kf, big0);
    k_rowsm<<<NB, 256, 0, stream>>>(big0, maskds, big1);
    k_attn_apply<<<dim3(72,4), 256, 0, stream>>>(vf, big1, bcol);   // partials in bcol
    k_fp<<<CDIV(NC*NB,256), 256, 0, stream>>>(bcol, fds, maskds, fa_g, fp);

    // Stage C: correlation GEMM score0 = wi_n @ im2col(fp)
    k_bcol<<<CDIV(576*NB,256), 256, 0, stream>>>(fp, bcol);
    k_gemm<<<dim3(36,36), 256, 0, stream>>>(win, bcol, big0, NB, NB, 576);

    // Stage D: two diagonal fuse passes
    k_fuse1<<<20737, 256, 0, stream>>>(big0, big1);
    k_fuse2<<<20737, 256, 0, stream>>>(big1, big0);

    // Stage E: column softmax over patches with mm gating
    k_colsm_partial<<<dim3(9,16), 256, 0, stream>>>(big0, mm, pmax, psum);
    k_colsm_combine<<<9, 256, 0, stream>>>(pmax, psum, cmax, cinv);
    k_colsm_apply<<<20737, 256, 0, stream>>>(big0, mm, cmax, cinv, big1);

    // Stage F: conv-transpose via phase decomposition (U-form)
    k_zbuild<<<CDIV((int)((size_t)NP*NP),256)+1, 256, 0, stream>>>(big1, U);
    k_b4<<<CDIV(256*NP,256), 256, 0, stream>>>(b, b4m, s);
    k_gemm<<<dim3(CDIV(NP,64),4), 256, 0, stream>>>(b4m, U, Gb, 256, NP, NP);
    k_epi<<<CDIV(NC*IMG*IMG,256), 256, 0, stream>>>(Gb, out, s);
  }
}

// Round 3
// 890.151 us; speedup vs baseline: 2.0436x; 2.0436x over previous
//
#include <hip/hip_runtime.h>
#include <math.h>

#define HD 48
#define NB 2304      // 48*48
#define NC 64
#define IMG 96
#define NP 2401      // 49*49
#define KP 2432      // NP padded to mult of 32

#define CDIV(a,b) (((a)+(b)-1)/(b))

typedef unsigned short u16;
typedef __attribute__((ext_vector_type(8))) short  s16x8;
typedef __attribute__((ext_vector_type(8))) unsigned short u16x8;
typedef __attribute__((ext_vector_type(4))) float  f32x4;

// ---------------- workspace layout (float slots) ----------------
// small: maskds NB, mm NB, cmax NB, cinv NB, pmax 16NB, psum 16NB = 36*NB
constexpr size_t O_FDS  = (size_t)36*NB;
constexpr size_t O_BDS  = O_FDS + (size_t)NC*NB;
constexpr size_t O_QF   = O_BDS + (size_t)NC*NB;
constexpr size_t O_KF   = O_QF  + (size_t)NC*NB;
constexpr size_t O_VF   = O_KF  + (size_t)NC*NB;
constexpr size_t O_FP   = O_VF  + (size_t)NC*NB;
constexpr size_t O_BIG0 = O_FP  + (size_t)NC*NB;
constexpr size_t O_BIG1 = O_BIG0 + (size_t)NB*NB;
constexpr size_t O_TAIL = O_BIG1 + (size_t)NB*NB;
// UT (bf16 hi+lo, [NP][KP] each) starts at O_BIG1, spills into tail:
constexpr size_t UT_U16    = (size_t)NP*KP;            // per buffer
constexpr size_t UT_SPILLF = (2*UT_U16 + 1)/2 - (size_t)NB*NB;  // f-slots beyond big1
constexpr size_t O_B4   = O_TAIL + UT_SPILLF;          // b4 hi+lo: 2*256*KP u16 = 256*KP f
constexpr size_t O_G    = O_B4 + (size_t)256*KP;       // 256*NP f32
constexpr size_t TOTAL_F = O_G + (size_t)256*NP;

// ---------------- helpers ----------------
__device__ inline void split_bf16(float x, u16& hi, u16& lo){
  unsigned int u = __float_as_uint(x);
  unsigned int r = u + 0x7FFFu + ((u >> 16) & 1u);
  hi = (u16)(r >> 16);
  float xh = __uint_as_float(((unsigned int)hi) << 16);
  float res = x - xh;
  unsigned int u2 = __float_as_uint(res);
  unsigned int r2 = u2 + 0x7FFFu + ((u2 >> 16) & 1u);
  lo = (u16)(r2 >> 16);
}

// ---------------- kernels ----------------

__global__ void k_prep_mask(const float* __restrict__ mask, float* __restrict__ maskds,
                            float* __restrict__ mm){
  int q = blockIdx.x*256 + threadIdx.x;
  if(q >= NB) return;
  int hq = q/HD, wq = q%HD;
  maskds[q] = mask[(2*hq)*IMG + 2*wq];
  float any = 0.f;
  for(int u=-1;u<=1;u++)
    for(int v=-1;v<=1;v++){
      int y=hq+u, x=wq+v;
      if(y>=0&&y<HD&&x>=0&&x<HD) any += mask[(2*y)*IMG + 2*x];
    }
  mm[q] = (any == 0.f) ? 1.f : 0.f;
}

__global__ void k_ds(const float* __restrict__ src, float* __restrict__ dst, int s){
  int idx = blockIdx.x*256 + threadIdx.x;
  if(idx >= NC*NB) return;
  int c = idx/NB, j = idx%NB;
  int h = j/HD, w = j%HD;
  dst[idx] = src[(((size_t)s*NC + c)*IMG + 2*h)*IMG + 2*w];
}

// Stage A: per-patch attention + normalization -> A-hi/lo bf16 [p][c*9+i]
__global__ void k_patch_attn(const float* __restrict__ fds, const float* __restrict__ bds,
                             const float* __restrict__ maskds,
                             const float* __restrict__ wq, const float* __restrict__ bq,
                             const float* __restrict__ wk, const float* __restrict__ bk,
                             const float* __restrict__ wv, const float* __restrict__ bv,
                             const float* __restrict__ gammap,
                             u16* __restrict__ AH, u16* __restrict__ AL){
  __shared__ float A[64][9], Bm[64][9], Q[64][9], K[64][9], V[64][9];
  __shared__ float attn[9][9];
  __shared__ float mval[9];
  int p = blockIdx.x;
  int ph = p/HD, pw = p%HD;
  int c = threadIdx.x;
  for(int i=0;i<9;i++){
    int u=i/3, v=i%3;
    int y=ph+u-1, x=pw+v-1;
    bool in = (y>=0&&y<HD&&x>=0&&x<HD);
    float fv = in ? fds[c*NB + y*HD + x] : 0.f;
    float bvv= in ? bds[c*NB + y*HD + x] : 0.f;
    A[c][i] = fv;  Bm[c][i] = bvv;
    if(c==0) mval[i] = in ? maskds[y*HD + x] : 0.f;
  }
  __syncthreads();
  float qr[9]={}, kr[9]={}, vr[9]={};
  for(int cc=0;cc<64;cc++){
    float wqv = wq[c*64+cc], wkv = wk[c*64+cc], wvv = wv[c*64+cc];
    #pragma unroll
    for(int i=0;i<9;i++){
      qr[i] += wqv*A[cc][i];
      kr[i] += wkv*Bm[cc][i];
      vr[i] += wvv*A[cc][i];
    }
  }
  float bqv=bq[c], bkv=bk[c], bvv2=bv[c];
  #pragma unroll
  for(int i=0;i<9;i++){ Q[c][i]=qr[i]+bqv; K[c][i]=kr[i]+bkv; V[c][i]=vr[i]+bvv2; }
  __syncthreads();
  if(c<9){
    int i = c;
    float mv = mval[i];
    float L[9];
    for(int j=0;j<9;j++){
      float sacc = 0.f;
      for(int cc=0;cc<64;cc++) sacc += Q[cc][i]*K[cc][j];
      L[j] = sacc*mv;
    }
    float mx = L[0];
    for(int j=1;j<9;j++) mx = fmaxf(mx, L[j]);
    float sum = 0.f;
    for(int j=0;j<9;j++){ L[j] = expf(L[j]-mx); sum += L[j]; }
    float inv = 1.f/sum;
    for(int j=0;j<9;j++) attn[i][j] = L[j]*inv;
  }
  __syncthreads();
  float gamma = gammap[0];
  float fpv[9];
  float ss = 0.f;
  #pragma unroll
  for(int i=0;i<9;i++){
    float o = 0.f;
    #pragma unroll
    for(int j=0;j<9;j++) o += V[c][j]*attn[i][j];
    float mv = mval[i];
    float val = gamma*A[c][i]*mv + (1.f-mv)*o;
    fpv[i] = val;
    ss += val*val;
  }
  for(int off=32; off>0; off>>=1) ss += __shfl_down(ss, off);
  ss = __shfl(ss, 0);
  float scale = 1.f / fmaxf(sqrtf(ss), 1e-4f);
  #pragma unroll
  for(int i=0;i<9;i++){
    u16 h,l; split_bf16(fpv[i]*scale, h, l);
    size_t o = (size_t)p*576 + c*9 + i;
    AH[o] = h; AL[o] = l;
  }
}

__global__ void k_conv1x1(const float* __restrict__ fds, const float* __restrict__ bds,
                          const float* __restrict__ wq, const float* __restrict__ bq,
                          const float* __restrict__ wk, const float* __restrict__ bk,
                          const float* __restrict__ wv, const float* __restrict__ bv,
                          float* __restrict__ qf, float* __restrict__ kf, float* __restrict__ vf){
  int m = blockIdx.z;
  const float* W    = (m==0)? wq : (m==1? wk : wv);
  const float* bias = (m==0)? bq : (m==1? bk : bv);
  const float* src  = (m==1)? bds : fds;
  float* dst        = (m==0)? qf : (m==1? kf : vf);
  __shared__ float Wl[16][64];
  int o0 = blockIdx.x*16;
  int j  = blockIdx.y*256 + threadIdx.x;
  for(int t=threadIdx.x; t<16*64; t+=256) Wl[t>>6][t&63] = W[(o0 + (t>>6))*64 + (t&63)];
  __syncthreads();
  float acc[16]={};
  for(int c=0;c<64;c++){
    float xv = src[c*NB + j];
    #pragma unroll
    for(int oo=0;oo<16;oo++) acc[oo] += Wl[oo][c]*xv;
  }
  for(int oo=0;oo<16;oo++) dst[(size_t)(o0+oo)*NB + j] = acc[oo] + bias[o0+oo];
}

__global__ void k_simgemm(const float* __restrict__ Amat, const float* __restrict__ Bmat,
                          float* __restrict__ Cm){
  __shared__ float At[64][32], Bt2[64][32];
  int i0 = blockIdx.y*32, j0 = blockIdx.x*32;
  int tid = threadIdx.x;
  for(int t=tid; t<2048; t+=256){
    int cc=t>>5, xx=t&31;
    At[cc][xx]  = Amat[cc*NB + i0+xx];
    Bt2[cc][xx] = Bmat[cc*NB + j0+xx];
  }
  __syncthreads();
  int ti = tid>>4, tj = tid&15;
  float a00=0,a01=0,a10=0,a11=0;
  for(int cc=0;cc<64;cc++){
    float x0=At[cc][ti*2], x1=At[cc][ti*2+1];
    float y0=Bt2[cc][tj*2], y1=Bt2[cc][tj*2+1];
    a00+=x0*y0; a01+=x0*y1; a10+=x1*y0; a11+=x1*y1;
  }
  size_t r0=(size_t)(i0+ti*2)*NB + j0+tj*2;
  Cm[r0]=a00; Cm[r0+1]=a01; Cm[r0+NB]=a10; Cm[r0+NB+1]=a11;
}

__global__ void k_rowsm(const float* __restrict__ sim, const float* __restrict__ maskds,
                        float* __restrict__ attn){
  int i = blockIdx.x;
  float mv = maskds[i];
  const float* row = sim + (size_t)i*NB;
  float* orow = attn + (size_t)i*NB;
  __shared__ float red[8];
  int tid = threadIdx.x;
  float mx = -1e30f;
  for(int j=tid;j<NB;j+=256) mx = fmaxf(mx, row[j]*mv);
  for(int off=32;off>0;off>>=1) mx = fmaxf(mx, __shfl_down(mx,off));
  if((tid&63)==0) red[tid>>6]=mx;
  __syncthreads();
  mx = fmaxf(fmaxf(red[0],red[1]),fmaxf(red[2],red[3]));
  float sum=0.f;
  for(int j=tid;j<NB;j+=256){ float e = expf(row[j]*mv - mx); orow[j]=e; sum+=e; }
  for(int off=32;off>0;off>>=1) sum += __shfl_down(sum,off);
  if((tid&63)==0) red[4+(tid>>6)]=sum;
  __syncthreads();
  sum = red[4]+red[5]+red[6]+red[7];
  float inv = 1.f/sum;
  for(int j=tid;j<NB;j+=256) orow[j] *= inv;
}

__global__ void k_attn_apply(const float* __restrict__ vf, const float* __restrict__ attn,
                             float* __restrict__ part){
  int i0 = blockIdx.x*32;
  int ks = blockIdx.y;
  __shared__ float Vt[64][33];
  __shared__ float At[32][33];
  int tid = threadIdx.x;
  int il = tid&31, cg = tid>>5;
  float acc[8]={};
  for(int k0=ks*576; k0<ks*576+576; k0+=32){
    for(int t=tid;t<2048;t+=256){ int c=t>>5, j=t&31; Vt[c][j]=vf[c*NB + k0+j]; }
    for(int t=tid;t<1024;t+=256){ int i=t>>5, j=t&31; At[i][j]=attn[(size_t)(i0+i)*NB + k0+j]; }
    __syncthreads();
    for(int j=0;j<32;j++){
      float a = At[il][j];
      #pragma unroll
      for(int q=0;q<8;q++) acc[q] += Vt[cg*8+q][j]*a;
    }
    __syncthreads();
  }
  #pragma unroll
  for(int q=0;q<8;q++) part[(size_t)(ks*64 + cg*8+q)*NB + i0+il] = acc[q];
}

__global__ void k_fp(const float* __restrict__ part, const float* __restrict__ fds,
                     const float* __restrict__ maskds, const float* __restrict__ gammap,
                     float* __restrict__ fp){
  int idx = blockIdx.x*256 + threadIdx.x;
  if(idx >= NC*NB) return;
  int i = idx%NB;
  float o = part[idx] + part[(size_t)NC*NB + idx] + part[(size_t)2*NC*NB + idx] + part[(size_t)3*NC*NB + idx];
  float mv = maskds[i];
  fp[idx] = gammap[0]*fds[idx]*mv + (1.f-mv)*o;
}

// bcol^T split: BT[P][k=(c,u,v)] = fp[c][neighbor(P,(u,v))], bf16 hi/lo
__global__ void k_bcolT_split(const float* __restrict__ fp,
                              u16* __restrict__ BTH, u16* __restrict__ BTL){
  int idx = blockIdx.x*256 + threadIdx.x;
  if(idx >= NB*576) return;
  int P = idx/576, k = idx%576;
  int c = k/9, i = k%9, u = i/3, v = i%3;
  int hP = P/HD, wP = P%HD;
  int y = hP+u-1, x = wP+v-1;
  float val = (y>=0&&y<HD&&x>=0&&x<HD) ? fp[c*NB + y*HD + x] : 0.f;
  u16 h,l; split_bf16(val, h, l);
  BTH[idx] = h; BTL[idx] = l;
}

// ---------------- MFMA bf16x3 GEMM ----------------
// C[M][N](f32, ldC) = (AH+AL)[M][K](ldA) @ (BH+BL)^T where BT[n][k](ldB).
// K must be a multiple of 32 (pad with zeros). Tiles 128x128, BK=32, 4 waves.
__global__ __launch_bounds__(256)
void k_gemm_mfma(const u16* __restrict__ AH, const u16* __restrict__ AL,
                 const u16* __restrict__ BTH, const u16* __restrict__ BTL,
                 float* __restrict__ C, int M, int N, int K,
                 int ldA, int ldB, int ldC){
  __shared__ u16 lAH[128][40], lAL[128][40], lBH[128][40], lBL[128][40];
  int tid = threadIdx.x;
  int m0 = blockIdx.y*128, n0 = blockIdx.x*128;
  int w = tid>>6, lane = tid&63;
  int wr = w>>1, wc = w&1;
  int fr = lane&15, fq = lane>>4;
  f32x4 acc[4][4];
  #pragma unroll
  for(int i=0;i<4;i++)
    #pragma unroll
    for(int j=0;j<4;j++) acc[i][j] = (f32x4){0.f,0.f,0.f,0.f};

  int srow = tid>>1;            // 0..127
  int shalf = (tid&1)*16;       // element offset 0 or 16

  for(int k0=0; k0<K; k0+=32){
    // stage A tiles
    {
      int ar = m0 + srow;
      u16x8 z = (u16x8)(u16)0;
      u16x8 h0=z,h1=z,l0=z,l1=z;
      if(ar < M){
        size_t o = (size_t)ar*ldA + k0 + shalf;
        h0 = *(const u16x8*)&AH[o];   h1 = *(const u16x8*)&AH[o+8];
        l0 = *(const u16x8*)&AL[o];   l1 = *(const u16x8*)&AL[o+8];
      }
      *(u16x8*)&lAH[srow][shalf]   = h0;  *(u16x8*)&lAH[srow][shalf+8] = h1;
      *(u16x8*)&lAL[srow][shalf]   = l0;  *(u16x8*)&lAL[srow][shalf+8] = l1;
      int br = n0 + srow;
      h0=z; h1=z; l0=z; l1=z;
      if(br < N){
        size_t o = (size_t)br*ldB + k0 + shalf;
        h0 = *(const u16x8*)&BTH[o];  h1 = *(const u16x8*)&BTH[o+8];
        l0 = *(const u16x8*)&BTL[o];  l1 = *(const u16x8*)&BTL[o+8];
      }
      *(u16x8*)&lBH[srow][shalf]   = h0;  *(u16x8*)&lBH[srow][shalf+8] = h1;
      *(u16x8*)&lBL[srow][shalf]   = l0;  *(u16x8*)&lBL[srow][shalf+8] = l1;
    }
    __syncthreads();
    s16x8 ah[4], al[4], bh[4], bl[4];
    #pragma unroll
    for(int mi=0;mi<4;mi++){
      ah[mi] = *(const s16x8*)&lAH[wr*64 + mi*16 + fr][fq*8];
      al[mi] = *(const s16x8*)&lAL[wr*64 + mi*16 + fr][fq*8];
    }
    #pragma unroll
    for(int ni=0;ni<4;ni++){
      bh[ni] = *(const s16x8*)&lBH[wc*64 + ni*16 + fr][fq*8];
      bl[ni] = *(const s16x8*)&lBL[wc*64 + ni*16 + fr][fq*8];
    }
    #pragma unroll
    for(int mi=0;mi<4;mi++)
      #pragma unroll
      for(int ni=0;ni<4;ni++){
        acc[mi][ni] = __builtin_amdgcn_mfma_f32_16x16x32_bf16(ah[mi], bh[ni], acc[mi][ni], 0,0,0);
        acc[mi][ni] = __builtin_amdgcn_mfma_f32_16x16x32_bf16(ah[mi], bl[ni], acc[mi][ni], 0,0,0);
        acc[mi][ni] = __builtin_amdgcn_mfma_f32_16x16x32_bf16(al[mi], bh[ni], acc[mi][ni], 0,0,0);
      }
    __syncthreads();
  }
  // epilogue: C/D layout col=lane&15, row=(lane>>4)*4+reg
  #pragma unroll
  for(int mi=0;mi<4;mi++)
    #pragma unroll
    for(int ni=0;ni<4;ni++){
      int row = m0 + wr*64 + mi*16 + fq*4;
      int col = n0 + wc*64 + ni*16 + fr;
      if(col < N){
        #pragma unroll
        for(int r=0;r<4;r++)
          if(row+r < M) C[(size_t)(row+r)*ldC + col] = acc[mi][ni][r];
      }
    }
}

__global__ void k_fuse1(const float* __restrict__ in, float* __restrict__ out){
  size_t idx = (size_t)blockIdx.x*256 + threadIdx.x;
  if(idx >= (size_t)NB*NB) return;
  int q = (int)(idx/NB), P = (int)(idx%NB);
  float s = in[idx];
  if(q>0 && P>0)       s += in[idx - NB - 1];
  if(q<NB-1 && P<NB-1) s += in[idx + NB + 1];
  out[idx] = s;
}

__global__ void k_fuse2(const float* __restrict__ in, float* __restrict__ out){
  size_t idx = (size_t)blockIdx.x*256 + threadIdx.x;
  if(idx >= (size_t)NB*NB) return;
  int q = (int)(idx/NB), P = (int)(idx%NB);
  int hq=q/HD, wq=q%HD, hP=P/HD, wP=P%HD;
  int qw = wq*HD + hq, Pw = wP*HD + hP;
  float s = 0.f;
  #pragma unroll
  for(int d=-1;d<=1;d++){
    int qd = qw+d, Pd = Pw+d;
    if(qd>=0 && qd<NB && Pd>=0 && Pd<NB){
      int q2 = (qd%HD)*HD + qd/HD;
      int P2 = (Pd%HD)*HD + Pd/HD;
      s += in[(size_t)q2*NB + P2];
    }
  }
  out[idx] = s;
}

__global__ void k_colsm_partial(const float* __restrict__ sc, const float* __restrict__ mm,
                                float* __restrict__ pmax, float* __restrict__ psum){
  int col = blockIdx.x*256 + threadIdx.x;
  int q0 = blockIdx.y*144;
  float mx = -1e30f, sum = 0.f;
  for(int q=q0; q<q0+144; q++){
    float L = (mm[q]!=0.f) ? 10.f*sc[(size_t)q*NB + col] : 0.f;
    if(L > mx){ sum *= expf(mx - L); mx = L; }
    sum += expf(L - mx);
  }
  pmax[blockIdx.y*NB + col] = mx;
  psum[blockIdx.y*NB + col] = sum;
}

__global__ void k_colsm_combine(const float* __restrict__ pmax, const float* __restrict__ psum,
                                float* __restrict__ cmax, float* __restrict__ cinv){
  int col = blockIdx.x*256 + threadIdx.x;
  if(col >= NB) return;
  float M = -1e30f;
  for(int k=0;k<16;k++) M = fmaxf(M, pmax[k*NB+col]);
  float S = 0.f;
  for(int k=0;k<16;k++) S += psum[k*NB+col]*expf(pmax[k*NB+col]-M);
  cmax[col] = M;
  cinv[col] = 1.f/S;
}

__global__ void k_colsm_apply(const float* __restrict__ sc, const float* __restrict__ mm,
                              const float* __restrict__ cmax, const float* __restrict__ cinv,
                              float* __restrict__ yi){
  size_t idx = (size_t)blockIdx.x*256 + threadIdx.x;
  if(idx >= (size_t)NB*NB) return;
  int q = (int)(idx/NB), P = (int)(idx%NB);
  yi[idx] = (mm[q]!=0.f) ? expf(10.f*sc[idx] - cmax[P])*cinv[P] : 0.f;
}

// tiled fp32 transpose, n x n (n multiple of 32)
__global__ void k_transpose(const float* __restrict__ in, float* __restrict__ out, int n){
  __shared__ float tile[32][33];
  int bx = blockIdx.x*32, by = blockIdx.y*32;
  int tx = threadIdx.x & 31, ty = threadIdx.x >> 5;  // ty 0..7
  for(int r=ty; r<32; r+=8) tile[r][tx] = in[(size_t)(by+r)*n + bx+tx];
  __syncthreads();
  for(int r=ty; r<32; r+=8) out[(size_t)(bx+r)*n + by+tx] = tile[tx][r];
}

// U^T via stencil on yi^T, split bf16: UT[col'=(rho,sig)][pp], [NP][KP]
__global__ void k_zbuildT_split(const float* __restrict__ yiT,
                                u16* __restrict__ UTH, u16* __restrict__ UTL){
  int row = blockIdx.y;                       // 0..NP-1
  int cc  = blockIdx.x*256 + threadIdx.x;     // 0..KP-1
  if(cc >= KP) return;
  size_t o = (size_t)row*KP + cc;
  float z = 0.f;
  if(cc < NP){
    int rho = row/49, sig = row%49;
    int ph = cc/49, pw = cc%49;
    #pragma unroll
    for(int a=0;a<2;a++)
      #pragma unroll
      for(int bb=0;bb<2;bb++){
        int sh=ph-a, sw=pw-bb, rr=rho-a, ss=sig-bb;
        if(sh>=0 && sh<HD && sw>=0 && sw<HD && rr>=0 && rr<HD && ss>=0 && ss<HD)
          z += yiT[(size_t)(rr*HD+ss)*NB + sh*HD+sw];
      }
  }
  u16 h,l; split_bf16(z, h, l);
  UTH[o] = h; UTL[o] = l;
}

// phase-gathered b split: b4[m=(phase*64+c)][kk=pp], [256][KP]
__global__ void k_b4_split(const float* __restrict__ b,
                           u16* __restrict__ B4H, u16* __restrict__ B4L, int s){
  int idx = blockIdx.x*256 + threadIdx.x;
  if(idx >= 256*KP) return;
  int m = idx/KP, kk = idx%KP;
  float val = 0.f;
  if(kk < NP){
    int phase = m>>6, c = m&63;
    int py = phase>>1, px = phase&1;
    int ph = kk/49, pw = kk%49;
    int y = 2*ph - py, x = 2*pw - px;
    if(y>=0&&y<IMG&&x>=0&&x<IMG) val = b[(((size_t)s*NC + c)*IMG + y)*IMG + x];
  }
  u16 h,l; split_bf16(val, h, l);
  B4H[idx] = h; B4L[idx] = l;
}

__global__ void k_epi(const float* __restrict__ G, float* __restrict__ out, int s){
  int idx = blockIdx.x*256 + threadIdx.x;
  if(idx >= NC*IMG*IMG) return;
  int c = idx/(IMG*IMG), rem = idx%(IMG*IMG);
  int y = rem/IMG, x = rem%IMG;
  int py = y&1, px = x&1, r = y>>1, s2 = x>>1;
  out[((size_t)s*NC + c)*IMG*IMG + rem] =
      G[(size_t)((py*2+px)*64 + c)*NP + (r+py)*49 + (s2+px)] * 0.25f;
}

// ---------------- launcher ----------------
extern "C" void kernel_launch(void* const* d_in, const int* in_sizes, int n_in,
                              void* d_out, int out_size, void* d_ws, size_t ws_size,
                              hipStream_t stream){
  const float* f    = (const float*)d_in[0];
  const float* b    = (const float*)d_in[1];
  const float* mask = (const float*)d_in[2];
  const float* fa_wq=(const float*)d_in[3];  const float* fa_bq=(const float*)d_in[4];
  const float* fa_wk=(const float*)d_in[5];  const float* fa_bk=(const float*)d_in[6];
  const float* fa_wv=(const float*)d_in[7];  const float* fa_bv=(const float*)d_in[8];
  const float* fa_g =(const float*)d_in[9];
  const float* pa_wq=(const float*)d_in[10]; const float* pa_bq=(const float*)d_in[11];
  const float* pa_wk=(const float*)d_in[12]; const float* pa_bk=(const float*)d_in[13];
  const float* pa_wv=(const float*)d_in[14]; const float* pa_bv=(const float*)d_in[15];
  const float* pa_g =(const float*)d_in[16];
  float* out = (float*)d_out;
  float* ws  = (float*)d_ws;
  if(ws_size < TOTAL_F*sizeof(float)) return;

  float* maskds = ws;
  float* mm     = ws + NB;
  float* cmax   = ws + 2*NB;
  float* cinv   = ws + 3*NB;
  float* pmax   = ws + 4*NB;
  float* psum   = ws + 20*NB;
  float* fds = ws + O_FDS;
  float* bds = ws + O_BDS;
  float* qf  = ws + O_QF;
  float* kf  = ws + O_KF;
  float* vf  = ws + O_VF;
  float* fp  = ws + O_FP;
  float* big0 = ws + O_BIG0;
  float* big1 = ws + O_BIG1;
  float* part = ws + O_TAIL;                 // stage-B partials (temporal)
  // stage-C split buffers live inside big1 (dead region at that point)
  u16* AH  = (u16*)big1;
  u16* AL  = AH  + (size_t)NB*576;
  u16* BTH = AL  + (size_t)NB*576;
  u16* BTL = BTH + (size_t)NB*576;
  // stage-F UT lives at big1 start, spilling into tail
  u16* UTH = (u16*)big1;
  u16* UTL = UTH + UT_U16;
  u16* B4H = (u16*)(ws + O_B4);
  u16* B4L = B4H + (size_t)256*KP;
  float* G = ws + O_G;

  k_prep_mask<<<9, 256, 0, stream>>>(mask, maskds, mm);

  for(int s=0; s<2; s++){
    k_ds<<<CDIV(NC*NB,256), 256, 0, stream>>>(f, fds, s);
    k_ds<<<CDIV(NC*NB,256), 256, 0, stream>>>(b, bds, s);

    // Stage B: full global attention -> fp (uses big0=sim, big1=attn, part)
    k_conv1x1<<<dim3(4,9,3), 256, 0, stream>>>(fds, bds,
        fa_wq, fa_bq, fa_wk, fa_bk, fa_wv, fa_bv, qf, kf, vf);
    k_simgemm<<<dim3(72,72), 256, 0, stream>>>(qf, kf, big0);
    k_rowsm<<<NB, 256, 0, stream>>>(big0, maskds, big1);
    k_attn_apply<<<dim3(72,4), 256, 0, stream>>>(vf, big1, part);
    k_fp<<<CDIV(NC*NB,256), 256, 0, stream>>>(part, fds, maskds, fa_g, fp);

    // Stage A (after B: big1 free): patch attention -> A-hi/lo
    k_patch_attn<<<NB, 64, 0, stream>>>(fds, bds, maskds,
        pa_wq, pa_bq, pa_wk, pa_bk, pa_wv, pa_bv, pa_g, AH, AL);

    // Stage C: scores = wi_n @ im2col(fp)  (MFMA bf16x3)
    k_bcolT_split<<<CDIV(NB*576,256), 256, 0, stream>>>(fp, BTH, BTL);
    k_gemm_mfma<<<dim3(18,18), 256, 0, stream>>>(AH, AL, BTH, BTL, big0,
        NB, NB, 576, 576, 576, NB);

    // Stage D: two diagonal fuse passes
    k_fuse1<<<20736, 256, 0, stream>>>(big0, big1);
    k_fuse2<<<20736, 256, 0, stream>>>(big1, big0);

    // Stage E: column softmax with mm gating -> yi (big1)
    k_colsm_partial<<<dim3(9,16), 256, 0, stream>>>(big0, mm, pmax, psum);
    k_colsm_combine<<<9, 256, 0, stream>>>(pmax, psum, cmax, cinv);
    k_colsm_apply<<<20736, 256, 0, stream>>>(big0, mm, cmax, cinv, big1);

    // Stage F: yi^T -> U^T (bf16 split) -> G = b4 @ U
    k_transpose<<<dim3(72,72), 256, 0, stream>>>(big1, big0, NB);       // yiT in big0
    k_zbuildT_split<<<dim3(CDIV(KP,256), NP), 256, 0, stream>>>(big0, UTH, UTL);
    k_b4_split<<<CDIV(256*KP,256), 256, 0, stream>>>(b, B4H, B4L, s);
    k_gemm_mfma<<<dim3(CDIV(NP,128), 2), 256, 0, stream>>>(B4H, B4L, UTH, UTL, G,
        256, NP, KP, KP, KP, NP);
    k_epi<<<CDIV(NC*IMG*IMG,256), 256, 0, stream>>>(G, out, s);
  }
}

// Round 4
// 772.534 us; speedup vs baseline: 2.3547x; 1.1522x over previous
//
#include <hip/hip_runtime.h>
#include <math.h>

#define HD 48
#define NB 2304      // 48*48
#define NC 64
#define IMG 96
#define NP 2401      // 49*49
#define KP 2432      // NP padded to mult of 32

#define CDIV(a,b) (((a)+(b)-1)/(b))

typedef unsigned short u16;
typedef __attribute__((ext_vector_type(8))) short  s16x8;
typedef __attribute__((ext_vector_type(8))) unsigned short u16x8;
typedef __attribute__((ext_vector_type(4))) float  f32x4;

// ---------------- workspace layout (float slots) ----------------
// smalls: maskds NB, mm NB, mmP NB, cmax NB, cinv NB, pmax 16NB, psum 16NB = 37NB
constexpr size_t SZ = (size_t)NC*NB;
constexpr size_t O_FDS  = (size_t)37*NB;
constexpr size_t O_BDS  = O_FDS + SZ;
constexpr size_t O_QF   = O_BDS + SZ;
constexpr size_t O_KF   = O_QF  + SZ;
constexpr size_t O_VF   = O_KF  + SZ;
constexpr size_t O_FP   = O_VF  + SZ;
constexpr size_t O_BIG0 = O_FP  + SZ;
constexpr size_t O_BIG1 = O_BIG0 + (size_t)NB*NB;
constexpr size_t O_BIG2 = O_BIG1 + (size_t)NB*NB;
constexpr size_t TOTAL_F = O_BIG2 + (size_t)NB*NB;   // ~16.9M floats ~67.6MB
// stage-F sub-layout inside big1/big2:
constexpr size_t UT_SPILLF = ((size_t)NP*KP) - (size_t)NB*NB;  // f32 slots of UT beyond big1
constexpr size_t O_B4 = O_BIG2 + UT_SPILLF;                    // B4H+B4L: 2*256*KP u16 = 311296 f
constexpr size_t O_G  = O_B4 + (size_t)256*KP/2*2;             // 4 partials * 256*NP f32

// ---------------- helpers ----------------
__device__ inline void split_bf16(float x, u16& hi, u16& lo){
  unsigned int u = __float_as_uint(x);
  unsigned int r = u + 0x7FFFu + ((u >> 16) & 1u);
  hi = (u16)(r >> 16);
  float xh = __uint_as_float(((unsigned int)hi) << 16);
  float res = x - xh;
  unsigned int u2 = __float_as_uint(res);
  unsigned int r2 = u2 + 0x7FFFu + ((u2 >> 16) & 1u);
  lo = (u16)(r2 >> 16);
}

// ---------------- kernels ----------------

__global__ void k_prep_mask(const float* __restrict__ mask, float* __restrict__ maskds,
                            float* __restrict__ mm, float* __restrict__ mmP){
  int q = blockIdx.x*256 + threadIdx.x;
  if(q >= NB) return;
  int hq = q/HD, wq = q%HD;
  maskds[q] = mask[(2*hq)*IMG + 2*wq];
  float any = 0.f;
  for(int u=-1;u<=1;u++)
    for(int v=-1;v<=1;v++){
      int y=hq+u, x=wq+v;
      if(y>=0&&y<HD&&x>=0&&x<HD) any += mask[(2*y)*IMG + 2*x];
    }
  float v = (any == 0.f) ? 1.f : 0.f;
  mm[q] = v;
  mmP[wq*HD + hq] = v;
}

__global__ void k_ds(const float* __restrict__ src, float* __restrict__ dst, int s){
  int idx = blockIdx.x*256 + threadIdx.x;
  if(idx >= NC*NB) return;
  int c = idx/NB, j = idx%NB;
  int h = j/HD, w = j%HD;
  dst[idx] = src[(((size_t)s*NC + c)*IMG + 2*h)*IMG + 2*w];
}

// Stage A: per-patch attention + normalization -> A-hi/lo bf16 [p][c*9+i]
__global__ void k_patch_attn(const float* __restrict__ fds, const float* __restrict__ bds,
                             const float* __restrict__ maskds,
                             const float* __restrict__ wq, const float* __restrict__ bq,
                             const float* __restrict__ wk, const float* __restrict__ bk,
                             const float* __restrict__ wv, const float* __restrict__ bv,
                             const float* __restrict__ gammap,
                             u16* __restrict__ AH, u16* __restrict__ AL){
  __shared__ float A[64][9], Bm[64][9], Q[64][9], K[64][9], V[64][9];
  __shared__ float attn[9][9];
  __shared__ float mval[9];
  int p = blockIdx.x;
  int ph = p/HD, pw = p%HD;
  int c = threadIdx.x;
  for(int i=0;i<9;i++){
    int u=i/3, v=i%3;
    int y=ph+u-1, x=pw+v-1;
    bool in = (y>=0&&y<HD&&x>=0&&x<HD);
    float fv = in ? fds[c*NB + y*HD + x] : 0.f;
    float bvv= in ? bds[c*NB + y*HD + x] : 0.f;
    A[c][i] = fv;  Bm[c][i] = bvv;
    if(c==0) mval[i] = in ? maskds[y*HD + x] : 0.f;
  }
  __syncthreads();
  float qr[9]={}, kr[9]={}, vr[9]={};
  for(int cc=0;cc<64;cc++){
    float wqv = wq[c*64+cc], wkv = wk[c*64+cc], wvv = wv[c*64+cc];
    #pragma unroll
    for(int i=0;i<9;i++){
      qr[i] += wqv*A[cc][i];
      kr[i] += wkv*Bm[cc][i];
      vr[i] += wvv*A[cc][i];
    }
  }
  float bqv=bq[c], bkv=bk[c], bvv2=bv[c];
  #pragma unroll
  for(int i=0;i<9;i++){ Q[c][i]=qr[i]+bqv; K[c][i]=kr[i]+bkv; V[c][i]=vr[i]+bvv2; }
  __syncthreads();
  if(c<9){
    int i = c;
    float mv = mval[i];
    float L[9];
    for(int j=0;j<9;j++){
      float sacc = 0.f;
      for(int cc=0;cc<64;cc++) sacc += Q[cc][i]*K[cc][j];
      L[j] = sacc*mv;
    }
    float mx = L[0];
    for(int j=1;j<9;j++) mx = fmaxf(mx, L[j]);
    float sum = 0.f;
    for(int j=0;j<9;j++){ L[j] = expf(L[j]-mx); sum += L[j]; }
    float inv = 1.f/sum;
    for(int j=0;j<9;j++) attn[i][j] = L[j]*inv;
  }
  __syncthreads();
  float gamma = gammap[0];
  float fpv[9];
  float ss = 0.f;
  #pragma unroll
  for(int i=0;i<9;i++){
    float o = 0.f;
    #pragma unroll
    for(int j=0;j<9;j++) o += V[c][j]*attn[i][j];
    float mv = mval[i];
    float val = gamma*A[c][i]*mv + (1.f-mv)*o;
    fpv[i] = val;
    ss += val*val;
  }
  for(int off=32; off>0; off>>=1) ss += __shfl_down(ss, off);
  ss = __shfl(ss, 0);
  float scale = 1.f / fmaxf(sqrtf(ss), 1e-4f);
  #pragma unroll
  for(int i=0;i<9;i++){
    u16 h,l; split_bf16(fpv[i]*scale, h, l);
    size_t o = (size_t)p*576 + c*9 + i;
    AH[o] = h; AL[o] = l;
  }
}

__global__ void k_conv1x1(const float* __restrict__ fds, const float* __restrict__ bds,
                          const float* __restrict__ wq, const float* __restrict__ bq,
                          const float* __restrict__ wk, const float* __restrict__ bk,
                          const float* __restrict__ wv, const float* __restrict__ bv,
                          float* __restrict__ qf, float* __restrict__ kf, float* __restrict__ vf){
  int m = blockIdx.z;
  const float* W    = (m==0)? wq : (m==1? wk : wv);
  const float* bias = (m==0)? bq : (m==1? bk : bv);
  const float* src  = (m==1)? bds : fds;
  float* dst        = (m==0)? qf : (m==1? kf : vf);
  __shared__ float Wl[16][64];
  int o0 = blockIdx.x*16;
  int j  = blockIdx.y*256 + threadIdx.x;
  for(int t=threadIdx.x; t<16*64; t+=256) Wl[t>>6][t&63] = W[(o0 + (t>>6))*64 + (t&63)];
  __syncthreads();
  float acc[16]={};
  for(int c=0;c<64;c++){
    float xv = src[c*NB + j];
    #pragma unroll
    for(int oo=0;oo<16;oo++) acc[oo] += Wl[oo][c]*xv;
  }
  for(int oo=0;oo<16;oo++) dst[(size_t)(o0+oo)*NB + j] = acc[oo] + bias[o0+oo];
}

__global__ void k_simgemm(const float* __restrict__ Amat, const float* __restrict__ Bmat,
                          float* __restrict__ Cm){
  __shared__ float At[64][32], Bt2[64][32];
  int i0 = blockIdx.y*32, j0 = blockIdx.x*32;
  int tid = threadIdx.x;
  for(int t=tid; t<2048; t+=256){
    int cc=t>>5, xx=t&31;
    At[cc][xx]  = Amat[cc*NB + i0+xx];
    Bt2[cc][xx] = Bmat[cc*NB + j0+xx];
  }
  __syncthreads();
  int ti = tid>>4, tj = tid&15;
  float a00=0,a01=0,a10=0,a11=0;
  for(int cc=0;cc<64;cc++){
    float x0=At[cc][ti*2], x1=At[cc][ti*2+1];
    float y0=Bt2[cc][tj*2], y1=Bt2[cc][tj*2+1];
    a00+=x0*y0; a01+=x0*y1; a10+=x1*y0; a11+=x1*y1;
  }
  size_t r0=(size_t)(i0+ti*2)*NB + j0+tj*2;
  Cm[r0]=a00; Cm[r0+1]=a01; Cm[r0+NB]=a10; Cm[r0+NB+1]=a11;
}

__global__ void k_rowsm(const float* __restrict__ sim, const float* __restrict__ maskds,
                        float* __restrict__ attn){
  int i = blockIdx.x;
  float mv = maskds[i];
  const float* row = sim + (size_t)i*NB;
  float* orow = attn + (size_t)i*NB;
  __shared__ float red[8];
  int tid = threadIdx.x;
  float mx = -1e30f;
  for(int j=tid;j<NB;j+=256) mx = fmaxf(mx, row[j]*mv);
  for(int off=32;off>0;off>>=1) mx = fmaxf(mx, __shfl_down(mx,off));
  if((tid&63)==0) red[tid>>6]=mx;
  __syncthreads();
  mx = fmaxf(fmaxf(red[0],red[1]),fmaxf(red[2],red[3]));
  float sum=0.f;
  for(int j=tid;j<NB;j+=256){ float e = expf(row[j]*mv - mx); orow[j]=e; sum+=e; }
  for(int off=32;off>0;off>>=1) sum += __shfl_down(sum,off);
  if((tid&63)==0) red[4+(tid>>6)]=sum;
  __syncthreads();
  sum = red[4]+red[5]+red[6]+red[7];
  float inv = 1.f/sum;
  for(int j=tid;j<NB;j+=256) orow[j] *= inv;
}

__global__ void k_attn_apply(const float* __restrict__ vf, const float* __restrict__ attn,
                             float* __restrict__ part){
  int i0 = blockIdx.x*32;
  int ks = blockIdx.y;
  __shared__ float Vt[64][33];
  __shared__ float At[32][33];
  int tid = threadIdx.x;
  int il = tid&31, cg = tid>>5;
  float acc[8]={};
  for(int k0=ks*576; k0<ks*576+576; k0+=32){
    for(int t=tid;t<2048;t+=256){ int c=t>>5, j=t&31; Vt[c][j]=vf[c*NB + k0+j]; }
    for(int t=tid;t<1024;t+=256){ int i=t>>5, j=t&31; At[i][j]=attn[(size_t)(i0+i)*NB + k0+j]; }
    __syncthreads();
    for(int j=0;j<32;j++){
      float a = At[il][j];
      #pragma unroll
      for(int q=0;q<8;q++) acc[q] += Vt[cg*8+q][j]*a;
    }
    __syncthreads();
  }
  #pragma unroll
  for(int q=0;q<8;q++) part[(size_t)(ks*64 + cg*8+q)*NB + i0+il] = acc[q];
}

__global__ void k_fp(const float* __restrict__ part, const float* __restrict__ fds,
                     const float* __restrict__ maskds, const float* __restrict__ gammap,
                     float* __restrict__ fp){
  int idx = blockIdx.x*256 + threadIdx.x;
  if(idx >= NC*NB) return;
  int i = idx%NB;
  float o = part[idx] + part[(size_t)NC*NB + idx] + part[(size_t)2*NC*NB + idx] + part[(size_t)3*NC*NB + idx];
  float mv = maskds[i];
  fp[idx] = gammap[0]*fds[idx]*mv + (1.f-mv)*o;
}

// bcol^T split: BT[P][k=(c,u,v)] = fp[c][neighbor(P,(u,v))], bf16 hi/lo
__global__ void k_bcolT_split(const float* __restrict__ fp,
                              u16* __restrict__ BTH, u16* __restrict__ BTL){
  int idx = blockIdx.x*256 + threadIdx.x;
  if(idx >= NB*576) return;
  int P = idx/576, k = idx%576;
  int c = k/9, i = k%9, u = i/3, v = i%3;
  int hP = P/HD, wP = P%HD;
  int y = hP+u-1, x = wP+v-1;
  float val = (y>=0&&y<HD&&x>=0&&x<HD) ? fp[c*NB + y*HD + x] : 0.f;
  u16 h,l; split_bf16(val, h, l);
  BTH[idx] = h; BTL[idx] = l;
}

// ---------------- MFMA bf16x3 GEMM v2 ----------------
// C_z[M][N] = (AH+AL)[M][K-slice z] @ (BH+BL)^T[K-slice z][N]
// 128x128 tile, BK=32, 4 waves (each 64x64), K-split over blockIdx.z,
// register prefetch of next K-tile, granule-XOR LDS swizzle.
__global__ __launch_bounds__(256, 2)
void k_gemm2(const u16* __restrict__ AH, const u16* __restrict__ AL,
             const u16* __restrict__ BTH, const u16* __restrict__ BTL,
             float* __restrict__ C, int M, int N, int Kc,
             int ldA, int ldB, int ldC, long zstride){
  __shared__ u16 sAH[128*32], sAL[128*32], sBH[128*32], sBL[128*32];
  int tid = threadIdx.x;
  int m0 = blockIdx.y*128, n0 = blockIdx.x*128;
  int z  = blockIdx.z;
  float* Cz = C + (size_t)z*zstride;
  int kbeg = z*Kc, kend = kbeg + Kc;
  int w = tid>>6, lane = tid&63;
  int wr = w>>1, wc = w&1;
  int fr = lane&15, fq = lane>>4;
  int r = tid>>1, hf = tid&1;       // staging: row r, granules hf*2..hf*2+1
  int ar = m0 + r, br = n0 + r;
  bool aok = (ar < M), bok = (br < N);

  f32x4 acc[4][4];
  #pragma unroll
  for(int i=0;i<4;i++)
    #pragma unroll
    for(int j=0;j<4;j++) acc[i][j] = (f32x4){0.f,0.f,0.f,0.f};

  u16x8 pah[2], pal[2], pbh[2], pbl[2];
  const u16x8 z8 = (u16x8)(u16)0;

  // prologue load
  #pragma unroll
  for(int g2=0; g2<2; ++g2){
    int g = hf*2+g2;
    pah[g2]=z8; pal[g2]=z8; pbh[g2]=z8; pbl[g2]=z8;
    if(aok){ size_t o=(size_t)ar*ldA + kbeg + g*8; pah[g2]=*(const u16x8*)&AH[o]; pal[g2]=*(const u16x8*)&AL[o]; }
    if(bok){ size_t o=(size_t)br*ldB + kbeg + g*8; pbh[g2]=*(const u16x8*)&BTH[o]; pbl[g2]=*(const u16x8*)&BTL[o]; }
  }

  for(int k0=kbeg; k0<kend; k0+=32){
    // write prefetched regs -> LDS (swizzled)
    #pragma unroll
    for(int g2=0; g2<2; ++g2){
      int g = hf*2+g2;
      int gs = (g ^ ((r>>1)&3))*8;
      *(u16x8*)&sAH[r*32+gs] = pah[g2];
      *(u16x8*)&sAL[r*32+gs] = pal[g2];
      *(u16x8*)&sBH[r*32+gs] = pbh[g2];
      *(u16x8*)&sBL[r*32+gs] = pbl[g2];
    }
    __syncthreads();
    // prefetch next K-tile (overlaps with MFMA below)
    if(k0+32 < kend){
      #pragma unroll
      for(int g2=0; g2<2; ++g2){
        int g = hf*2+g2;
        pah[g2]=z8; pal[g2]=z8; pbh[g2]=z8; pbl[g2]=z8;
        if(aok){ size_t o=(size_t)ar*ldA + (k0+32) + g*8; pah[g2]=*(const u16x8*)&AH[o]; pal[g2]=*(const u16x8*)&AL[o]; }
        if(bok){ size_t o=(size_t)br*ldB + (k0+32) + g*8; pbh[g2]=*(const u16x8*)&BTH[o]; pbl[g2]=*(const u16x8*)&BTL[o]; }
      }
    }
    s16x8 ah[4],al[4],bh[4],bl[4];
    #pragma unroll
    for(int mi=0;mi<4;mi++){
      int row = wr*64 + mi*16 + fr;
      int gs = (fq ^ ((row>>1)&3))*8;
      ah[mi] = *(const s16x8*)&sAH[row*32+gs];
      al[mi] = *(const s16x8*)&sAL[row*32+gs];
    }
    #pragma unroll
    for(int ni=0;ni<4;ni++){
      int row = wc*64 + ni*16 + fr;
      int gs = (fq ^ ((row>>1)&3))*8;
      bh[ni] = *(const s16x8*)&sBH[row*32+gs];
      bl[ni] = *(const s16x8*)&sBL[row*32+gs];
    }
    #pragma unroll
    for(int mi=0;mi<4;mi++)
      #pragma unroll
      for(int ni=0;ni<4;ni++){
        acc[mi][ni] = __builtin_amdgcn_mfma_f32_16x16x32_bf16(ah[mi], bh[ni], acc[mi][ni], 0,0,0);
        acc[mi][ni] = __builtin_amdgcn_mfma_f32_16x16x32_bf16(ah[mi], bl[ni], acc[mi][ni], 0,0,0);
        acc[mi][ni] = __builtin_amdgcn_mfma_f32_16x16x32_bf16(al[mi], bh[ni], acc[mi][ni], 0,0,0);
      }
    __syncthreads();
  }
  // epilogue: C/D layout col=lane&15, row=(lane>>4)*4+reg
  #pragma unroll
  for(int mi=0;mi<4;mi++)
    #pragma unroll
    for(int ni=0;ni<4;ni++){
      int row = m0 + wr*64 + mi*16 + fq*4;
      int col = n0 + wc*64 + ni*16 + fr;
      if(col < N){
        #pragma unroll
        for(int rr=0;rr<4;rr++)
          if(row+rr < M) Cz[(size_t)(row+rr)*ldC + col] = acc[mi][ni][rr];
      }
    }
}

// D1+merge: X = fuse1(p0+p1) (flat diagonal stencil, zero-pad at flat edges)
__global__ void k_fuse_merge(const float* __restrict__ p0, const float* __restrict__ p1,
                             float* __restrict__ out){
  size_t idx = (size_t)blockIdx.x*256 + threadIdx.x;
  if(idx >= (size_t)NB*NB) return;
  int q = (int)(idx/NB), P = (int)(idx%NB);
  float s = p0[idx] + p1[idx];
  if(q>0 && P>0)       s += p0[idx - NB - 1] + p1[idx - NB - 1];
  if(q<NB-1 && P<NB-1) s += p0[idx + NB + 1] + p1[idx + NB + 1];
  out[idx] = s;
}

// plain flat diagonal fuse
__global__ void k_fuse1p(const float* __restrict__ in, float* __restrict__ out){
  size_t idx = (size_t)blockIdx.x*256 + threadIdx.x;
  if(idx >= (size_t)NB*NB) return;
  int q = (int)(idx/NB), P = (int)(idx%NB);
  float s = in[idx];
  if(q>0 && P>0)       s += in[idx - NB - 1];
  if(q<NB-1 && P<NB-1) s += in[idx + NB + 1];
  out[idx] = s;
}

// Pi-permutation: out[pi(r)][(d,c)] = in[r][(c,d)]  (row remap + in-row 48x48 transpose)
__global__ void k_ptrans(const float* __restrict__ in, float* __restrict__ out){
  __shared__ float lds[48*49];
  int r = blockIdx.x;             // input row
  int a = r/HD, b2 = r%HD;
  int rb = b2*HD + a;             // output row
  const float* irow = in + (size_t)r*NB;
  float* orow = out + (size_t)rb*NB;
  for(int t=threadIdx.x; t<NB; t+=256){
    int c = t/HD, d = t%HD;
    lds[c*49 + d] = irow[t];
  }
  __syncthreads();
  for(int t=threadIdx.x; t<NB; t+=256){
    int d = t/HD, c = t%HD;
    orow[t] = lds[c*49 + d];
  }
}

// E1: per-(chunk,col) online softmax partials over rows of Z (permuted space)
__global__ void k_colsm_partial(const float* __restrict__ sc, const float* __restrict__ mm,
                                float* __restrict__ pmax, float* __restrict__ psum){
  int col = blockIdx.x*256 + threadIdx.x;
  int q0 = blockIdx.y*144;
  float mx = -1e30f, sum = 0.f;
  for(int q=q0; q<q0+144; q++){
    float L = (mm[q]!=0.f) ? 10.f*sc[(size_t)q*NB + col] : 0.f;
    if(L > mx){ sum *= expf(mx - L); mx = L; }
    sum += expf(L - mx);
  }
  pmax[blockIdx.y*NB + col] = mx;
  psum[blockIdx.y*NB + col] = sum;
}

__global__ void k_colsm_combine(const float* __restrict__ pmax, const float* __restrict__ psum,
                                float* __restrict__ cmax, float* __restrict__ cinv){
  int col = blockIdx.x*256 + threadIdx.x;
  if(col >= NB) return;
  float M = -1e30f;
  for(int k=0;k<16;k++) M = fmaxf(M, pmax[k*NB+col]);
  float S = 0.f;
  for(int k=0;k<16;k++) S += psum[k*NB+col]*expf(pmax[k*NB+col]-M);
  cmax[col] = M;
  cinv[col] = 1.f/S;
}

// apply softmax in permuted space AND emit yiT[P][q] = yiPerm[pi(q)][pi(P)].
// block = (alpha, delta); reads Z rows (beta*48+alpha), cols (delta*48+gamma);
// writes yiT rows (gamma*48+delta), cols (alpha*48+beta).
__global__ void k_apply_trans(const float* __restrict__ Z, const float* __restrict__ mmP,
                              const float* __restrict__ cmax, const float* __restrict__ cinv,
                              float* __restrict__ yiT){
  __shared__ float lds[48*49];
  int alpha = blockIdx.x/HD, delta = blockIdx.x%HD;
  for(int t=threadIdx.x; t<NB; t+=256){
    int beta = t/HD, gamma = t%HD;
    int qp = beta*HD + alpha;     // Z row
    int Pp = delta*HD + gamma;    // Z col
    float v = 0.f;
    if(mmP[qp] != 0.f)
      v = expf(10.f*Z[(size_t)qp*NB + Pp] - cmax[Pp]) * cinv[Pp];
    lds[beta*49 + gamma] = v;
  }
  __syncthreads();
  for(int t=threadIdx.x; t<NB; t+=256){
    int gamma = t/HD, beta = t%HD;
    yiT[(size_t)(gamma*HD + delta)*NB + alpha*HD + beta] = lds[beta*49 + gamma];
  }
}

// U^T via stencil on yiT, split bf16: UT[(rho,sig)][pp], [NP][KP]
__global__ void k_zbuildT_split(const float* __restrict__ yiT,
                                u16* __restrict__ UTH, u16* __restrict__ UTL){
  int row = blockIdx.y;                       // 0..NP-1
  int cc  = blockIdx.x*256 + threadIdx.x;     // 0..KP-1
  if(cc >= KP) return;
  size_t o = (size_t)row*KP + cc;
  float z = 0.f;
  if(cc < NP){
    int rho = row/49, sig = row%49;
    int ph = cc/49, pw = cc%49;
    #pragma unroll
    for(int a=0;a<2;a++)
      #pragma unroll
      for(int bb=0;bb<2;bb++){
        int sh=ph-a, sw=pw-bb, rr=rho-a, ss=sig-bb;
        if(sh>=0 && sh<HD && sw>=0 && sw<HD && rr>=0 && rr<HD && ss>=0 && ss<HD)
          z += yiT[(size_t)(rr*HD+ss)*NB + sh*HD+sw];
      }
  }
  u16 h,l; split_bf16(z, h, l);
  UTH[o] = h; UTL[o] = l;
}

// phase-gathered b split: b4[m=(phase*64+c)][kk=pp], [256][KP]
__global__ void k_b4_split(const float* __restrict__ b,
                           u16* __restrict__ B4H, u16* __restrict__ B4L, int s){
  int idx = blockIdx.x*256 + threadIdx.x;
  if(idx >= 256*KP) return;
  int m = idx/KP, kk = idx%KP;
  float val = 0.f;
  if(kk < NP){
    int phase = m>>6, c = m&63;
    int py = phase>>1, px = phase&1;
    int ph = kk/49, pw = kk%49;
    int y = 2*ph - py, x = 2*pw - px;
    if(y>=0&&y<IMG&&x>=0&&x<IMG) val = b[(((size_t)s*NC + c)*IMG + y)*IMG + x];
  }
  u16 h,l; split_bf16(val, h, l);
  B4H[idx] = h; B4L[idx] = l;
}

// epilogue: sum 4 G partials, interleave phases, *0.25
__global__ void k_epi(const float* __restrict__ G, float* __restrict__ out, int s){
  int idx = blockIdx.x*256 + threadIdx.x;
  if(idx >= NC*IMG*IMG) return;
  int c = idx/(IMG*IMG), rem = idx%(IMG*IMG);
  int y = rem/IMG, x = rem%IMG;
  int py = y&1, px = x&1, r = y>>1, s2 = x>>1;
  size_t gi = (size_t)((py*2+px)*64 + c)*NP + (r+py)*49 + (s2+px);
  const size_t gz = (size_t)256*NP;
  float v = G[gi] + G[gi+gz] + G[gi+2*gz] + G[gi+3*gz];
  out[((size_t)s*NC + c)*IMG*IMG + rem] = v * 0.25f;
}

// ---------------- launcher ----------------
extern "C" void kernel_launch(void* const* d_in, const int* in_sizes, int n_in,
                              void* d_out, int out_size, void* d_ws, size_t ws_size,
                              hipStream_t stream){
  const float* f    = (const float*)d_in[0];
  const float* b    = (const float*)d_in[1];
  const float* mask = (const float*)d_in[2];
  const float* fa_wq=(const float*)d_in[3];  const float* fa_bq=(const float*)d_in[4];
  const float* fa_wk=(const float*)d_in[5];  const float* fa_bk=(const float*)d_in[6];
  const float* fa_wv=(const float*)d_in[7];  const float* fa_bv=(const float*)d_in[8];
  const float* fa_g =(const float*)d_in[9];
  const float* pa_wq=(const float*)d_in[10]; const float* pa_bq=(const float*)d_in[11];
  const float* pa_wk=(const float*)d_in[12]; const float* pa_bk=(const float*)d_in[13];
  const float* pa_wv=(const float*)d_in[14]; const float* pa_bv=(const float*)d_in[15];
  const float* pa_g =(const float*)d_in[16];
  float* out = (float*)d_out;
  float* ws  = (float*)d_ws;
  if(ws_size < TOTAL_F*sizeof(float)) return;

  float* maskds = ws;
  float* mm     = ws + NB;
  float* mmP    = ws + 2*NB;
  float* cmax   = ws + 3*NB;
  float* cinv   = ws + 4*NB;
  float* pmax   = ws + 5*NB;
  float* psum   = ws + 21*NB;
  float* fds = ws + O_FDS;
  float* bds = ws + O_BDS;
  float* qf  = ws + O_QF;
  float* kf  = ws + O_KF;
  float* vf  = ws + O_VF;
  float* fp  = ws + O_FP;
  float* big0 = ws + O_BIG0;
  float* big1 = ws + O_BIG1;
  float* big2 = ws + O_BIG2;
  // stage-B partials (temporal, dead before big2 reused as GEMM p1)
  float* part = big2;
  // stage-C split operands live in big1 (dead region at that time)
  u16* AH  = (u16*)big1;
  u16* AL  = AH  + (size_t)NB*576;
  u16* BTH = AL  + (size_t)NB*576;
  u16* BTL = BTH + (size_t)NB*576;
  // stage-F: UT at big1 spilling into big2; B4/G after the spill
  u16* UTH = (u16*)big1;
  u16* UTL = UTH + (size_t)NP*KP;
  u16* B4H = (u16*)(ws + O_B4);
  u16* B4L = B4H + (size_t)256*KP;
  float* G = ws + O_G;

  k_prep_mask<<<9, 256, 0, stream>>>(mask, maskds, mm, mmP);

  for(int s=0; s<2; s++){
    k_ds<<<CDIV(NC*NB,256), 256, 0, stream>>>(f, fds, s);
    k_ds<<<CDIV(NC*NB,256), 256, 0, stream>>>(b, bds, s);

    // Stage B: full global attention -> fp
    k_conv1x1<<<dim3(4,9,3), 256, 0, stream>>>(fds, bds,
        fa_wq, fa_bq, fa_wk, fa_bk, fa_wv, fa_bv, qf, kf, vf);
    k_simgemm<<<dim3(72,72), 256, 0, stream>>>(qf, kf, big0);
    k_rowsm<<<NB, 256, 0, stream>>>(big0, maskds, big1);
    k_attn_apply<<<dim3(72,4), 256, 0, stream>>>(vf, big1, part);
    k_fp<<<CDIV(NC*NB,256), 256, 0, stream>>>(part, fds, maskds, fa_g, fp);

    // Stage A: patch attention -> A-hi/lo (big1 free now)
    k_patch_attn<<<NB, 64, 0, stream>>>(fds, bds, maskds,
        pa_wq, pa_bq, pa_wk, pa_bk, pa_wv, pa_bv, pa_g, AH, AL);

    // Stage C: scores = wi_n @ im2col(fp)  (MFMA bf16x3, K-split 2)
    k_bcolT_split<<<CDIV(NB*576,256), 256, 0, stream>>>(fp, BTH, BTL);
    k_gemm2<<<dim3(18,18,2), 256, 0, stream>>>(AH, AL, BTH, BTL, big0,
        NB, NB, 288, 576, 576, NB, (long)2*NB*NB);   // p0=big0, p1=big2

    // Stage D/E: fuse chain via Pi-permutation (all coalesced)
    k_fuse_merge<<<20736, 256, 0, stream>>>(big0, big2, big1);   // X = fuse1(p0+p1)
    k_ptrans<<<NB, 256, 0, stream>>>(big1, big0);                // Y = Pi X
    k_fuse1p<<<20736, 256, 0, stream>>>(big0, big2);             // Z = fuse1(Y)
    k_colsm_partial<<<dim3(9,16), 256, 0, stream>>>(big2, mmP, pmax, psum);
    k_colsm_combine<<<9, 256, 0, stream>>>(pmax, psum, cmax, cinv);
    k_apply_trans<<<NB, 256, 0, stream>>>(big2, mmP, cmax, cinv, big0);  // yiT

    // Stage F: zbuild -> GEMM (K-split 4) -> epilogue
    k_zbuildT_split<<<dim3(CDIV(KP,256), NP), 256, 0, stream>>>(big0, UTH, UTL);
    k_b4_split<<<CDIV(256*KP,256), 256, 0, stream>>>(b, B4H, B4L, s);
    k_gemm2<<<dim3(CDIV(NP,128), 2, 4), 256, 0, stream>>>(B4H, B4L, UTH, UTL, G,
        256, NP, 608, KP, KP, NP, (long)256*NP);
    k_epi<<<CDIV(NC*IMG*IMG,256), 256, 0, stream>>>(G, out, s);
  }
}

// Round 5
// 450.797 us; speedup vs baseline: 4.0352x; 1.7137x over previous
//
#include <hip/hip_runtime.h>
#include <math.h>

#define HD 48
#define NB 2304      // 48*48
#define NC 64
#define IMG 96
#define NP 2401      // 49*49
#define KP 2432      // NP padded to mult of 32

#define CDIV(a,b) (((a)+(b)-1)/(b))

typedef unsigned short u16;
typedef __attribute__((ext_vector_type(8))) short  s16x8;
typedef __attribute__((ext_vector_type(8))) unsigned short u16x8;
typedef __attribute__((ext_vector_type(4))) float  f32x4;

// ---------------- workspace layout (float slots) ----------------
// smalls: maskds NB, mm NB, mmP NB, cmax NB, cinv NB, pmax 16NB, psum 16NB, meanf 64, meanVf 64
constexpr size_t SZ = (size_t)NC*NB;
constexpr size_t O_FDS  = (size_t)38*NB;
constexpr size_t O_FDST = O_FDS + SZ;            // fdsT [NB][64]
constexpr size_t O_BIG0 = O_FDST + SZ;
constexpr size_t O_BIG1 = O_BIG0 + (size_t)NB*NB;
constexpr size_t O_BIG2 = O_BIG1 + (size_t)NB*NB;
constexpr size_t TOTAL_F = O_BIG2 + (size_t)NB*NB;   // ~16.3M floats ~65MB
// stage-F sub-layout: UT (2 u16 bufs [NP][KP]) at big1, spills into big2 head
constexpr size_t UT_SPILLF = ((size_t)NP*KP) - (size_t)NB*NB;
constexpr size_t O_B4 = O_BIG2 + UT_SPILLF;          // B4H+B4L: 2*256*KP u16
constexpr size_t O_G  = O_B4 + (size_t)256*KP/2*2;   // 4 partials * 256*NP f32

// ---------------- helpers ----------------
__device__ inline void split_bf16(float x, u16& hi, u16& lo){
  unsigned int u = __float_as_uint(x);
  unsigned int r = u + 0x7FFFu + ((u >> 16) & 1u);
  hi = (u16)(r >> 16);
  float xh = __uint_as_float(((unsigned int)hi) << 16);
  float res = x - xh;
  unsigned int u2 = __float_as_uint(res);
  unsigned int r2 = u2 + 0x7FFFu + ((u2 >> 16) & 1u);
  lo = (u16)(r2 >> 16);
}

// ---------------- kernels ----------------

__global__ void k_prep_mask(const float* __restrict__ mask, float* __restrict__ maskds,
                            float* __restrict__ mm, float* __restrict__ mmP){
  int q = blockIdx.x*256 + threadIdx.x;
  if(q >= NB) return;
  int hq = q/HD, wq = q%HD;
  maskds[q] = mask[(2*hq)*IMG + 2*wq];
  float any = 0.f;
  for(int u=-1;u<=1;u++)
    for(int v=-1;v<=1;v++){
      int y=hq+u, x=wq+v;
      if(y>=0&&y<HD&&x>=0&&x<HD) any += mask[(2*y)*IMG + 2*x];
    }
  float v = (any == 0.f) ? 1.f : 0.f;
  mm[q] = v;
  mmP[wq*HD + hq] = v;
}

// downsample f -> fds [c][j] and fdsT [j][c]
__global__ void k_ds(const float* __restrict__ src, float* __restrict__ fds,
                     float* __restrict__ fdsT, int s){
  int idx = blockIdx.x*256 + threadIdx.x;
  if(idx >= NC*NB) return;
  int c = idx/NB, j = idx%NB;
  int h = j/HD, w = j%HD;
  float v = src[(((size_t)s*NC + c)*IMG + 2*h)*IMG + 2*w];
  fds[idx] = v;
  fdsT[(size_t)j*64 + c] = v;
}

// column mean of fds: meanf[c] = (1/NB) sum_j fds[c][j]
__global__ void k_colmean(const float* __restrict__ fds, float* __restrict__ meanf){
  int c = blockIdx.x;
  int tid = threadIdx.x;
  float s = 0.f;
  for(int j=tid; j<NB; j+=256) s += fds[(size_t)c*NB + j];
  for(int off=32; off>0; off>>=1) s += __shfl_down(s, off);
  __shared__ float red[4];
  if((tid&63)==0) red[tid>>6] = s;
  __syncthreads();
  if(tid==0) meanf[c] = (red[0]+red[1]+red[2]+red[3]) * (1.f/NB);
}

// meanVf[c] = fa_wv[c][:] . meanf + fa_bv[c]
__global__ void k_meanvf(const float* __restrict__ meanf, const float* __restrict__ wv,
                         const float* __restrict__ bv, float* __restrict__ meanVf){
  __shared__ float mf[64];
  int c = threadIdx.x;
  mf[c] = meanf[c];
  __syncthreads();
  float s = 0.f;
  for(int cc=0;cc<64;cc++) s += wv[c*64+cc]*mf[cc];
  meanVf[c] = s + bv[c];
}

// Stage A collapsed: per patch p, fpv[c][i] = mval[i] ? g*A[c][i] : (Wv.sumA)/9 + bv
// then L2-normalize over (c,i) and emit bf16 hi/lo at [p][c*9+i].
__global__ void k_stageA(const float* __restrict__ fdsT, const float* __restrict__ maskds,
                         const float* __restrict__ wv, const float* __restrict__ bv,
                         const float* __restrict__ gammap,
                         u16* __restrict__ AH, u16* __restrict__ AL){
  __shared__ float sumA[64];
  __shared__ float mval[9];
  int p = blockIdx.x;
  int ph = p/HD, pw = p%HD;
  int c = threadIdx.x;   // 64 threads
  float A[9]; float sa = 0.f;
  #pragma unroll
  for(int i=0;i<9;i++){
    int u=i/3, v=i%3;
    int y=ph+u-1, x=pw+v-1;
    bool in = (y>=0&&y<HD&&x>=0&&x<HD);
    float fv = in ? fdsT[(size_t)(y*HD+x)*64 + c] : 0.f;
    A[i] = fv; sa += fv;
    if(c==0) mval[i] = in ? maskds[y*HD+x] : 0.f;
  }
  sumA[c] = sa;
  __syncthreads();
  float acc = 0.f;
  for(int cc=0;cc<64;cc++) acc += wv[c*64+cc]*sumA[cc];
  float meanVc = acc*(1.f/9.f) + bv[c];
  float gamma = gammap[0];
  float fpv[9]; float ss = 0.f;
  #pragma unroll
  for(int i=0;i<9;i++){
    float v = (mval[i]!=0.f) ? gamma*A[i] : meanVc;
    fpv[i] = v; ss += v*v;
  }
  for(int off=32; off>0; off>>=1) ss += __shfl_down(ss, off);
  ss = __shfl(ss, 0);
  float scale = 1.f / fmaxf(sqrtf(ss), 1e-4f);
  #pragma unroll
  for(int i=0;i<9;i++){
    u16 h,l; split_bf16(fpv[i]*scale, h, l);
    size_t o = (size_t)p*576 + c*9 + i;
    AH[o] = h; AL[o] = l;
  }
}

// Stage B collapsed + im2col + split:
// BT[P][k=(c,u,v)] = pad ? 0 : (maskds[pos] ? gf*fds[c][pos] : meanVf[c])
__global__ void k_bcolT_split(const float* __restrict__ fds, const float* __restrict__ maskds,
                              const float* __restrict__ meanVf, const float* __restrict__ gfp,
                              u16* __restrict__ BTH, u16* __restrict__ BTL){
  int idx = blockIdx.x*256 + threadIdx.x;
  if(idx >= NB*576) return;
  int P = idx/576, k = idx%576;
  int c = k/9, i = k%9, u = i/3, v = i%3;
  int hP = P/HD, wP = P%HD;
  int y = hP+u-1, x = wP+v-1;
  float val = 0.f;
  if(y>=0&&y<HD&&x>=0&&x<HD){
    int pos = y*HD + x;
    val = (maskds[pos]!=0.f) ? gfp[0]*fds[(size_t)c*NB + pos] : meanVf[c];
  }
  u16 h,l; split_bf16(val, h, l);
  BTH[idx] = h; BTL[idx] = l;
}

// ---------------- MFMA bf16x3 GEMM v2 ----------------
__global__ __launch_bounds__(256, 2)
void k_gemm2(const u16* __restrict__ AH, const u16* __restrict__ AL,
             const u16* __restrict__ BTH, const u16* __restrict__ BTL,
             float* __restrict__ C, int M, int N, int Kc,
             int ldA, int ldB, int ldC, long zstride){
  __shared__ u16 sAH[128*32], sAL[128*32], sBH[128*32], sBL[128*32];
  int tid = threadIdx.x;
  int m0 = blockIdx.y*128, n0 = blockIdx.x*128;
  int z  = blockIdx.z;
  float* Cz = C + (size_t)z*zstride;
  int kbeg = z*Kc, kend = kbeg + Kc;
  int w = tid>>6, lane = tid&63;
  int wr = w>>1, wc = w&1;
  int fr = lane&15, fq = lane>>4;
  int r = tid>>1, hf = tid&1;
  int ar = m0 + r, br = n0 + r;
  bool aok = (ar < M), bok = (br < N);

  f32x4 acc[4][4];
  #pragma unroll
  for(int i=0;i<4;i++)
    #pragma unroll
    for(int j=0;j<4;j++) acc[i][j] = (f32x4){0.f,0.f,0.f,0.f};

  u16x8 pah[2], pal[2], pbh[2], pbl[2];
  const u16x8 z8 = (u16x8)(u16)0;

  #pragma unroll
  for(int g2=0; g2<2; ++g2){
    int g = hf*2+g2;
    pah[g2]=z8; pal[g2]=z8; pbh[g2]=z8; pbl[g2]=z8;
    if(aok){ size_t o=(size_t)ar*ldA + kbeg + g*8; pah[g2]=*(const u16x8*)&AH[o]; pal[g2]=*(const u16x8*)&AL[o]; }
    if(bok){ size_t o=(size_t)br*ldB + kbeg + g*8; pbh[g2]=*(const u16x8*)&BTH[o]; pbl[g2]=*(const u16x8*)&BTL[o]; }
  }

  for(int k0=kbeg; k0<kend; k0+=32){
    #pragma unroll
    for(int g2=0; g2<2; ++g2){
      int g = hf*2+g2;
      int gs = (g ^ ((r>>1)&3))*8;
      *(u16x8*)&sAH[r*32+gs] = pah[g2];
      *(u16x8*)&sAL[r*32+gs] = pal[g2];
      *(u16x8*)&sBH[r*32+gs] = pbh[g2];
      *(u16x8*)&sBL[r*32+gs] = pbl[g2];
    }
    __syncthreads();
    if(k0+32 < kend){
      #pragma unroll
      for(int g2=0; g2<2; ++g2){
        int g = hf*2+g2;
        pah[g2]=z8; pal[g2]=z8; pbh[g2]=z8; pbl[g2]=z8;
        if(aok){ size_t o=(size_t)ar*ldA + (k0+32) + g*8; pah[g2]=*(const u16x8*)&AH[o]; pal[g2]=*(const u16x8*)&AL[o]; }
        if(bok){ size_t o=(size_t)br*ldB + (k0+32) + g*8; pbh[g2]=*(const u16x8*)&BTH[o]; pbl[g2]=*(const u16x8*)&BTL[o]; }
      }
    }
    s16x8 ah[4],al[4],bh[4],bl[4];
    #pragma unroll
    for(int mi=0;mi<4;mi++){
      int row = wr*64 + mi*16 + fr;
      int gs = (fq ^ ((row>>1)&3))*8;
      ah[mi] = *(const s16x8*)&sAH[row*32+gs];
      al[mi] = *(const s16x8*)&sAL[row*32+gs];
    }
    #pragma unroll
    for(int ni=0;ni<4;ni++){
      int row = wc*64 + ni*16 + fr;
      int gs = (fq ^ ((row>>1)&3))*8;
      bh[ni] = *(const s16x8*)&sBH[row*32+gs];
      bl[ni] = *(const s16x8*)&sBL[row*32+gs];
    }
    #pragma unroll
    for(int mi=0;mi<4;mi++)
      #pragma unroll
      for(int ni=0;ni<4;ni++){
        acc[mi][ni] = __builtin_amdgcn_mfma_f32_16x16x32_bf16(ah[mi], bh[ni], acc[mi][ni], 0,0,0);
        acc[mi][ni] = __builtin_amdgcn_mfma_f32_16x16x32_bf16(ah[mi], bl[ni], acc[mi][ni], 0,0,0);
        acc[mi][ni] = __builtin_amdgcn_mfma_f32_16x16x32_bf16(al[mi], bh[ni], acc[mi][ni], 0,0,0);
      }
    __syncthreads();
  }
  #pragma unroll
  for(int mi=0;mi<4;mi++)
    #pragma unroll
    for(int ni=0;ni<4;ni++){
      int row = m0 + wr*64 + mi*16 + fq*4;
      int col = n0 + wc*64 + ni*16 + fr;
      if(col < N){
        #pragma unroll
        for(int rr=0;rr<4;rr++)
          if(row+rr < M) Cz[(size_t)(row+rr)*ldC + col] = acc[mi][ni][rr];
      }
    }
}

// D1+merge: X = fuse1(p0+p1)
__global__ void k_fuse_merge(const float* __restrict__ p0, const float* __restrict__ p1,
                             float* __restrict__ out){
  size_t idx = (size_t)blockIdx.x*256 + threadIdx.x;
  if(idx >= (size_t)NB*NB) return;
  int q = (int)(idx/NB), P = (int)(idx%NB);
  float s = p0[idx] + p1[idx];
  if(q>0 && P>0)       s += p0[idx - NB - 1] + p1[idx - NB - 1];
  if(q<NB-1 && P<NB-1) s += p0[idx + NB + 1] + p1[idx + NB + 1];
  out[idx] = s;
}

__global__ void k_fuse1p(const float* __restrict__ in, float* __restrict__ out){
  size_t idx = (size_t)blockIdx.x*256 + threadIdx.x;
  if(idx >= (size_t)NB*NB) return;
  int q = (int)(idx/NB), P = (int)(idx%NB);
  float s = in[idx];
  if(q>0 && P>0)       s += in[idx - NB - 1];
  if(q<NB-1 && P<NB-1) s += in[idx + NB + 1];
  out[idx] = s;
}

// Pi-permutation: out[pi(r)][(d,c)] = in[r][(c,d)]
__global__ void k_ptrans(const float* __restrict__ in, float* __restrict__ out){
  __shared__ float lds[48*49];
  int r = blockIdx.x;
  int a = r/HD, b2 = r%HD;
  int rb = b2*HD + a;
  const float* irow = in + (size_t)r*NB;
  float* orow = out + (size_t)rb*NB;
  for(int t=threadIdx.x; t<NB; t+=256){
    int c = t/HD, d = t%HD;
    lds[c*49 + d] = irow[t];
  }
  __syncthreads();
  for(int t=threadIdx.x; t<NB; t+=256){
    int d = t/HD, c = t%HD;
    orow[t] = lds[c*49 + d];
  }
}

__global__ void k_colsm_partial(const float* __restrict__ sc, const float* __restrict__ mm,
                                float* __restrict__ pmax, float* __restrict__ psum){
  int col = blockIdx.x*256 + threadIdx.x;
  int q0 = blockIdx.y*144;
  float mx = -1e30f, sum = 0.f;
  for(int q=q0; q<q0+144; q++){
    float L = (mm[q]!=0.f) ? 10.f*sc[(size_t)q*NB + col] : 0.f;
    if(L > mx){ sum *= expf(mx - L); mx = L; }
    sum += expf(L - mx);
  }
  pmax[blockIdx.y*NB + col] = mx;
  psum[blockIdx.y*NB + col] = sum;
}

__global__ void k_colsm_combine(const float* __restrict__ pmax, const float* __restrict__ psum,
                                float* __restrict__ cmax, float* __restrict__ cinv){
  int col = blockIdx.x*256 + threadIdx.x;
  if(col >= NB) return;
  float M = -1e30f;
  for(int k=0;k<16;k++) M = fmaxf(M, pmax[k*NB+col]);
  float S = 0.f;
  for(int k=0;k<16;k++) S += psum[k*NB+col]*expf(pmax[k*NB+col]-M);
  cmax[col] = M;
  cinv[col] = 1.f/S;
}

// apply softmax in permuted space AND emit yiT
__global__ void k_apply_trans(const float* __restrict__ Z, const float* __restrict__ mmP,
                              const float* __restrict__ cmax, const float* __restrict__ cinv,
                              float* __restrict__ yiT){
  __shared__ float lds[48*49];
  int alpha = blockIdx.x/HD, delta = blockIdx.x%HD;
  for(int t=threadIdx.x; t<NB; t+=256){
    int beta = t/HD, gamma = t%HD;
    int qp = beta*HD + alpha;
    int Pp = delta*HD + gamma;
    float v = 0.f;
    if(mmP[qp] != 0.f)
      v = expf(10.f*Z[(size_t)qp*NB + Pp] - cmax[Pp]) * cinv[Pp];
    lds[beta*49 + gamma] = v;
  }
  __syncthreads();
  for(int t=threadIdx.x; t<NB; t+=256){
    int gamma = t/HD, beta = t%HD;
    yiT[(size_t)(gamma*HD + delta)*NB + alpha*HD + beta] = lds[beta*49 + gamma];
  }
}

// U^T via stencil on yiT, split bf16: UT[(rho,sig)][pp], [NP][KP]
__global__ void k_zbuildT_split(const float* __restrict__ yiT,
                                u16* __restrict__ UTH, u16* __restrict__ UTL){
  int row = blockIdx.y;
  int cc  = blockIdx.x*256 + threadIdx.x;
  if(cc >= KP) return;
  size_t o = (size_t)row*KP + cc;
  float z = 0.f;
  if(cc < NP){
    int rho = row/49, sig = row%49;
    int ph = cc/49, pw = cc%49;
    #pragma unroll
    for(int a=0;a<2;a++)
      #pragma unroll
      for(int bb=0;bb<2;bb++){
        int sh=ph-a, sw=pw-bb, rr=rho-a, ss=sig-bb;
        if(sh>=0 && sh<HD && sw>=0 && sw<HD && rr>=0 && rr<HD && ss>=0 && ss<HD)
          z += yiT[(size_t)(rr*HD+ss)*NB + sh*HD+sw];
      }
  }
  u16 h,l; split_bf16(z, h, l);
  UTH[o] = h; UTL[o] = l;
}

__global__ void k_b4_split(const float* __restrict__ b,
                           u16* __restrict__ B4H, u16* __restrict__ B4L, int s){
  int idx = blockIdx.x*256 + threadIdx.x;
  if(idx >= 256*KP) return;
  int m = idx/KP, kk = idx%KP;
  float val = 0.f;
  if(kk < NP){
    int phase = m>>6, c = m&63;
    int py = phase>>1, px = phase&1;
    int ph = kk/49, pw = kk%49;
    int y = 2*ph - py, x = 2*pw - px;
    if(y>=0&&y<IMG&&x>=0&&x<IMG) val = b[(((size_t)s*NC + c)*IMG + y)*IMG + x];
  }
  u16 h,l; split_bf16(val, h, l);
  B4H[idx] = h; B4L[idx] = l;
}

__global__ void k_epi(const float* __restrict__ G, float* __restrict__ out, int s){
  int idx = blockIdx.x*256 + threadIdx.x;
  if(idx >= NC*IMG*IMG) return;
  int c = idx/(IMG*IMG), rem = idx%(IMG*IMG);
  int y = rem/IMG, x = rem%IMG;
  int py = y&1, px = x&1, r = y>>1, s2 = x>>1;
  size_t gi = (size_t)((py*2+px)*64 + c)*NP + (r+py)*49 + (s2+px);
  const size_t gz = (size_t)256*NP;
  float v = G[gi] + G[gi+gz] + G[gi+2*gz] + G[gi+3*gz];
  out[((size_t)s*NC + c)*IMG*IMG + rem] = v * 0.25f;
}

// ---------------- launcher ----------------
extern "C" void kernel_launch(void* const* d_in, const int* in_sizes, int n_in,
                              void* d_out, int out_size, void* d_ws, size_t ws_size,
                              hipStream_t stream){
  const float* f    = (const float*)d_in[0];
  const float* b    = (const float*)d_in[1];
  const float* mask = (const float*)d_in[2];
  const float* fa_wv=(const float*)d_in[7];  const float* fa_bv=(const float*)d_in[8];
  const float* fa_g =(const float*)d_in[9];
  const float* pa_wv=(const float*)d_in[14]; const float* pa_bv=(const float*)d_in[15];
  const float* pa_g =(const float*)d_in[16];
  float* out = (float*)d_out;
  float* ws  = (float*)d_ws;
  if(ws_size < TOTAL_F*sizeof(float)) return;

  float* maskds = ws;
  float* mm     = ws + NB;
  float* mmP    = ws + 2*NB;
  float* cmax   = ws + 3*NB;
  float* cinv   = ws + 4*NB;
  float* pmax   = ws + 5*NB;
  float* psum   = ws + 21*NB;
  float* meanf  = ws + 37*NB;
  float* meanVf = ws + 37*NB + 64;
  float* fds  = ws + O_FDS;
  float* fdsT = ws + O_FDST;
  float* big0 = ws + O_BIG0;
  float* big1 = ws + O_BIG1;
  float* big2 = ws + O_BIG2;
  // stage-C split operands live in big1 (dead at that time)
  u16* AH  = (u16*)big1;
  u16* AL  = AH  + (size_t)NB*576;
  u16* BTH = AL  + (size_t)NB*576;
  u16* BTL = BTH + (size_t)NB*576;
  // stage-F: UT at big1 spilling into big2 head; B4/G after the spill
  u16* UTH = (u16*)big1;
  u16* UTL = UTH + (size_t)NP*KP;
  u16* B4H = (u16*)(ws + O_B4);
  u16* B4L = B4H + (size_t)256*KP;
  float* G = ws + O_G;

  k_prep_mask<<<9, 256, 0, stream>>>(mask, maskds, mm, mmP);

  for(int s=0; s<2; s++){
    k_ds<<<CDIV(NC*NB,256), 256, 0, stream>>>(f, fds, fdsT, s);

    // Stage B collapsed: column mean + matvec
    k_colmean<<<64, 256, 0, stream>>>(fds, meanf);
    k_meanvf<<<1, 64, 0, stream>>>(meanf, fa_wv, fa_bv, meanVf);

    // Stage A collapsed: patch filters -> AH/AL
    k_stageA<<<NB, 64, 0, stream>>>(fdsT, maskds, pa_wv, pa_bv, pa_g, AH, AL);

    // Stage C: scores = wi_n @ im2col(fp)  (fp-select folded into im2col)
    k_bcolT_split<<<CDIV(NB*576,256), 256, 0, stream>>>(fds, maskds, meanVf, fa_g, BTH, BTL);
    k_gemm2<<<dim3(18,18,2), 256, 0, stream>>>(AH, AL, BTH, BTL, big0,
        NB, NB, 288, 576, 576, NB, (long)2*NB*NB);   // p0=big0, p1=big2

    // Stage D/E: fuse chain via Pi-permutation
    k_fuse_merge<<<20736, 256, 0, stream>>>(big0, big2, big1);   // X = fuse1(p0+p1)
    k_ptrans<<<NB, 256, 0, stream>>>(big1, big0);                // Y = Pi X
    k_fuse1p<<<20736, 256, 0, stream>>>(big0, big2);             // Z = fuse1(Y)
    k_colsm_partial<<<dim3(9,16), 256, 0, stream>>>(big2, mmP, pmax, psum);
    k_colsm_combine<<<9, 256, 0, stream>>>(pmax, psum, cmax, cinv);
    k_apply_trans<<<NB, 256, 0, stream>>>(big2, mmP, cmax, cinv, big0);  // yiT

    // Stage F: zbuild -> GEMM (K-split 4) -> epilogue
    k_zbuildT_split<<<dim3(CDIV(KP,256), NP), 256, 0, stream>>>(big0, UTH, UTL);
    k_b4_split<<<CDIV(256*KP,256), 256, 0, stream>>>(b, B4H, B4L, s);
    k_gemm2<<<dim3(CDIV(NP,128), 2, 4), 256, 0, stream>>>(B4H, B4L, UTH, UTL, G,
        256, NP, 608, KP, KP, NP, (long)256*NP);
    k_epi<<<CDIV(NC*IMG*IMG,256), 256, 0, stream>>>(G, out, s);
  }
}

// Round 6
// 258.795 us; speedup vs baseline: 7.0290x; 1.7419x over previous
//
#include <hip/hip_runtime.h>
#include <math.h>

#define HD 48
#define NB 2304      // 48*48
#define NC 64
#define IMG 96
#define NP 2401      // 49*49
#define KP 2432      // NP padded to mult of 64

#define CDIV(a,b) (((a)+(b)-1)/(b))

typedef unsigned short u16;
typedef __attribute__((ext_vector_type(8))) short  s16x8;
typedef __attribute__((ext_vector_type(8))) unsigned short u16x8;
typedef __attribute__((ext_vector_type(4))) float  f32x4;

// ---------------- workspace layout (float slots) ----------------
// shared smalls: maskds NB | mmP NB | cmax 2NB | cinv 2NB | pmax 32NB | psum 32NB | mean 256
constexpr size_t O_MASKDS = 0;
constexpr size_t O_MMP    = NB;
constexpr size_t O_CMAX   = (size_t)2*NB;   // 2 samples
constexpr size_t O_CINV   = (size_t)4*NB;
constexpr size_t O_PMAX   = (size_t)6*NB;   // [s][16][NB]
constexpr size_t O_PSUM   = (size_t)38*NB;
constexpr size_t O_MEAN   = (size_t)70*NB;  // meanf 2x64, meanVf 2x64
constexpr size_t O_ARENA0 = (size_t)71*NB;
// per-sample arena (floats):
constexpr size_t A_FDS  = 0;                         // 147456
constexpr size_t A_FDST = 147456;                    // 147456
constexpr size_t A_SCR  = 294912;                    // AH/AL/BTH/BTL (4 x NB*576 u16) -> later G (4 x 256*NP f)
constexpr size_t A_P0   = A_SCR + 2654208;           // NB^2 partial0 -> later yiT
constexpr size_t A_P1   = A_P0 + (size_t)NB*NB;      // NB^2 partial1 -> later UT (2 x NP*KP u16 = 5839232 f)
constexpr size_t A_Y    = A_P1 + 5839232;            // NB^2
constexpr size_t A_B4   = A_Y + (size_t)NB*NB;       // 2 x 256*KP u16 = 622592 f
constexpr size_t SSTR   = A_B4 + 622592;             // = 20027776 floats (~80MB)
constexpr size_t TOTAL_F = O_ARENA0 + 2*SSTR;        // ~40.2M floats ~153.4 MiB

// ---------------- helpers ----------------
__device__ inline void split_bf16(float x, u16& hi, u16& lo){
  unsigned int u = __float_as_uint(x);
  unsigned int r = u + 0x7FFFu + ((u >> 16) & 1u);
  hi = (u16)(r >> 16);
  float xh = __uint_as_float(((unsigned int)hi) << 16);
  float res = x - xh;
  unsigned int u2 = __float_as_uint(res);
  unsigned int r2 = u2 + 0x7FFFu + ((u2 >> 16) & 1u);
  lo = (u16)(r2 >> 16);
}

// ---------------- kernels ----------------

__global__ void k_prep_mask(const float* __restrict__ mask, float* __restrict__ maskds,
                            float* __restrict__ mmP){
  int q = blockIdx.x*256 + threadIdx.x;
  if(q >= NB) return;
  int hq = q/HD, wq = q%HD;
  maskds[q] = mask[(2*hq)*IMG + 2*wq];
  float any = 0.f;
  for(int u=-1;u<=1;u++)
    for(int v=-1;v<=1;v++){
      int y=hq+u, x=wq+v;
      if(y>=0&&y<HD&&x>=0&&x<HD) any += mask[(2*y)*IMG + 2*x];
    }
  mmP[wq*HD + hq] = (any == 0.f) ? 1.f : 0.f;
}

// downsample f -> fds [c][j] and fdsT [j][c], batched over samples
__global__ void k_ds(const float* __restrict__ src, float* __restrict__ fds0,
                     float* __restrict__ fdsT0){
  int s = blockIdx.y;
  float* fds  = fds0  + (size_t)s*SSTR;
  float* fdsT = fdsT0 + (size_t)s*SSTR;
  int idx = blockIdx.x*256 + threadIdx.x;
  if(idx >= NC*NB) return;
  int c = idx/NB, j = idx%NB;
  int h = j/HD, w = j%HD;
  float v = src[(((size_t)s*NC + c)*IMG + 2*h)*IMG + 2*w];
  fds[idx] = v;
  fdsT[(size_t)j*64 + c] = v;
}

__global__ void k_colmean(const float* __restrict__ fds0, float* __restrict__ meanf){
  int s = blockIdx.y;
  const float* fds = fds0 + (size_t)s*SSTR;
  int c = blockIdx.x;
  int tid = threadIdx.x;
  float sum = 0.f;
  for(int j=tid; j<NB; j+=256) sum += fds[(size_t)c*NB + j];
  for(int off=32; off>0; off>>=1) sum += __shfl_down(sum, off);
  __shared__ float red[4];
  if((tid&63)==0) red[tid>>6] = sum;
  __syncthreads();
  if(tid==0) meanf[s*64 + c] = (red[0]+red[1]+red[2]+red[3]) * (1.f/NB);
}

__global__ void k_meanvf(const float* __restrict__ meanf, const float* __restrict__ wv,
                         const float* __restrict__ bv, float* __restrict__ meanVf){
  int s = blockIdx.x;
  __shared__ float mf[64];
  int c = threadIdx.x;
  mf[c] = meanf[s*64 + c];
  __syncthreads();
  float sum = 0.f;
  for(int cc=0;cc<64;cc++) sum += wv[c*64+cc]*mf[cc];
  meanVf[s*64 + c] = sum + bv[c];
}

// Stage A collapsed: fpv[c][i] = mval[i] ? g*A[c][i] : (Wv.sumA)/9 + bv; L2-norm; bf16 split
__global__ void k_stageA(const float* __restrict__ fdsT0, const float* __restrict__ maskds,
                         const float* __restrict__ wv, const float* __restrict__ bv,
                         const float* __restrict__ gammap,
                         u16* __restrict__ AH0, u16* __restrict__ AL0){
  int s = blockIdx.y;
  const float* fdsT = fdsT0 + (size_t)s*SSTR;
  u16* AH = AH0 + (size_t)s*2*SSTR;
  u16* AL = AL0 + (size_t)s*2*SSTR;
  __shared__ float sumA[64];
  __shared__ float mval[9];
  int p = blockIdx.x;
  int ph = p/HD, pw = p%HD;
  int c = threadIdx.x;
  float A[9]; float sa = 0.f;
  #pragma unroll
  for(int i=0;i<9;i++){
    int u=i/3, v=i%3;
    int y=ph+u-1, x=pw+v-1;
    bool in = (y>=0&&y<HD&&x>=0&&x<HD);
    float fv = in ? fdsT[(size_t)(y*HD+x)*64 + c] : 0.f;
    A[i] = fv; sa += fv;
    if(c==0) mval[i] = in ? maskds[y*HD+x] : 0.f;
  }
  sumA[c] = sa;
  __syncthreads();
  float acc = 0.f;
  for(int cc=0;cc<64;cc++) acc += wv[c*64+cc]*sumA[cc];
  float meanVc = acc*(1.f/9.f) + bv[c];
  float gamma = gammap[0];
  float fpv[9]; float ss = 0.f;
  #pragma unroll
  for(int i=0;i<9;i++){
    float v = (mval[i]!=0.f) ? gamma*A[i] : meanVc;
    fpv[i] = v; ss += v*v;
  }
  for(int off=32; off>0; off>>=1) ss += __shfl_down(ss, off);
  ss = __shfl(ss, 0);
  float scale = 1.f / fmaxf(sqrtf(ss), 1e-4f);
  #pragma unroll
  for(int i=0;i<9;i++){
    u16 h,l; split_bf16(fpv[i]*scale, h, l);
    size_t o = (size_t)p*576 + c*9 + i;
    AH[o] = h; AL[o] = l;
  }
}

// Stage B collapsed + im2col + split
__global__ void k_bcolT_split(const float* __restrict__ fds0, const float* __restrict__ maskds,
                              const float* __restrict__ meanVf, const float* __restrict__ gfp,
                              u16* __restrict__ BTH0, u16* __restrict__ BTL0){
  int s = blockIdx.y;
  const float* fds = fds0 + (size_t)s*SSTR;
  u16* BTH = BTH0 + (size_t)s*2*SSTR;
  u16* BTL = BTL0 + (size_t)s*2*SSTR;
  int idx = blockIdx.x*256 + threadIdx.x;
  if(idx >= NB*576) return;
  int P = idx/576, k = idx%576;
  int c = k/9, i = k%9, u = i/3, v = i%3;
  int hP = P/HD, wP = P%HD;
  int y = hP+u-1, x = wP+v-1;
  float val = 0.f;
  if(y>=0&&y<HD&&x>=0&&x<HD){
    int pos = y*HD + x;
    val = (maskds[pos]!=0.f) ? gfp[0]*fds[(size_t)c*NB + pos] : meanVf[s*64 + c];
  }
  u16 h,l; split_bf16(val, h, l);
  BTH[idx] = h; BTL[idx] = l;
}

// ---------------- MFMA bf16x3 GEMM v3: double-buffered LDS, 1 barrier/K-step ----------------
__global__ __launch_bounds__(256, 2)
void k_gemm3(const u16* __restrict__ AH0, const u16* __restrict__ AL0,
             const u16* __restrict__ BTH0, const u16* __restrict__ BTL0,
             float* __restrict__ C0, int M, int N, int K, int Kc, int nz,
             int ldA, int ldB, int ldC, long zstrC){
  __shared__ u16 sAH[2][128*32], sAL[2][128*32], sBH[2][128*32], sBL[2][128*32];
  int tid = threadIdx.x;
  int s = blockIdx.z / nz, zk = blockIdx.z % nz;
  const u16* AH  = AH0  + (size_t)s*2*SSTR;
  const u16* AL  = AL0  + (size_t)s*2*SSTR;
  const u16* BTH = BTH0 + (size_t)s*2*SSTR;
  const u16* BTL = BTL0 + (size_t)s*2*SSTR;
  float* Cz = C0 + (size_t)s*SSTR + (size_t)zk*zstrC;
  int kbeg = zk*Kc; int kend = kbeg+Kc; if(kend>K) kend=K;
  int m0 = blockIdx.y*128, n0 = blockIdx.x*128;
  int w = tid>>6, lane = tid&63;
  int wr = w>>1, wc = w&1;
  int fr = lane&15, fq = lane>>4;
  int r = tid>>1, hf = tid&1;
  int ar = m0+r, br = n0+r;
  bool aok = (ar<M), bok = (br<N);
  int g0 = hf*2, g1 = hf*2+1;

  f32x4 acc[4][4];
  #pragma unroll
  for(int i=0;i<4;i++)
    #pragma unroll
    for(int j=0;j<4;j++) acc[i][j] = (f32x4){0.f,0.f,0.f,0.f};

  u16x8 pa0h,pa0l,pb0h,pb0l,pa1h,pa1l,pb1h,pb1l;
  const u16x8 z8 = (u16x8)(u16)0;

#define GLOAD(K0) { \
    pa0h=z8;pa0l=z8;pb0h=z8;pb0l=z8;pa1h=z8;pa1l=z8;pb1h=z8;pb1l=z8; \
    if(aok){ size_t o=(size_t)ar*ldA + (K0); \
      pa0h=*(const u16x8*)&AH[o+g0*8]; pa0l=*(const u16x8*)&AL[o+g0*8]; \
      pa1h=*(const u16x8*)&AH[o+g1*8]; pa1l=*(const u16x8*)&AL[o+g1*8]; } \
    if(bok){ size_t o=(size_t)br*ldB + (K0); \
      pb0h=*(const u16x8*)&BTH[o+g0*8]; pb0l=*(const u16x8*)&BTL[o+g0*8]; \
      pb1h=*(const u16x8*)&BTH[o+g1*8]; pb1l=*(const u16x8*)&BTL[o+g1*8]; } }

#define LSTORE(BUF) { \
    int gs0=(g0^((r>>1)&3))*8, gs1=(g1^((r>>1)&3))*8; \
    *(u16x8*)&sAH[BUF][r*32+gs0]=pa0h; *(u16x8*)&sAL[BUF][r*32+gs0]=pa0l; \
    *(u16x8*)&sBH[BUF][r*32+gs0]=pb0h; *(u16x8*)&sBL[BUF][r*32+gs0]=pb0l; \
    *(u16x8*)&sAH[BUF][r*32+gs1]=pa1h; *(u16x8*)&sAL[BUF][r*32+gs1]=pa1l; \
    *(u16x8*)&sBH[BUF][r*32+gs1]=pb1h; *(u16x8*)&sBL[BUF][r*32+gs1]=pb1l; }

  GLOAD(kbeg);
  LSTORE(0);
  if(kbeg+32 < kend) GLOAD(kbeg+32);
  __syncthreads();
  int cur = 0;
  for(int k0=kbeg; k0<kend; k0+=32){
    if(k0+32 < kend){
      LSTORE(cur^1);
      if(k0+64 < kend) GLOAD(k0+64);
    }
    s16x8 a_h[4],a_l[4],b_h[4],b_l[4];
    #pragma unroll
    for(int mi=0;mi<4;mi++){
      int row=wr*64+mi*16+fr; int gs=(fq^((row>>1)&3))*8;
      a_h[mi]=*(const s16x8*)&sAH[cur][row*32+gs];
      a_l[mi]=*(const s16x8*)&sAL[cur][row*32+gs];
    }
    #pragma unroll
    for(int ni=0;ni<4;ni++){
      int row=wc*64+ni*16+fr; int gs=(fq^((row>>1)&3))*8;
      b_h[ni]=*(const s16x8*)&sBH[cur][row*32+gs];
      b_l[ni]=*(const s16x8*)&sBL[cur][row*32+gs];
    }
    #pragma unroll
    for(int mi=0;mi<4;mi++)
      #pragma unroll
      for(int ni=0;ni<4;ni++){
        acc[mi][ni] = __builtin_amdgcn_mfma_f32_16x16x32_bf16(a_h[mi], b_h[ni], acc[mi][ni], 0,0,0);
        acc[mi][ni] = __builtin_amdgcn_mfma_f32_16x16x32_bf16(a_h[mi], b_l[ni], acc[mi][ni], 0,0,0);
        acc[mi][ni] = __builtin_amdgcn_mfma_f32_16x16x32_bf16(a_l[mi], b_h[ni], acc[mi][ni], 0,0,0);
      }
    __syncthreads();
    cur ^= 1;
  }
#undef GLOAD
#undef LSTORE
  #pragma unroll
  for(int mi=0;mi<4;mi++)
    #pragma unroll
    for(int ni=0;ni<4;ni++){
      int row = m0 + wr*64 + mi*16 + fq*4;
      int col = n0 + wc*64 + ni*16 + fr;
      if(col < N){
        #pragma unroll
        for(int rr=0;rr<4;rr++)
          if(row+rr < M) Cz[(size_t)(row+rr)*ldC + col] = acc[mi][ni][rr];
      }
    }
}

// fuse_merge + fuse1 + Pi-permute, with yneed row skip.
// X[r][t] = sum_z pz taps; write Y[pi(r)][d*48+c] = X[r][c*48+d]
__global__ void k_fuseP(const float* __restrict__ P0b, const float* __restrict__ P1b,
                        const float* __restrict__ mmP, float* __restrict__ Yb){
  int s = blockIdx.y;
  const float* p0 = P0b + (size_t)s*SSTR;
  const float* p1 = P1b + (size_t)s*SSTR;
  float* Y = Yb + (size_t)s*SSTR;
  int r = blockIdx.x;
  int a = r/HD, b2 = r%HD;
  int rb = b2*HD + a;
  float need = mmP[rb];
  if(rb>0)    need += mmP[rb-1];
  if(rb<NB-1) need += mmP[rb+1];
  if(need == 0.f) return;   // Y row never read downstream
  __shared__ float lds[48*49];
  const float* r0a = p0 + (size_t)r*NB;
  const float* r1a = p1 + (size_t)r*NB;
  for(int t=threadIdx.x; t<NB; t+=256){
    float v = r0a[t] + r1a[t];
    if(r>0 && t>0){
      size_t o = (size_t)(r-1)*NB + (t-1);
      v += p0[o] + p1[o];
    }
    if(r<NB-1 && t<NB-1){
      size_t o = (size_t)(r+1)*NB + (t+1);
      v += p0[o] + p1[o];
    }
    lds[(t/HD)*49 + (t%HD)] = v;
  }
  __syncthreads();
  float* orow = Y + (size_t)rb*NB;
  for(int t=threadIdx.x; t<NB; t+=256){
    int d = t/HD, c = t%HD;
    orow[t] = lds[c*49 + d];
  }
}

// fuse1-on-the-fly + column-softmax partials over ACTIVE rows only
__global__ void k_fuse_colsm(const float* __restrict__ Yb, const float* __restrict__ mmP,
                             float* __restrict__ pmax, float* __restrict__ psum){
  int s = blockIdx.z;
  const float* Y = Yb + (size_t)s*SSTR;
  int col = blockIdx.x*256 + threadIdx.x;
  int q0 = blockIdx.y*144;
  float mx = -1e30f, sum = 0.f;
  for(int q=q0; q<q0+144; q++){
    if(mmP[q] == 0.f) continue;          // wave-uniform skip
    float L = Y[(size_t)q*NB + col];
    if(q>0 && col>0)       L += Y[(size_t)(q-1)*NB + col-1];
    if(q<NB-1 && col<NB-1) L += Y[(size_t)(q+1)*NB + col+1];
    L *= 10.f;
    if(L > mx){ sum *= __expf(mx - L); mx = L; }
    sum += __expf(L - mx);
  }
  pmax[(size_t)(s*16 + blockIdx.y)*NB + col] = mx;
  psum[(size_t)(s*16 + blockIdx.y)*NB + col] = sum;
}

// combine partials; inactive rows contribute (NB-nAct)*exp(-M) in closed form
__global__ void k_combine(const float* __restrict__ pmax, const float* __restrict__ psum,
                          const float* __restrict__ mmP,
                          float* __restrict__ cmax, float* __restrict__ cinv){
  int s = blockIdx.y;
  int col = blockIdx.x*256 + threadIdx.x;
  int tid = threadIdx.x;
  __shared__ float redc[4];
  float cnt = 0.f;
  for(int k=tid; k<NB; k+=256) cnt += mmP[k];
  for(int off=32; off>0; off>>=1) cnt += __shfl_down(cnt, off);
  if((tid&63)==0) redc[tid>>6] = cnt;
  __syncthreads();
  float nAct = redc[0]+redc[1]+redc[2]+redc[3];
  float M = -1e30f;
  for(int k=0;k<16;k++) M = fmaxf(M, pmax[(size_t)(s*16+k)*NB + col]);
  if(nAct < NB - 0.5f) M = fmaxf(M, 0.f);
  float S = 0.f;
  for(int k=0;k<16;k++){
    float pm = pmax[(size_t)(s*16+k)*NB + col];
    float ps = psum[(size_t)(s*16+k)*NB + col];
    S += ps * __expf(pm - M);
  }
  S += ((float)NB - nAct) * __expf(0.f - M);
  cmax[s*NB + col] = M;
  cinv[s*NB + col] = 1.f/S;
}

// fuse1-on-the-fly + softmax apply + double transpose -> yiT
__global__ void k_fuse_apply(const float* __restrict__ Yb, const float* __restrict__ mmP,
                             const float* __restrict__ cmax, const float* __restrict__ cinv,
                             float* __restrict__ yiTb){
  int s = blockIdx.y;
  const float* Y = Yb + (size_t)s*SSTR;
  float* yiT = yiTb + (size_t)s*SSTR;
  const float* cm = cmax + s*NB;
  const float* ci = cinv + s*NB;
  __shared__ float lds[48*49];
  int alpha = blockIdx.x/HD, delta = blockIdx.x%HD;
  for(int t=threadIdx.x; t<NB; t+=256){
    int beta = t/HD, gamma = t%HD;
    int qp = beta*HD + alpha;
    int Pp = delta*HD + gamma;
    float v = 0.f;
    if(mmP[qp] != 0.f){
      float L = Y[(size_t)qp*NB + Pp];
      if(qp>0 && Pp>0)       L += Y[(size_t)(qp-1)*NB + Pp-1];
      if(qp<NB-1 && Pp<NB-1) L += Y[(size_t)(qp+1)*NB + Pp+1];
      v = __expf(10.f*L - cm[Pp]) * ci[Pp];
    }
    lds[beta*49 + gamma] = v;
  }
  __syncthreads();
  for(int t=threadIdx.x; t<NB; t+=256){
    int gamma = t/HD, beta = t%HD;
    yiT[(size_t)(gamma*HD + delta)*NB + alpha*HD + beta] = lds[beta*49 + gamma];
  }
}

// U^T via stencil on yiT, split bf16: UT[(rho,sig)][pp], [NP][KP]
__global__ void k_zbuildT_split(const float* __restrict__ yiTb,
                                u16* __restrict__ UTH0, u16* __restrict__ UTL0){
  int s = blockIdx.z;
  const float* yiT = yiTb + (size_t)s*SSTR;
  u16* UTH = UTH0 + (size_t)s*2*SSTR;
  u16* UTL = UTL0 + (size_t)s*2*SSTR;
  int row = blockIdx.y;
  int cc  = blockIdx.x*256 + threadIdx.x;
  if(cc >= KP) return;
  size_t o = (size_t)row*KP + cc;
  float z = 0.f;
  if(cc < NP){
    int rho = row/49, sig = row%49;
    int ph = cc/49, pw = cc%49;
    #pragma unroll
    for(int a=0;a<2;a++)
      #pragma unroll
      for(int bb=0;bb<2;bb++){
        int sh=ph-a, sw=pw-bb, rr=rho-a, ss=sig-bb;
        if(sh>=0 && sh<HD && sw>=0 && sw<HD && rr>=0 && rr<HD && ss>=0 && ss<HD)
          z += yiT[(size_t)(rr*HD+ss)*NB + sh*HD+sw];
      }
  }
  u16 h,l; split_bf16(z, h, l);
  UTH[o] = h; UTL[o] = l;
}

__global__ void k_b4_split(const float* __restrict__ b,
                           u16* __restrict__ B4H0, u16* __restrict__ B4L0){
  int s = blockIdx.y;
  u16* B4H = B4H0 + (size_t)s*2*SSTR;
  u16* B4L = B4L0 + (size_t)s*2*SSTR;
  int idx = blockIdx.x*256 + threadIdx.x;
  if(idx >= 256*KP) return;
  int m = idx/KP, kk = idx%KP;
  float val = 0.f;
  if(kk < NP){
    int phase = m>>6, c = m&63;
    int py = phase>>1, px = phase&1;
    int ph = kk/49, pw = kk%49;
    int y = 2*ph - py, x = 2*pw - px;
    if(y>=0&&y<IMG&&x>=0&&x<IMG) val = b[(((size_t)s*NC + c)*IMG + y)*IMG + x];
  }
  u16 h,l; split_bf16(val, h, l);
  B4H[idx] = h; B4L[idx] = l;
}

// epilogue: sum 4 G partials, interleave phases, *0.25
__global__ void k_epi(const float* __restrict__ Gb, float* __restrict__ out){
  int s = blockIdx.y;
  const float* G = Gb + (size_t)s*SSTR;
  int idx = blockIdx.x*256 + threadIdx.x;
  if(idx >= NC*IMG*IMG) return;
  int c = idx/(IMG*IMG), rem = idx%(IMG*IMG);
  int y = rem/IMG, x = rem%IMG;
  int py = y&1, px = x&1, r = y>>1, s2 = x>>1;
  size_t gi = (size_t)((py*2+px)*64 + c)*NP + (r+py)*49 + (s2+px);
  const size_t gz = (size_t)256*NP;
  float v = G[gi] + G[gi+gz] + G[gi+2*gz] + G[gi+3*gz];
  out[((size_t)s*NC + c)*IMG*IMG + rem] = v * 0.25f;
}

// ---------------- launcher ----------------
extern "C" void kernel_launch(void* const* d_in, const int* in_sizes, int n_in,
                              void* d_out, int out_size, void* d_ws, size_t ws_size,
                              hipStream_t stream){
  const float* f    = (const float*)d_in[0];
  const float* b    = (const float*)d_in[1];
  const float* mask = (const float*)d_in[2];
  const float* fa_wv=(const float*)d_in[7];  const float* fa_bv=(const float*)d_in[8];
  const float* fa_g =(const float*)d_in[9];
  const float* pa_wv=(const float*)d_in[14]; const float* pa_bv=(const float*)d_in[15];
  const float* pa_g =(const float*)d_in[16];
  float* out = (float*)d_out;
  float* ws  = (float*)d_ws;
  if(ws_size < TOTAL_F*sizeof(float)) return;

  float* maskds = ws + O_MASKDS;
  float* mmP    = ws + O_MMP;
  float* cmax   = ws + O_CMAX;
  float* cinv   = ws + O_CINV;
  float* pmax   = ws + O_PMAX;
  float* psum   = ws + O_PSUM;
  float* meanf  = ws + O_MEAN;
  float* meanVf = ws + O_MEAN + 128;

  float* fds0  = ws + O_ARENA0 + A_FDS;
  float* fdsT0 = ws + O_ARENA0 + A_FDST;
  u16*   AH0   = (u16*)(ws + O_ARENA0 + A_SCR);
  u16*   AL0   = AH0 + (size_t)NB*576;
  u16*   BTH0  = AL0 + (size_t)NB*576;
  u16*   BTL0  = BTH0 + (size_t)NB*576;
  float* G0    = ws + O_ARENA0 + A_SCR;         // reuses scratch after C-GEMM consumed it
  float* P0_0  = ws + O_ARENA0 + A_P0;
  float* P1_0  = ws + O_ARENA0 + A_P1;
  float* Y0    = ws + O_ARENA0 + A_Y;
  float* yiT0  = P0_0;                          // partials dead after fuseP
  u16*   UTH0  = (u16*)P1_0;
  u16*   UTL0  = UTH0 + (size_t)NP*KP;
  u16*   B4H0  = (u16*)(ws + O_ARENA0 + A_B4);
  u16*   B4L0  = B4H0 + (size_t)256*KP;

  k_prep_mask<<<9, 256, 0, stream>>>(mask, maskds, mmP);
  k_ds<<<dim3(CDIV(NC*NB,256), 2), 256, 0, stream>>>(f, fds0, fdsT0);
  k_colmean<<<dim3(64, 2), 256, 0, stream>>>(fds0, meanf);
  k_meanvf<<<2, 64, 0, stream>>>(meanf, fa_wv, fa_bv, meanVf);
  k_stageA<<<dim3(NB, 2), 64, 0, stream>>>(fdsT0, maskds, pa_wv, pa_bv, pa_g, AH0, AL0);
  k_bcolT_split<<<dim3(CDIV(NB*576,256), 2), 256, 0, stream>>>(fds0, maskds, meanVf, fa_g, BTH0, BTL0);

  // Stage C GEMM: both samples, K-split 2 (partials -> P0, P1)
  k_gemm3<<<dim3(18,18,4), 256, 0, stream>>>(AH0, AL0, BTH0, BTL0, P0_0,
      NB, NB, 576, 288, 2, 576, 576, NB, (long)(P1_0 - P0_0));

  // fuse chain (sparse)
  k_fuseP<<<dim3(NB, 2), 256, 0, stream>>>(P0_0, P1_0, mmP, Y0);
  k_fuse_colsm<<<dim3(9,16,2), 256, 0, stream>>>(Y0, mmP, pmax, psum);
  k_combine<<<dim3(9, 2), 256, 0, stream>>>(pmax, psum, mmP, cmax, cinv);
  k_fuse_apply<<<dim3(NB, 2), 256, 0, stream>>>(Y0, mmP, cmax, cinv, yiT0);

  // Stage F
  k_zbuildT_split<<<dim3(CDIV(KP,256), NP, 2), 256, 0, stream>>>(yiT0, UTH0, UTL0);
  k_b4_split<<<dim3(CDIV(256*KP,256), 2), 256, 0, stream>>>(b, B4H0, B4L0);
  k_gemm3<<<dim3(CDIV(NP,128), 2, 8), 256, 0, stream>>>(B4H0, B4L0, UTH0, UTL0, G0,
      256, NP, KP, 608, 4, KP, KP, NP, (long)256*NP);
  k_epi<<<dim3(CDIV(NC*IMG*IMG,256), 2), 256, 0, stream>>>(G0, out);
}

// Round 7
// 241.755 us; speedup vs baseline: 7.5244x; 1.0705x over previous
//
#include <hip/hip_runtime.h>
#include <math.h>

#define HD 48
#define NB 2304      // 48*48
#define NC 64
#define IMG 96
#define NP 2401      // 49*49
#define KP 2432      // NP padded to mult of 64

#define CDIV(a,b) (((a)+(b)-1)/(b))

typedef unsigned short u16;
typedef __attribute__((ext_vector_type(8))) short  s16x8;
typedef __attribute__((ext_vector_type(8))) unsigned short u16x8;
typedef __attribute__((ext_vector_type(4))) float  f32x4;

// ---------------- workspace layout (float slots) ----------------
constexpr size_t O_MASKDS = 0;
constexpr size_t O_MMP    = NB;
constexpr size_t O_CMAX   = (size_t)2*NB;   // 2 samples
constexpr size_t O_CINV   = (size_t)4*NB;
constexpr size_t O_PMAX   = (size_t)6*NB;   // [s][16][NB]
constexpr size_t O_PSUM   = (size_t)38*NB;
constexpr size_t O_MEAN   = (size_t)70*NB;  // meanf 2x64, meanVf 2x64
constexpr size_t O_ACT    = (size_t)70*NB + 256;  // int actIdx[2432] + int nActPad[2]
constexpr size_t O_ARENA0 = (size_t)72*NB;
// per-sample arena (floats):
constexpr size_t A_FDS  = 0;                         // 147456
constexpr size_t A_FDST = 147456;                    // 147456
constexpr size_t A_SCR  = 294912;                    // AH/AL/BTH/BTL (4 x NB*576 u16) -> later G (4 x 256*NP f)
constexpr size_t A_P0   = A_SCR + 2654208;           // NB^2 partial0 -> later yiT
constexpr size_t A_P1   = A_P0 + (size_t)NB*NB;      // NB^2 partial1 -> later UT (2 x NP*KP u16)
constexpr size_t A_Y    = A_P1 + 5839232;            // NB^2
constexpr size_t A_B4   = A_Y + (size_t)NB*NB;       // 2 x 256*KP u16
constexpr size_t SSTR   = A_B4 + 622592;
constexpr size_t TOTAL_F = O_ARENA0 + 2*SSTR;        // ~161 MiB

// ---------------- helpers ----------------
__device__ inline void split_bf16(float x, u16& hi, u16& lo){
  unsigned int u = __float_as_uint(x);
  unsigned int r = u + 0x7FFFu + ((u >> 16) & 1u);
  hi = (u16)(r >> 16);
  float xh = __uint_as_float(((unsigned int)hi) << 16);
  float res = x - xh;
  unsigned int u2 = __float_as_uint(res);
  unsigned int r2 = u2 + 0x7FFFu + ((u2 >> 16) & 1u);
  lo = (u16)(r2 >> 16);
}

// ---------------- kernels ----------------

__global__ void k_prep_mask(const float* __restrict__ mask, float* __restrict__ maskds,
                            float* __restrict__ mmP){
  int q = blockIdx.x*256 + threadIdx.x;
  if(q >= NB) return;
  int hq = q/HD, wq = q%HD;
  maskds[q] = mask[(2*hq)*IMG + 2*wq];
  float any = 0.f;
  for(int u=-1;u<=1;u++)
    for(int v=-1;v<=1;v++){
      int y=hq+u, x=wq+v;
      if(y>=0&&y<HD&&x>=0&&x<HD) any += mask[(2*y)*IMG + 2*x];
    }
  mmP[wq*HD + hq] = (any == 0.f) ? 1.f : 0.f;
}

// active-p' list (mask-shared across samples): p' active iff any of its 4 source q is mm-active
__global__ void k_actlist(const float* __restrict__ mmP, int* __restrict__ actIdx,
                          int* __restrict__ nActPad){
  __shared__ int cnt[256], base[256];
  int tid = threadIdx.x;
  int c0 = tid*10, c1 = min(c0+10, NP);
  int flags = 0, lc = 0;
  for(int i=c0;i<c1;i++){
    int ph=i/49, pw=i%49;
    bool act=false;
    #pragma unroll
    for(int a=0;a<2;a++)
      #pragma unroll
      for(int bb=0;bb<2;bb++){
        int sh=ph-a, sw=pw-bb;
        if(sh>=0&&sh<HD&&sw>=0&&sw<HD && mmP[sw*HD+sh]!=0.f) act=true;
      }
    if(act){ flags |= 1<<(i-c0); lc++; }
  }
  cnt[tid]=lc;
  __syncthreads();
  if(tid==0){
    int run=0;
    for(int i=0;i<256;i++){ base[i]=run; run+=cnt[i]; }
    int pad=(run+63)&~63;
    nActPad[0]=pad; nActPad[1]=run;
    for(int k=run;k<pad;k++) actIdx[k]=NP;   // sentinel
  }
  __syncthreads();
  int o=base[tid];
  for(int i=c0;i<c1;i++) if(flags & (1<<(i-c0))) actIdx[o++]=i;
}

// downsample f -> fds [c][j] and fdsT [j][c], batched over samples
__global__ void k_ds(const float* __restrict__ src, float* __restrict__ fds0,
                     float* __restrict__ fdsT0){
  int s = blockIdx.y;
  float* fds  = fds0  + (size_t)s*SSTR;
  float* fdsT = fdsT0 + (size_t)s*SSTR;
  int idx = blockIdx.x*256 + threadIdx.x;
  if(idx >= NC*NB) return;
  int c = idx/NB, j = idx%NB;
  int h = j/HD, w = j%HD;
  float v = src[(((size_t)s*NC + c)*IMG + 2*h)*IMG + 2*w];
  fds[idx] = v;
  fdsT[(size_t)j*64 + c] = v;
}

__global__ void k_colmean(const float* __restrict__ fds0, float* __restrict__ meanf){
  int s = blockIdx.y;
  const float* fds = fds0 + (size_t)s*SSTR;
  int c = blockIdx.x;
  int tid = threadIdx.x;
  float sum = 0.f;
  for(int j=tid; j<NB; j+=256) sum += fds[(size_t)c*NB + j];
  for(int off=32; off>0; off>>=1) sum += __shfl_down(sum, off);
  __shared__ float red[4];
  if((tid&63)==0) red[tid>>6] = sum;
  __syncthreads();
  if(tid==0) meanf[s*64 + c] = (red[0]+red[1]+red[2]+red[3]) * (1.f/NB);
}

__global__ void k_meanvf(const float* __restrict__ meanf, const float* __restrict__ wv,
                         const float* __restrict__ bv, float* __restrict__ meanVf){
  int s = blockIdx.x;
  __shared__ float mf[64];
  int c = threadIdx.x;
  mf[c] = meanf[s*64 + c];
  __syncthreads();
  float sum = 0.f;
  for(int cc=0;cc<64;cc++) sum += wv[c*64+cc]*mf[cc];
  meanVf[s*64 + c] = sum + bv[c];
}

// Stage A collapsed, 4 patches per 256-thread block (one per wave)
__global__ void k_stageA(const float* __restrict__ fdsT0, const float* __restrict__ maskds,
                         const float* __restrict__ wv, const float* __restrict__ bv,
                         const float* __restrict__ gammap,
                         u16* __restrict__ AH0, u16* __restrict__ AL0){
  int s = blockIdx.y;
  const float* fdsT = fdsT0 + (size_t)s*SSTR;
  u16* AH = AH0 + (size_t)s*2*SSTR;
  u16* AL = AL0 + (size_t)s*2*SSTR;
  __shared__ float sumA[4][64];
  __shared__ float mval[4][9];
  int wsl = threadIdx.x>>6;
  int c = threadIdx.x&63;
  int p = blockIdx.x*4 + wsl;
  int ph = p/HD, pw = p%HD;
  float A[9]; float sa = 0.f;
  #pragma unroll
  for(int i=0;i<9;i++){
    int u=i/3, v=i%3;
    int y=ph+u-1, x=pw+v-1;
    bool in = (y>=0&&y<HD&&x>=0&&x<HD);
    float fv = in ? fdsT[(size_t)(y*HD+x)*64 + c] : 0.f;
    A[i] = fv; sa += fv;
    if(c==0) mval[wsl][i] = in ? maskds[y*HD+x] : 0.f;
  }
  sumA[wsl][c] = sa;
  __syncthreads();
  float acc = 0.f;
  for(int cc=0;cc<64;cc++) acc += wv[c*64+cc]*sumA[wsl][cc];
  float meanVc = acc*(1.f/9.f) + bv[c];
  float gamma = gammap[0];
  float fpv[9]; float ss = 0.f;
  #pragma unroll
  for(int i=0;i<9;i++){
    float v = (mval[wsl][i]!=0.f) ? gamma*A[i] : meanVc;
    fpv[i] = v; ss += v*v;
  }
  for(int off=32; off>0; off>>=1) ss += __shfl_down(ss, off);
  ss = __shfl(ss, 0);
  float scale = 1.f / fmaxf(sqrtf(ss), 1e-4f);
  #pragma unroll
  for(int i=0;i<9;i++){
    u16 h,l; split_bf16(fpv[i]*scale, h, l);
    size_t o = (size_t)p*576 + c*9 + i;
    AH[o] = h; AL[o] = l;
  }
}

// Stage B collapsed + im2col + split
__global__ void k_bcolT_split(const float* __restrict__ fds0, const float* __restrict__ maskds,
                              const float* __restrict__ meanVf, const float* __restrict__ gfp,
                              u16* __restrict__ BTH0, u16* __restrict__ BTL0){
  int s = blockIdx.y;
  const float* fds = fds0 + (size_t)s*SSTR;
  u16* BTH = BTH0 + (size_t)s*2*SSTR;
  u16* BTL = BTL0 + (size_t)s*2*SSTR;
  int idx = blockIdx.x*256 + threadIdx.x;
  if(idx >= NB*576) return;
  int P = idx/576, k = idx%576;
  int c = k/9, i = k%9, u = i/3, v = i%3;
  int hP = P/HD, wP = P%HD;
  int y = hP+u-1, x = wP+v-1;
  float val = 0.f;
  if(y>=0&&y<HD&&x>=0&&x<HD){
    int pos = y*HD + x;
    val = (maskds[pos]!=0.f) ? gfp[0]*fds[(size_t)c*NB + pos] : meanVf[s*64 + c];
  }
  u16 h,l; split_bf16(val, h, l);
  BTH[idx] = h; BTL[idx] = l;
}

// ---------------- MFMA bf16x3 GEMM v3: dbuf LDS, runtime-K capable ----------------
__global__ __launch_bounds__(256, 2)
void k_gemm3(const u16* __restrict__ AH0, const u16* __restrict__ AL0,
             const u16* __restrict__ BTH0, const u16* __restrict__ BTL0,
             float* __restrict__ C0, int M, int N, int Kparam, int nz,
             const int* __restrict__ Kdev,
             int ldA, int ldB, int ldC, long zstrC){
  __shared__ u16 sAH[2][128*32], sAL[2][128*32], sBH[2][128*32], sBL[2][128*32];
  int tid = threadIdx.x;
  int s = blockIdx.z / nz, zk = blockIdx.z % nz;
  const u16* AH  = AH0  + (size_t)s*2*SSTR;
  const u16* AL  = AL0  + (size_t)s*2*SSTR;
  const u16* BTH = BTH0 + (size_t)s*2*SSTR;
  const u16* BTL = BTL0 + (size_t)s*2*SSTR;
  float* Cz = C0 + (size_t)s*SSTR + (size_t)zk*zstrC;
  int K = Kdev ? Kdev[0] : Kparam;
  int Kc = (((K+31)/32 + nz - 1)/nz)*32;
  int kbeg = zk*Kc; int kend = kbeg+Kc; if(kend>K) kend=K;
  int m0 = blockIdx.y*128, n0 = blockIdx.x*128;
  int w = tid>>6, lane = tid&63;
  int wr = w>>1, wc = w&1;
  int fr = lane&15, fq = lane>>4;
  int r = tid>>1, hf = tid&1;
  int ar = m0+r, br = n0+r;
  bool aok = (ar<M), bok = (br<N);
  int g0 = hf*2, g1 = hf*2+1;

  f32x4 acc[4][4];
  #pragma unroll
  for(int i=0;i<4;i++)
    #pragma unroll
    for(int j=0;j<4;j++) acc[i][j] = (f32x4){0.f,0.f,0.f,0.f};

  u16x8 pa0h,pa0l,pb0h,pb0l,pa1h,pa1l,pb1h,pb1l;
  const u16x8 z8 = (u16x8)(u16)0;

#define GLOAD(K0) { \
    pa0h=z8;pa0l=z8;pb0h=z8;pb0l=z8;pa1h=z8;pa1l=z8;pb1h=z8;pb1l=z8; \
    if(aok){ size_t o=(size_t)ar*ldA + (K0); \
      pa0h=*(const u16x8*)&AH[o+g0*8]; pa0l=*(const u16x8*)&AL[o+g0*8]; \
      pa1h=*(const u16x8*)&AH[o+g1*8]; pa1l=*(const u16x8*)&AL[o+g1*8]; } \
    if(bok){ size_t o=(size_t)br*ldB + (K0); \
      pb0h=*(const u16x8*)&BTH[o+g0*8]; pb0l=*(const u16x8*)&BTL[o+g0*8]; \
      pb1h=*(const u16x8*)&BTH[o+g1*8]; pb1l=*(const u16x8*)&BTL[o+g1*8]; } }

#define LSTORE(BUF) { \
    int gs0=(g0^((r>>1)&3))*8, gs1=(g1^((r>>1)&3))*8; \
    *(u16x8*)&sAH[BUF][r*32+gs0]=pa0h; *(u16x8*)&sAL[BUF][r*32+gs0]=pa0l; \
    *(u16x8*)&sBH[BUF][r*32+gs0]=pb0h; *(u16x8*)&sBL[BUF][r*32+gs0]=pb0l; \
    *(u16x8*)&sAH[BUF][r*32+gs1]=pa1h; *(u16x8*)&sAL[BUF][r*32+gs1]=pa1l; \
    *(u16x8*)&sBH[BUF][r*32+gs1]=pb1h; *(u16x8*)&sBL[BUF][r*32+gs1]=pb1l; }

  if(kbeg < kend){
    GLOAD(kbeg);
    LSTORE(0);
    if(kbeg+32 < kend) GLOAD(kbeg+32);
  }
  __syncthreads();
  int cur = 0;
  for(int k0=kbeg; k0<kend; k0+=32){
    if(k0+32 < kend){
      LSTORE(cur^1);
      if(k0+64 < kend) GLOAD(k0+64);
    }
    s16x8 a_h[4],a_l[4],b_h[4],b_l[4];
    #pragma unroll
    for(int mi=0;mi<4;mi++){
      int row=wr*64+mi*16+fr; int gs=(fq^((row>>1)&3))*8;
      a_h[mi]=*(const s16x8*)&sAH[cur][row*32+gs];
      a_l[mi]=*(const s16x8*)&sAL[cur][row*32+gs];
    }
    #pragma unroll
    for(int ni=0;ni<4;ni++){
      int row=wc*64+ni*16+fr; int gs=(fq^((row>>1)&3))*8;
      b_h[ni]=*(const s16x8*)&sBH[cur][row*32+gs];
      b_l[ni]=*(const s16x8*)&sBL[cur][row*32+gs];
    }
    #pragma unroll
    for(int mi=0;mi<4;mi++)
      #pragma unroll
      for(int ni=0;ni<4;ni++){
        acc[mi][ni] = __builtin_amdgcn_mfma_f32_16x16x32_bf16(a_h[mi], b_h[ni], acc[mi][ni], 0,0,0);
        acc[mi][ni] = __builtin_amdgcn_mfma_f32_16x16x32_bf16(a_h[mi], b_l[ni], acc[mi][ni], 0,0,0);
        acc[mi][ni] = __builtin_amdgcn_mfma_f32_16x16x32_bf16(a_l[mi], b_h[ni], acc[mi][ni], 0,0,0);
      }
    __syncthreads();
    cur ^= 1;
  }
#undef GLOAD
#undef LSTORE
  #pragma unroll
  for(int mi=0;mi<4;mi++)
    #pragma unroll
    for(int ni=0;ni<4;ni++){
      int row = m0 + wr*64 + mi*16 + fq*4;
      int col = n0 + wc*64 + ni*16 + fr;
      if(col < N){
        #pragma unroll
        for(int rr=0;rr<4;rr++)
          if(row+rr < M) Cz[(size_t)(row+rr)*ldC + col] = acc[mi][ni][rr];
      }
    }
}

// fuse_merge + fuse1 + Pi-permute, with yneed row skip
__global__ void k_fuseP(const float* __restrict__ P0b, const float* __restrict__ P1b,
                        const float* __restrict__ mmP, float* __restrict__ Yb){
  int s = blockIdx.y;
  const float* p0 = P0b + (size_t)s*SSTR;
  const float* p1 = P1b + (size_t)s*SSTR;
  float* Y = Yb + (size_t)s*SSTR;
  int r = blockIdx.x;
  int a = r/HD, b2 = r%HD;
  int rb = b2*HD + a;
  float need = mmP[rb];
  if(rb>0)    need += mmP[rb-1];
  if(rb<NB-1) need += mmP[rb+1];
  if(need == 0.f) return;
  __shared__ float lds[48*49];
  const float* r0a = p0 + (size_t)r*NB;
  const float* r1a = p1 + (size_t)r*NB;
  for(int t=threadIdx.x; t<NB; t+=256){
    float v = r0a[t] + r1a[t];
    if(r>0 && t>0){
      size_t o = (size_t)(r-1)*NB + (t-1);
      v += p0[o] + p1[o];
    }
    if(r<NB-1 && t<NB-1){
      size_t o = (size_t)(r+1)*NB + (t+1);
      v += p0[o] + p1[o];
    }
    lds[(t/HD)*49 + (t%HD)] = v;
  }
  __syncthreads();
  float* orow = Y + (size_t)rb*NB;
  for(int t=threadIdx.x; t<NB; t+=256){
    int d = t/HD, c = t%HD;
    orow[t] = lds[c*49 + d];
  }
}

// fuse1-on-the-fly + column-softmax partials over ACTIVE rows only
__global__ void k_fuse_colsm(const float* __restrict__ Yb, const float* __restrict__ mmP,
                             float* __restrict__ pmax, float* __restrict__ psum){
  int s = blockIdx.z;
  const float* Y = Yb + (size_t)s*SSTR;
  int col = blockIdx.x*256 + threadIdx.x;
  int q0 = blockIdx.y*144;
  float mx = -1e30f, sum = 0.f;
  for(int q=q0; q<q0+144; q++){
    if(mmP[q] == 0.f) continue;
    float L = Y[(size_t)q*NB + col];
    if(q>0 && col>0)       L += Y[(size_t)(q-1)*NB + col-1];
    if(q<NB-1 && col<NB-1) L += Y[(size_t)(q+1)*NB + col+1];
    L *= 10.f;
    if(L > mx){ sum *= __expf(mx - L); mx = L; }
    sum += __expf(L - mx);
  }
  pmax[(size_t)(s*16 + blockIdx.y)*NB + col] = mx;
  psum[(size_t)(s*16 + blockIdx.y)*NB + col] = sum;
}

__global__ void k_combine(const float* __restrict__ pmax, const float* __restrict__ psum,
                          const float* __restrict__ mmP,
                          float* __restrict__ cmax, float* __restrict__ cinv){
  int s = blockIdx.y;
  int col = blockIdx.x*256 + threadIdx.x;
  int tid = threadIdx.x;
  __shared__ float redc[4];
  float cnt = 0.f;
  for(int k=tid; k<NB; k+=256) cnt += mmP[k];
  for(int off=32; off>0; off>>=1) cnt += __shfl_down(cnt, off);
  if((tid&63)==0) redc[tid>>6] = cnt;
  __syncthreads();
  float nAct = redc[0]+redc[1]+redc[2]+redc[3];
  float M = -1e30f;
  for(int k=0;k<16;k++) M = fmaxf(M, pmax[(size_t)(s*16+k)*NB + col]);
  if(nAct < NB - 0.5f) M = fmaxf(M, 0.f);
  float S = 0.f;
  for(int k=0;k<16;k++){
    float pm = pmax[(size_t)(s*16+k)*NB + col];
    float ps = psum[(size_t)(s*16+k)*NB + col];
    S += ps * __expf(pm - M);
  }
  S += ((float)NB - nAct) * __expf(0.f - M);
  cmax[s*NB + col] = M;
  cinv[s*NB + col] = 1.f/S;
}

// fuse1-on-the-fly + softmax apply + double transpose -> yiT (active columns only)
__global__ void k_fuse_apply(const float* __restrict__ Yb, const float* __restrict__ mmP,
                             const float* __restrict__ cmax, const float* __restrict__ cinv,
                             float* __restrict__ yiTb){
  int s = blockIdx.y;
  const float* Y = Yb + (size_t)s*SSTR;
  float* yiT = yiTb + (size_t)s*SSTR;
  const float* cm = cmax + s*NB;
  const float* ci = cinv + s*NB;
  __shared__ float lds[48*49];
  int alpha = blockIdx.x/HD, delta = blockIdx.x%HD;
  for(int t=threadIdx.x; t<NB; t+=256){
    int beta = t/HD, gamma = t%HD;
    int qp = beta*HD + alpha;
    int Pp = delta*HD + gamma;
    float v = 0.f;
    if(mmP[qp] != 0.f){
      float L = Y[(size_t)qp*NB + Pp];
      if(qp>0 && Pp>0)       L += Y[(size_t)(qp-1)*NB + Pp-1];
      if(qp<NB-1 && Pp<NB-1) L += Y[(size_t)(qp+1)*NB + Pp+1];
      v = __expf(10.f*L - cm[Pp]) * ci[Pp];
    }
    lds[beta*49 + gamma] = v;
  }
  __syncthreads();
  for(int t=threadIdx.x; t<NB; t+=256){
    int gamma = t/HD, beta = t%HD;
    if(mmP[beta*HD + alpha] != 0.f)   // column active -> worth storing
      yiT[(size_t)(gamma*HD + delta)*NB + alpha*HD + beta] = lds[beta*49 + gamma];
  }
}

// U^T compacted: UTc[(rho,sig)][k] for k < nActPad, p' = actIdx[k]; taps mm-guarded
__global__ void k_zbuildT_split(const float* __restrict__ yiTb, const float* __restrict__ mmP,
                                const int* __restrict__ actIdx, const int* __restrict__ nActPad,
                                u16* __restrict__ UTH0, u16* __restrict__ UTL0){
  int s = blockIdx.z;
  const float* yiT = yiTb + (size_t)s*SSTR;
  u16* UTH = UTH0 + (size_t)s*2*SSTR;
  u16* UTL = UTL0 + (size_t)s*2*SSTR;
  int row = blockIdx.y;
  int cc  = blockIdx.x*256 + threadIdx.x;
  if(cc >= nActPad[0]) return;
  int pp = actIdx[cc];
  float z = 0.f;
  if(pp < NP){
    int rho = row/49, sig = row%49;
    int ph = pp/49, pw = pp%49;
    #pragma unroll
    for(int a=0;a<2;a++)
      #pragma unroll
      for(int bb=0;bb<2;bb++){
        int sh=ph-a, sw=pw-bb, rr=rho-a, ss=sig-bb;
        if(sh>=0 && sh<HD && sw>=0 && sw<HD && rr>=0 && rr<HD && ss>=0 && ss<HD
           && mmP[sw*HD+sh] != 0.f)
          z += yiT[(size_t)(rr*HD+ss)*NB + sh*HD+sw];
      }
  }
  u16 h,l; split_bf16(z, h, l);
  size_t o = (size_t)row*KP + cc;
  UTH[o] = h; UTL[o] = l;
}

// phase-gathered b, compacted in k: b4c[m][k] = b[...actIdx[k]...]
__global__ void k_b4_split(const float* __restrict__ b,
                           const int* __restrict__ actIdx, const int* __restrict__ nActPad,
                           u16* __restrict__ B4H0, u16* __restrict__ B4L0){
  int s = blockIdx.y;
  u16* B4H = B4H0 + (size_t)s*2*SSTR;
  u16* B4L = B4L0 + (size_t)s*2*SSTR;
  int idx = blockIdx.x*256 + threadIdx.x;
  if(idx >= 256*KP) return;
  int m = idx/KP, kk = idx%KP;
  if(kk >= nActPad[0]) return;
  int pp = actIdx[kk];
  float val = 0.f;
  if(pp < NP){
    int phase = m>>6, c = m&63;
    int py = phase>>1, px = phase&1;
    int ph = pp/49, pw = pp%49;
    int y = 2*ph - py, x = 2*pw - px;
    if(y>=0&&y<IMG&&x>=0&&x<IMG) val = b[(((size_t)s*NC + c)*IMG + y)*IMG + x];
  }
  u16 h,l; split_bf16(val, h, l);
  B4H[idx] = h; B4L[idx] = l;
}

// epilogue: sum 4 G partials, interleave phases, *0.25
__global__ void k_epi(const float* __restrict__ Gb, float* __restrict__ out){
  int s = blockIdx.y;
  const float* G = Gb + (size_t)s*SSTR;
  int idx = blockIdx.x*256 + threadIdx.x;
  if(idx >= NC*IMG*IMG) return;
  int c = idx/(IMG*IMG), rem = idx%(IMG*IMG);
  int y = rem/IMG, x = rem%IMG;
  int py = y&1, px = x&1, r = y>>1, s2 = x>>1;
  size_t gi = (size_t)((py*2+px)*64 + c)*NP + (r+py)*49 + (s2+px);
  const size_t gz = (size_t)256*NP;
  float v = G[gi] + G[gi+gz] + G[gi+2*gz] + G[gi+3*gz];
  out[((size_t)s*NC + c)*IMG*IMG + rem] = v * 0.25f;
}

// ---------------- launcher ----------------
extern "C" void kernel_launch(void* const* d_in, const int* in_sizes, int n_in,
                              void* d_out, int out_size, void* d_ws, size_t ws_size,
                              hipStream_t stream){
  const float* f    = (const float*)d_in[0];
  const float* b    = (const float*)d_in[1];
  const float* mask = (const float*)d_in[2];
  const float* fa_wv=(const float*)d_in[7];  const float* fa_bv=(const float*)d_in[8];
  const float* fa_g =(const float*)d_in[9];
  const float* pa_wv=(const float*)d_in[14]; const float* pa_bv=(const float*)d_in[15];
  const float* pa_g =(const float*)d_in[16];
  float* out = (float*)d_out;
  float* ws  = (float*)d_ws;
  if(ws_size < TOTAL_F*sizeof(float)) return;

  float* maskds = ws + O_MASKDS;
  float* mmP    = ws + O_MMP;
  float* cmax   = ws + O_CMAX;
  float* cinv   = ws + O_CINV;
  float* pmax   = ws + O_PMAX;
  float* psum   = ws + O_PSUM;
  float* meanf  = ws + O_MEAN;
  float* meanVf = ws + O_MEAN + 128;
  int*   actIdx  = (int*)(ws + O_ACT);
  int*   nActPad = actIdx + 2432;

  float* fds0  = ws + O_ARENA0 + A_FDS;
  float* fdsT0 = ws + O_ARENA0 + A_FDST;
  u16*   AH0   = (u16*)(ws + O_ARENA0 + A_SCR);
  u16*   AL0   = AH0 + (size_t)NB*576;
  u16*   BTH0  = AL0 + (size_t)NB*576;
  u16*   BTL0  = BTH0 + (size_t)NB*576;
  float* G0    = ws + O_ARENA0 + A_SCR;
  float* P0_0  = ws + O_ARENA0 + A_P0;
  float* P1_0  = ws + O_ARENA0 + A_P1;
  float* Y0    = ws + O_ARENA0 + A_Y;
  float* yiT0  = P0_0;
  u16*   UTH0  = (u16*)P1_0;
  u16*   UTL0  = UTH0 + (size_t)NP*KP;
  u16*   B4H0  = (u16*)(ws + O_ARENA0 + A_B4);
  u16*   B4L0  = B4H0 + (size_t)256*KP;

  k_prep_mask<<<9, 256, 0, stream>>>(mask, maskds, mmP);
  k_actlist<<<1, 256, 0, stream>>>(mmP, actIdx, nActPad);
  k_ds<<<dim3(CDIV(NC*NB,256), 2), 256, 0, stream>>>(f, fds0, fdsT0);
  k_colmean<<<dim3(64, 2), 256, 0, stream>>>(fds0, meanf);
  k_meanvf<<<2, 64, 0, stream>>>(meanf, fa_wv, fa_bv, meanVf);
  k_stageA<<<dim3(NB/4, 2), 256, 0, stream>>>(fdsT0, maskds, pa_wv, pa_bv, pa_g, AH0, AL0);
  k_bcolT_split<<<dim3(CDIV(NB*576,256), 2), 256, 0, stream>>>(fds0, maskds, meanVf, fa_g, BTH0, BTL0);

  // Stage C GEMM: K-split 2 (partials -> P0, P1)
  k_gemm3<<<dim3(18,18,4), 256, 0, stream>>>(AH0, AL0, BTH0, BTL0, P0_0,
      NB, NB, 576, 2, nullptr, 576, 576, NB, (long)(P1_0 - P0_0));

  // fuse chain (sparse)
  k_fuseP<<<dim3(NB, 2), 256, 0, stream>>>(P0_0, P1_0, mmP, Y0);
  k_fuse_colsm<<<dim3(9,16,2), 256, 0, stream>>>(Y0, mmP, pmax, psum);
  k_combine<<<dim3(9, 2), 256, 0, stream>>>(pmax, psum, mmP, cmax, cinv);
  k_fuse_apply<<<dim3(NB, 2), 256, 0, stream>>>(Y0, mmP, cmax, cinv, yiT0);

  // Stage F (K-compacted)
  k_zbuildT_split<<<dim3(CDIV(KP,256), NP, 2), 256, 0, stream>>>(yiT0, mmP, actIdx, nActPad, UTH0, UTL0);
  k_b4_split<<<dim3(CDIV(256*KP,256), 2), 256, 0, stream>>>(b, actIdx, nActPad, B4H0, B4L0);
  k_gemm3<<<dim3(CDIV(NP,128), 2, 8), 256, 0, stream>>>(B4H0, B4L0, UTH0, UTL0, G0,
      256, NP, KP, 4, nActPad, KP, KP, NP, (long)256*NP);
  k_epi<<<dim3(CDIV(NC*IMG*IMG,256), 2), 256, 0, stream>>>(G0, out);
}

// Round 8
// 224.059 us; speedup vs baseline: 8.1187x; 1.0790x over previous
//
#include <hip/hip_runtime.h>
#include <math.h>

#define HD 48
#define NB 2304      // 48*48
#define NC 64
#define IMG 96
#define NP 2401      // 49*49
#define KP 2432      // NP padded to mult of 64

#define CDIV(a,b) (((a)+(b)-1)/(b))

typedef unsigned short u16;
typedef __attribute__((ext_vector_type(8))) short  s16x8;
typedef __attribute__((ext_vector_type(8))) unsigned short u16x8;
typedef __attribute__((ext_vector_type(4))) float  f32x4;

// ---------------- workspace layout (float slots) ----------------
constexpr size_t O_MASKDS = 0;
constexpr size_t O_MMP    = NB;
constexpr size_t O_CMAX   = (size_t)2*NB;   // 2 samples
constexpr size_t O_CINV   = (size_t)4*NB;
constexpr size_t O_PMAX   = (size_t)6*NB;   // [s][16][NB]
constexpr size_t O_PSUM   = (size_t)38*NB;
constexpr size_t O_MEAN   = (size_t)70*NB;  // meanf 2x64, meanVf 2x64
constexpr size_t O_ACT    = (size_t)70*NB + 256;  // int actIdx[2432] + nActPad[2]
constexpr size_t O_ROWIDX = O_ACT + 2434/1 + 62;  // int rowIdx[2304+128]
constexpr size_t O_INVROW = O_ROWIDX + 2560;      // int invRow[2304]
constexpr size_t O_NROW   = O_INVROW + NB;        // int nRowPad[2]
constexpr size_t O_NEEDX  = O_NROW + 64;          // float needX[2304]
constexpr size_t O_ARENA0 = O_NEEDX + NB + 64;
// per-sample arena (floats):
constexpr size_t A_FDS  = 0;
constexpr size_t A_FDST = 147456;
constexpr size_t A_SCR  = 294912;                    // AH/AL/BTH/BTL (4 x NB*576 u16) -> later G
constexpr size_t A_P0   = A_SCR + 2654208;           // Scmp (<=NB^2) -> later yiT
constexpr size_t A_P1   = A_P0 + (size_t)NB*NB;      // free -> UT (2 x NP*KP u16)
constexpr size_t A_Y    = A_P1 + 5839232;            // NB^2
constexpr size_t A_B4   = A_Y + (size_t)NB*NB;       // 2 x 256*KP u16
constexpr size_t SSTR   = A_B4 + 622592;
constexpr size_t TOTAL_F = O_ARENA0 + 2*SSTR;

// ---------------- helpers ----------------
__device__ inline void split_bf16(float x, u16& hi, u16& lo){
  unsigned int u = __float_as_uint(x);
  unsigned int r = u + 0x7FFFu + ((u >> 16) & 1u);
  hi = (u16)(r >> 16);
  float xh = __uint_as_float(((unsigned int)hi) << 16);
  float res = x - xh;
  unsigned int u2 = __float_as_uint(res);
  unsigned int r2 = u2 + 0x7FFFu + ((u2 >> 16) & 1u);
  lo = (u16)(r2 >> 16);
}

// ---------------- kernels ----------------

__global__ void k_prep_mask(const float* __restrict__ mask, float* __restrict__ maskds,
                            float* __restrict__ mmP){
  int q = blockIdx.x*256 + threadIdx.x;
  if(q >= NB) return;
  int hq = q/HD, wq = q%HD;
  maskds[q] = mask[(2*hq)*IMG + 2*wq];
  float any = 0.f;
  for(int u=-1;u<=1;u++)
    for(int v=-1;v<=1;v++){
      int y=hq+u, x=wq+v;
      if(y>=0&&y<HD&&x>=0&&x<HD) any += mask[(2*y)*IMG + 2*x];
    }
  mmP[wq*HD + hq] = (any == 0.f) ? 1.f : 0.f;
}

// active-p' list for stage-F K compaction
__global__ void k_actlist(const float* __restrict__ mmP, int* __restrict__ actIdx,
                          int* __restrict__ nActPad){
  __shared__ int cnt[256], base[256];
  int tid = threadIdx.x;
  int c0 = tid*10, c1 = min(c0+10, NP);
  int flags = 0, lc = 0;
  for(int i=c0;i<c1;i++){
    int ph=i/49, pw=i%49;
    bool act=false;
    #pragma unroll
    for(int a=0;a<2;a++)
      #pragma unroll
      for(int bb=0;bb<2;bb++){
        int sh=ph-a, sw=pw-bb;
        if(sh>=0&&sh<HD&&sw>=0&&sw<HD && mmP[sw*HD+sh]!=0.f) act=true;
      }
    if(act){ flags |= 1<<(i-c0); lc++; }
  }
  cnt[tid]=lc;
  __syncthreads();
  if(tid==0){
    int run=0;
    for(int i=0;i<256;i++){ base[i]=run; run+=cnt[i]; }
    int pad=(run+63)&~63;
    nActPad[0]=pad; nActPad[1]=run;
    for(int k=run;k<pad;k++) actIdx[k]=NP;   // sentinel
  }
  __syncthreads();
  int o=base[tid];
  for(int i=c0;i<c1;i++) if(flags & (1<<(i-c0))) actIdx[o++]=i;
}

// needed score-row list for stage-C M compaction:
// Z rows needed = active qp; Y rows = +-1 dilation; X rows = invpi; score rows = +-1 dilation
__global__ void k_rowlist(const float* __restrict__ mmP, int* __restrict__ rowIdx,
                          int* __restrict__ invRow, int* __restrict__ nRowPad,
                          float* __restrict__ needXf){
  __shared__ unsigned char needX[NB], needS[NB];
  __shared__ int cnt[256], base[256];
  int tid = threadIdx.x;
  for(int i=tid;i<NB;i+=256){ needX[i]=0; }
  __syncthreads();
  for(int qp=tid; qp<NB; qp+=256){
    if(mmP[qp]!=0.f){
      #pragma unroll
      for(int d=-1;d<=1;d++){
        int rb=qp+d; if(rb<0||rb>=NB) continue;
        int b2=rb/HD, a=rb%HD;
        needX[a*HD + b2] = 1;
      }
    }
  }
  __syncthreads();
  for(int r=tid;r<NB;r+=256){
    unsigned char v = needX[r];
    if(r>0)    v |= needX[r-1];
    if(r<NB-1) v |= needX[r+1];
    needS[r]=v;
  }
  __syncthreads();
  int c0 = tid*9, c1 = min(c0+9, NB);
  int lc=0; for(int i=c0;i<c1;i++) lc += needS[i];
  cnt[tid]=lc;
  __syncthreads();
  if(tid==0){
    int run=0;
    for(int i=0;i<256;i++){ base[i]=run; run+=cnt[i]; }
    int pad=(run+127)&~127;
    nRowPad[0]=pad; nRowPad[1]=run;
    for(int k=run;k<pad;k++) rowIdx[k]=NB;   // sentinel
  }
  __syncthreads();
  int o=base[tid];
  for(int i=c0;i<c1;i++){
    if(needS[i]){ rowIdx[o]=i; invRow[i]=o; o++; }
    else invRow[i] = -1;
  }
  for(int i=tid;i<NB;i+=256) needXf[i] = needX[i] ? 1.f : 0.f;
}

// downsample f -> fds [c][j] and fdsT [j][c]
__global__ void k_ds(const float* __restrict__ src, float* __restrict__ fds0,
                     float* __restrict__ fdsT0){
  int s = blockIdx.y;
  float* fds  = fds0  + (size_t)s*SSTR;
  float* fdsT = fdsT0 + (size_t)s*SSTR;
  int idx = blockIdx.x*256 + threadIdx.x;
  if(idx >= NC*NB) return;
  int c = idx/NB, j = idx%NB;
  int h = j/HD, w = j%HD;
  float v = src[(((size_t)s*NC + c)*IMG + 2*h)*IMG + 2*w];
  fds[idx] = v;
  fdsT[(size_t)j*64 + c] = v;
}

__global__ void k_colmean(const float* __restrict__ fds0, float* __restrict__ meanf){
  int s = blockIdx.y;
  const float* fds = fds0 + (size_t)s*SSTR;
  int c = blockIdx.x;
  int tid = threadIdx.x;
  float sum = 0.f;
  for(int j=tid; j<NB; j+=256) sum += fds[(size_t)c*NB + j];
  for(int off=32; off>0; off>>=1) sum += __shfl_down(sum, off);
  __shared__ float red[4];
  if((tid&63)==0) red[tid>>6] = sum;
  __syncthreads();
  if(tid==0) meanf[s*64 + c] = (red[0]+red[1]+red[2]+red[3]) * (1.f/NB);
}

__global__ void k_meanvf(const float* __restrict__ meanf, const float* __restrict__ wv,
                         const float* __restrict__ bv, float* __restrict__ meanVf){
  int s = blockIdx.x;
  __shared__ float mf[64];
  int c = threadIdx.x;
  mf[c] = meanf[s*64 + c];
  __syncthreads();
  float sum = 0.f;
  for(int cc=0;cc<64;cc++) sum += wv[c*64+cc]*mf[cc];
  meanVf[s*64 + c] = sum + bv[c];
}

// Stage A collapsed, 4 patches per block
__global__ void k_stageA(const float* __restrict__ fdsT0, const float* __restrict__ maskds,
                         const float* __restrict__ wv, const float* __restrict__ bv,
                         const float* __restrict__ gammap,
                         u16* __restrict__ AH0, u16* __restrict__ AL0){
  int s = blockIdx.y;
  const float* fdsT = fdsT0 + (size_t)s*SSTR;
  u16* AH = AH0 + (size_t)s*2*SSTR;
  u16* AL = AL0 + (size_t)s*2*SSTR;
  __shared__ float sumA[4][64];
  __shared__ float mval[4][9];
  int wsl = threadIdx.x>>6;
  int c = threadIdx.x&63;
  int p = blockIdx.x*4 + wsl;
  int ph = p/HD, pw = p%HD;
  float A[9]; float sa = 0.f;
  #pragma unroll
  for(int i=0;i<9;i++){
    int u=i/3, v=i%3;
    int y=ph+u-1, x=pw+v-1;
    bool in = (y>=0&&y<HD&&x>=0&&x<HD);
    float fv = in ? fdsT[(size_t)(y*HD+x)*64 + c] : 0.f;
    A[i] = fv; sa += fv;
    if(c==0) mval[wsl][i] = in ? maskds[y*HD+x] : 0.f;
  }
  sumA[wsl][c] = sa;
  __syncthreads();
  float acc = 0.f;
  for(int cc=0;cc<64;cc++) acc += wv[c*64+cc]*sumA[wsl][cc];
  float meanVc = acc*(1.f/9.f) + bv[c];
  float gamma = gammap[0];
  float fpv[9]; float ss = 0.f;
  #pragma unroll
  for(int i=0;i<9;i++){
    float v = (mval[wsl][i]!=0.f) ? gamma*A[i] : meanVc;
    fpv[i] = v; ss += v*v;
  }
  for(int off=32; off>0; off>>=1) ss += __shfl_down(ss, off);
  ss = __shfl(ss, 0);
  float scale = 1.f / fmaxf(sqrtf(ss), 1e-4f);
  #pragma unroll
  for(int i=0;i<9;i++){
    u16 h,l; split_bf16(fpv[i]*scale, h, l);
    size_t o = (size_t)p*576 + c*9 + i;
    AH[o] = h; AL[o] = l;
  }
}

// Stage B collapsed + im2col + split
__global__ void k_bcolT_split(const float* __restrict__ fds0, const float* __restrict__ maskds,
                              const float* __restrict__ meanVf, const float* __restrict__ gfp,
                              u16* __restrict__ BTH0, u16* __restrict__ BTL0){
  int s = blockIdx.y;
  const float* fds = fds0 + (size_t)s*SSTR;
  u16* BTH = BTH0 + (size_t)s*2*SSTR;
  u16* BTL = BTL0 + (size_t)s*2*SSTR;
  int idx = blockIdx.x*256 + threadIdx.x;
  if(idx >= NB*576) return;
  int P = idx/576, k = idx%576;
  int c = k/9, i = k%9, u = i/3, v = i%3;
  int hP = P/HD, wP = P%HD;
  int y = hP+u-1, x = wP+v-1;
  float val = 0.f;
  if(y>=0&&y<HD&&x>=0&&x<HD){
    int pos = y*HD + x;
    val = (maskds[pos]!=0.f) ? gfp[0]*fds[(size_t)c*NB + pos] : meanVf[s*64 + c];
  }
  u16 h,l; split_bf16(val, h, l);
  BTH[idx] = h; BTL[idx] = l;
}

// ---------------- MFMA bf16x3 GEMM: dbuf LDS, runtime-K, optional A-row gather ----------------
__global__ __launch_bounds__(256, 2)
void k_gemm3(const u16* __restrict__ AH0, const u16* __restrict__ AL0,
             const u16* __restrict__ BTH0, const u16* __restrict__ BTL0,
             float* __restrict__ C0, int M, int N, int Kparam, int nz,
             const int* __restrict__ Kdev,
             const int* __restrict__ rowIdx, const int* __restrict__ Mdev,
             int ldA, int ldB, int ldC, long zstrC){
  __shared__ u16 sAH[2][128*32], sAL[2][128*32], sBH[2][128*32], sBL[2][128*32];
  int tid = threadIdx.x;
  int s = blockIdx.z / nz, zk = blockIdx.z % nz;
  int Mout = Mdev ? Mdev[0] : M;
  int m0 = blockIdx.y*128, n0 = blockIdx.x*128;
  if(m0 >= Mout) return;
  const u16* AH  = AH0  + (size_t)s*2*SSTR;
  const u16* AL  = AL0  + (size_t)s*2*SSTR;
  const u16* BTH = BTH0 + (size_t)s*2*SSTR;
  const u16* BTL = BTL0 + (size_t)s*2*SSTR;
  float* Cz = C0 + (size_t)s*SSTR + (size_t)zk*zstrC;
  int K = Kdev ? Kdev[0] : Kparam;
  int Kc = (((K+31)/32 + nz - 1)/nz)*32;
  int kbeg = zk*Kc; int kend = kbeg+Kc; if(kend>K) kend=K;
  int w = tid>>6, lane = tid&63;
  int wr = w>>1, wc = w&1;
  int fr = lane&15, fq = lane>>4;
  int r = tid>>1, hf = tid&1;
  int arow = m0+r;
  if(rowIdx) arow = rowIdx[arow];
  int br = n0+r;
  bool aok = (arow < M), bok = (br < N);
  int g0 = hf*2, g1 = hf*2+1;

  f32x4 acc[4][4];
  #pragma unroll
  for(int i=0;i<4;i++)
    #pragma unroll
    for(int j=0;j<4;j++) acc[i][j] = (f32x4){0.f,0.f,0.f,0.f};

  u16x8 pa0h,pa0l,pb0h,pb0l,pa1h,pa1l,pb1h,pb1l;
  const u16x8 z8 = (u16x8)(u16)0;

#define GLOAD(K0) { \
    pa0h=z8;pa0l=z8;pb0h=z8;pb0l=z8;pa1h=z8;pa1l=z8;pb1h=z8;pb1l=z8; \
    if(aok){ size_t o=(size_t)arow*ldA + (K0); \
      pa0h=*(const u16x8*)&AH[o+g0*8]; pa0l=*(const u16x8*)&AL[o+g0*8]; \
      pa1h=*(const u16x8*)&AH[o+g1*8]; pa1l=*(const u16x8*)&AL[o+g1*8]; } \
    if(bok){ size_t o=(size_t)br*ldB + (K0); \
      pb0h=*(const u16x8*)&BTH[o+g0*8]; pb0l=*(const u16x8*)&BTL[o+g0*8]; \
      pb1h=*(const u16x8*)&BTH[o+g1*8]; pb1l=*(const u16x8*)&BTL[o+g1*8]; } }

#define LSTORE(BUF) { \
    int gs0=(g0^((r>>1)&3))*8, gs1=(g1^((r>>1)&3))*8; \
    *(u16x8*)&sAH[BUF][r*32+gs0]=pa0h; *(u16x8*)&sAL[BUF][r*32+gs0]=pa0l; \
    *(u16x8*)&sBH[BUF][r*32+gs0]=pb0h; *(u16x8*)&sBL[BUF][r*32+gs0]=pb0l; \
    *(u16x8*)&sAH[BUF][r*32+gs1]=pa1h; *(u16x8*)&sAL[BUF][r*32+gs1]=pa1l; \
    *(u16x8*)&sBH[BUF][r*32+gs1]=pb1h; *(u16x8*)&sBL[BUF][r*32+gs1]=pb1l; }

  if(kbeg < kend){
    GLOAD(kbeg);
    LSTORE(0);
    if(kbeg+32 < kend) GLOAD(kbeg+32);
  }
  __syncthreads();
  int cur = 0;
  for(int k0=kbeg; k0<kend; k0+=32){
    if(k0+32 < kend){
      LSTORE(cur^1);
      if(k0+64 < kend) GLOAD(k0+64);
    }
    s16x8 a_h[4],a_l[4],b_h[4],b_l[4];
    #pragma unroll
    for(int mi=0;mi<4;mi++){
      int row=wr*64+mi*16+fr; int gs=(fq^((row>>1)&3))*8;
      a_h[mi]=*(const s16x8*)&sAH[cur][row*32+gs];
      a_l[mi]=*(const s16x8*)&sAL[cur][row*32+gs];
    }
    #pragma unroll
    for(int ni=0;ni<4;ni++){
      int row=wc*64+ni*16+fr; int gs=(fq^((row>>1)&3))*8;
      b_h[ni]=*(const s16x8*)&sBH[cur][row*32+gs];
      b_l[ni]=*(const s16x8*)&sBL[cur][row*32+gs];
    }
    #pragma unroll
    for(int mi=0;mi<4;mi++)
      #pragma unroll
      for(int ni=0;ni<4;ni++){
        acc[mi][ni] = __builtin_amdgcn_mfma_f32_16x16x32_bf16(a_h[mi], b_h[ni], acc[mi][ni], 0,0,0);
        acc[mi][ni] = __builtin_amdgcn_mfma_f32_16x16x32_bf16(a_h[mi], b_l[ni], acc[mi][ni], 0,0,0);
        acc[mi][ni] = __builtin_amdgcn_mfma_f32_16x16x32_bf16(a_l[mi], b_h[ni], acc[mi][ni], 0,0,0);
      }
    __syncthreads();
    cur ^= 1;
  }
#undef GLOAD
#undef LSTORE
  #pragma unroll
  for(int mi=0;mi<4;mi++)
    #pragma unroll
    for(int ni=0;ni<4;ni++){
      int row = m0 + wr*64 + mi*16 + fq*4;
      int col = n0 + wc*64 + ni*16 + fr;
      if(col < N){
        #pragma unroll
        for(int rr=0;rr<4;rr++)
          if(row+rr < Mout) Cz[(size_t)(row+rr)*ldC + col] = acc[mi][ni][rr];
      }
    }
}

// fuse1 on compacted scores + Pi-permute; only needed X rows
__global__ void k_fuseP(const float* __restrict__ Sb, const int* __restrict__ invRow,
                        const float* __restrict__ needXf, float* __restrict__ Yb){
  int s = blockIdx.y;
  int r = blockIdx.x;
  if(needXf[r] == 0.f) return;
  const float* S = Sb + (size_t)s*SSTR;
  float* Y = Yb + (size_t)s*SSTR;
  int i0 = invRow[r];
  int im = (r>0)    ? invRow[r-1] : -1;
  int ip = (r<NB-1) ? invRow[r+1] : -1;
  __shared__ float lds[48*49];
  const float* row0 = S + (size_t)i0*NB;
  for(int t=threadIdx.x; t<NB; t+=256){
    float v = row0[t];
    if(im>=0 && t>0)    v += S[(size_t)im*NB + t-1];
    if(ip>=0 && t<NB-1) v += S[(size_t)ip*NB + t+1];
    lds[(t/HD)*49 + (t%HD)] = v;
  }
  __syncthreads();
  int a = r/HD, b2 = r%HD;
  float* orow = Y + (size_t)(b2*HD + a)*NB;
  for(int t=threadIdx.x; t<NB; t+=256){
    int d = t/HD, c = t%HD;
    orow[t] = lds[c*49 + d];
  }
}

// fuse1-on-the-fly + column-softmax partials over ACTIVE rows only
__global__ void k_fuse_colsm(const float* __restrict__ Yb, const float* __restrict__ mmP,
                             float* __restrict__ pmax, float* __restrict__ psum){
  int s = blockIdx.z;
  const float* Y = Yb + (size_t)s*SSTR;
  int col = blockIdx.x*256 + threadIdx.x;
  int q0 = blockIdx.y*144;
  float mx = -1e30f, sum = 0.f;
  for(int q=q0; q<q0+144; q++){
    if(mmP[q] == 0.f) continue;
    float L = Y[(size_t)q*NB + col];
    if(q>0 && col>0)       L += Y[(size_t)(q-1)*NB + col-1];
    if(q<NB-1 && col<NB-1) L += Y[(size_t)(q+1)*NB + col+1];
    L *= 10.f;
    if(L > mx){ sum *= __expf(mx - L); mx = L; }
    sum += __expf(L - mx);
  }
  pmax[(size_t)(s*16 + blockIdx.y)*NB + col] = mx;
  psum[(size_t)(s*16 + blockIdx.y)*NB + col] = sum;
}

__global__ void k_combine(const float* __restrict__ pmax, const float* __restrict__ psum,
                          const float* __restrict__ mmP,
                          float* __restrict__ cmax, float* __restrict__ cinv){
  int s = blockIdx.y;
  int col = blockIdx.x*256 + threadIdx.x;
  int tid = threadIdx.x;
  __shared__ float redc[4];
  float cnt = 0.f;
  for(int k=tid; k<NB; k+=256) cnt += mmP[k];
  for(int off=32; off>0; off>>=1) cnt += __shfl_down(cnt, off);
  if((tid&63)==0) redc[tid>>6] = cnt;
  __syncthreads();
  float nAct = redc[0]+redc[1]+redc[2]+redc[3];
  float M = -1e30f;
  for(int k=0;k<16;k++) M = fmaxf(M, pmax[(size_t)(s*16+k)*NB + col]);
  if(nAct < NB - 0.5f) M = fmaxf(M, 0.f);
  float S = 0.f;
  for(int k=0;k<16;k++){
    float pm = pmax[(size_t)(s*16+k)*NB + col];
    float ps = psum[(size_t)(s*16+k)*NB + col];
    S += ps * __expf(pm - M);
  }
  S += ((float)NB - nAct) * __expf(0.f - M);
  cmax[s*NB + col] = M;
  cinv[s*NB + col] = 1.f/S;
}

// fuse1-on-the-fly + softmax apply + double transpose -> yiT (active columns only)
__global__ void k_fuse_apply(const float* __restrict__ Yb, const float* __restrict__ mmP,
                             const float* __restrict__ cmax, const float* __restrict__ cinv,
                             float* __restrict__ yiTb){
  int s = blockIdx.y;
  const float* Y = Yb + (size_t)s*SSTR;
  float* yiT = yiTb + (size_t)s*SSTR;
  const float* cm = cmax + s*NB;
  const float* ci = cinv + s*NB;
  __shared__ float lds[48*49];
  int alpha = blockIdx.x/HD, delta = blockIdx.x%HD;
  for(int t=threadIdx.x; t<NB; t+=256){
    int beta = t/HD, gamma = t%HD;
    int qp = beta*HD + alpha;
    int Pp = delta*HD + gamma;
    float v = 0.f;
    if(mmP[qp] != 0.f){
      float L = Y[(size_t)qp*NB + Pp];
      if(qp>0 && Pp>0)       L += Y[(size_t)(qp-1)*NB + Pp-1];
      if(qp<NB-1 && Pp<NB-1) L += Y[(size_t)(qp+1)*NB + Pp+1];
      v = __expf(10.f*L - cm[Pp]) * ci[Pp];
    }
    lds[beta*49 + gamma] = v;
  }
  __syncthreads();
  for(int t=threadIdx.x; t<NB; t+=256){
    int gamma = t/HD, beta = t%HD;
    if(mmP[beta*HD + alpha] != 0.f)
      yiT[(size_t)(gamma*HD + delta)*NB + alpha*HD + beta] = lds[beta*49 + gamma];
  }
}

// U^T compacted in K
__global__ void k_zbuildT_split(const float* __restrict__ yiTb, const float* __restrict__ mmP,
                                const int* __restrict__ actIdx, const int* __restrict__ nActPad,
                                u16* __restrict__ UTH0, u16* __restrict__ UTL0){
  int s = blockIdx.z;
  const float* yiT = yiTb + (size_t)s*SSTR;
  u16* UTH = UTH0 + (size_t)s*2*SSTR;
  u16* UTL = UTL0 + (size_t)s*2*SSTR;
  int row = blockIdx.y;
  int cc  = blockIdx.x*256 + threadIdx.x;
  if(cc >= nActPad[0]) return;
  int pp = actIdx[cc];
  float z = 0.f;
  if(pp < NP){
    int rho = row/49, sig = row%49;
    int ph = pp/49, pw = pp%49;
    #pragma unroll
    for(int a=0;a<2;a++)
      #pragma unroll
      for(int bb=0;bb<2;bb++){
        int sh=ph-a, sw=pw-bb, rr=rho-a, ss=sig-bb;
        if(sh>=0 && sh<HD && sw>=0 && sw<HD && rr>=0 && rr<HD && ss>=0 && ss<HD
           && mmP[sw*HD+sh] != 0.f)
          z += yiT[(size_t)(rr*HD+ss)*NB + sh*HD+sw];
      }
  }
  u16 h,l; split_bf16(z, h, l);
  size_t o = (size_t)row*KP + cc;
  UTH[o] = h; UTL[o] = l;
}

__global__ void k_b4_split(const float* __restrict__ b,
                           const int* __restrict__ actIdx, const int* __restrict__ nActPad,
                           u16* __restrict__ B4H0, u16* __restrict__ B4L0){
  int s = blockIdx.y;
  u16* B4H = B4H0 + (size_t)s*2*SSTR;
  u16* B4L = B4L0 + (size_t)s*2*SSTR;
  int idx = blockIdx.x*256 + threadIdx.x;
  if(idx >= 256*KP) return;
  int m = idx/KP, kk = idx%KP;
  if(kk >= nActPad[0]) return;
  int pp = actIdx[kk];
  float val = 0.f;
  if(pp < NP){
    int phase = m>>6, c = m&63;
    int py = phase>>1, px = phase&1;
    int ph = pp/49, pw = pp%49;
    int y = 2*ph - py, x = 2*pw - px;
    if(y>=0&&y<IMG&&x>=0&&x<IMG) val = b[(((size_t)s*NC + c)*IMG + y)*IMG + x];
  }
  u16 h,l; split_bf16(val, h, l);
  B4H[idx] = h; B4L[idx] = l;
}

// epilogue: sum 4 G partials, interleave phases, *0.25
__global__ void k_epi(const float* __restrict__ Gb, float* __restrict__ out){
  int s = blockIdx.y;
  const float* G = Gb + (size_t)s*SSTR;
  int idx = blockIdx.x*256 + threadIdx.x;
  if(idx >= NC*IMG*IMG) return;
  int c = idx/(IMG*IMG), rem = idx%(IMG*IMG);
  int y = rem/IMG, x = rem%IMG;
  int py = y&1, px = x&1, r = y>>1, s2 = x>>1;
  size_t gi = (size_t)((py*2+px)*64 + c)*NP + (r+py)*49 + (s2+px);
  const size_t gz = (size_t)256*NP;
  float v = G[gi] + G[gi+gz] + G[gi+2*gz] + G[gi+3*gz];
  out[((size_t)s*NC + c)*IMG*IMG + rem] = v * 0.25f;
}

// ---------------- launcher ----------------
extern "C" void kernel_launch(void* const* d_in, const int* in_sizes, int n_in,
                              void* d_out, int out_size, void* d_ws, size_t ws_size,
                              hipStream_t stream){
  const float* f    = (const float*)d_in[0];
  const float* b    = (const float*)d_in[1];
  const float* mask = (const float*)d_in[2];
  const float* fa_wv=(const float*)d_in[7];  const float* fa_bv=(const float*)d_in[8];
  const float* fa_g =(const float*)d_in[9];
  const float* pa_wv=(const float*)d_in[14]; const float* pa_bv=(const float*)d_in[15];
  const float* pa_g =(const float*)d_in[16];
  float* out = (float*)d_out;
  float* ws  = (float*)d_ws;
  if(ws_size < TOTAL_F*sizeof(float)) return;

  float* maskds = ws + O_MASKDS;
  float* mmP    = ws + O_MMP;
  float* cmax   = ws + O_CMAX;
  float* cinv   = ws + O_CINV;
  float* pmax   = ws + O_PMAX;
  float* psum   = ws + O_PSUM;
  float* meanf  = ws + O_MEAN;
  float* meanVf = ws + O_MEAN + 128;
  int*   actIdx  = (int*)(ws + O_ACT);
  int*   nActPad = actIdx + 2432;
  int*   rowIdx  = (int*)(ws + O_ROWIDX);
  int*   invRow  = (int*)(ws + O_INVROW);
  int*   nRowPad = (int*)(ws + O_NROW);
  float* needXf  = ws + O_NEEDX;

  float* fds0  = ws + O_ARENA0 + A_FDS;
  float* fdsT0 = ws + O_ARENA0 + A_FDST;
  u16*   AH0   = (u16*)(ws + O_ARENA0 + A_SCR);
  u16*   AL0   = AH0 + (size_t)NB*576;
  u16*   BTH0  = AL0 + (size_t)NB*576;
  u16*   BTL0  = BTH0 + (size_t)NB*576;
  float* G0    = ws + O_ARENA0 + A_SCR;
  float* Scmp0 = ws + O_ARENA0 + A_P0;
  float* Y0    = ws + O_ARENA0 + A_Y;
  float* yiT0  = Scmp0;                     // scores dead after fuseP
  u16*   UTH0  = (u16*)(ws + O_ARENA0 + A_P1);
  u16*   UTL0  = UTH0 + (size_t)NP*KP;
  u16*   B4H0  = (u16*)(ws + O_ARENA0 + A_B4);
  u16*   B4L0  = B4H0 + (size_t)256*KP;

  k_prep_mask<<<9, 256, 0, stream>>>(mask, maskds, mmP);
  k_actlist<<<1, 256, 0, stream>>>(mmP, actIdx, nActPad);
  k_rowlist<<<1, 256, 0, stream>>>(mmP, rowIdx, invRow, nRowPad, needXf);
  k_ds<<<dim3(CDIV(NC*NB,256), 2), 256, 0, stream>>>(f, fds0, fdsT0);
  k_colmean<<<dim3(64, 2), 256, 0, stream>>>(fds0, meanf);
  k_meanvf<<<2, 64, 0, stream>>>(meanf, fa_wv, fa_bv, meanVf);
  k_stageA<<<dim3(NB/4, 2), 256, 0, stream>>>(fdsT0, maskds, pa_wv, pa_bv, pa_g, AH0, AL0);
  k_bcolT_split<<<dim3(CDIV(NB*576,256), 2), 256, 0, stream>>>(fds0, maskds, meanVf, fa_g, BTH0, BTL0);

  // Stage C GEMM: row-compacted M, nz=1
  k_gemm3<<<dim3(18,18,2), 256, 0, stream>>>(AH0, AL0, BTH0, BTL0, Scmp0,
      NB, NB, 576, 1, nullptr, rowIdx, nRowPad, 576, 576, NB, 0L);

  // fuse chain (sparse)
  k_fuseP<<<dim3(NB, 2), 256, 0, stream>>>(Scmp0, invRow, needXf, Y0);
  k_fuse_colsm<<<dim3(9,16,2), 256, 0, stream>>>(Y0, mmP, pmax, psum);
  k_combine<<<dim3(9, 2), 256, 0, stream>>>(pmax, psum, mmP, cmax, cinv);
  k_fuse_apply<<<dim3(NB, 2), 256, 0, stream>>>(Y0, mmP, cmax, cinv, yiT0);

  // Stage F (K-compacted)
  k_zbuildT_split<<<dim3(CDIV(KP,256), NP, 2), 256, 0, stream>>>(yiT0, mmP, actIdx, nActPad, UTH0, UTL0);
  k_b4_split<<<dim3(CDIV(256*KP,256), 2), 256, 0, stream>>>(b, actIdx, nActPad, B4H0, B4L0);
  k_gemm3<<<dim3(CDIV(NP,128), 2, 8), 256, 0, stream>>>(B4H0, B4L0, UTH0, UTL0, G0,
      256, NP, KP, 4, nActPad, nullptr, nullptr, KP, KP, NP, (long)256*NP);
  k_epi<<<dim3(CDIV(NC*IMG*IMG,256), 2), 256, 0, stream>>>(G0, out);
}